// Round 2
// baseline (4107.757 us; speedup 1.0000x reference)
//
#include <hip/hip_runtime.h>
#include <math.h>

// ---------------------------------------------------------------------------
// WaveNet forward, f32 throughout (argmax output must match f32 reference).
// Flat layout for conv stages: (channel, time, batch) => buf[c][t*256+n] with
// the reference's dilate() being a pure reinterpretation (verified algebra);
// only leading zero-pads (padN cols) appear, handled at read time (a0 < 0).
//
// Memory-adaptive: the whole conv/skip/end pipeline is chunked over time at
// pool2 granularity; chunk size chosen from ws_size on the host (same every
// call -> graph-capture safe). Per-layer j-ranges per chunk:
//   J5=[M0,M1), Jq cascades with halo; Jlo offsets {-1536,-1280,-768,-768,-512,0},
//   Jhi offsets = skip tail offsets {1792,1536,1024,768,512,0}.
// ---------------------------------------------------------------------------

#define MCAP 327680

static inline long lmax_(long a, long b) { return a > b ? a : b; }

__global__ __launch_bounds__(256) void k_zero(float* __restrict__ p, int n) {
    int i = blockIdx.x * 256 + threadIdx.x;
    if (i < n) p[i] = 0.f;
}

// h0[o][t*256+n] = sum_i start_w[o,i] * x[n,i,t]
__global__ __launch_bounds__(256) void k_start(const float* __restrict__ x,
                                               const float* __restrict__ sw,
                                               float* __restrict__ h0) {
    int j = blockIdx.x * 256 + threadIdx.x;   // < 327680
    int t = j >> 8, n = j & 255;
    float xv[5];
#pragma unroll
    for (int i = 0; i < 5; ++i) xv[i] = x[n * 6400 + i * 1280 + t];
#pragma unroll
    for (int o = 0; o < 32; ++o) {
        float acc = 0.f;
#pragma unroll
        for (int i = 0; i < 5; ++i) acc = fmaf(sw[o * 5 + i], xv[i], acc);
        h0[o * MCAP + j] = acc;
    }
}

// transpose skip_w (6,256,32)->swt[(l*32+i)*256+ch], end1_w (128,256)->e1t[ci*128+co]
__global__ __launch_bounds__(256) void k_prep(const float* __restrict__ skw,
                                              const float* __restrict__ e1w,
                                              float* __restrict__ swt,
                                              float* __restrict__ e1t) {
    int idx = blockIdx.x * 256 + threadIdx.x;
    if (idx < 49152) {
        int k = idx >> 8, ch = idx & 255;
        int l = k >> 5, i = k & 31;
        swt[idx] = skw[l * 8192 + ch * 32 + i];
    }
    if (idx < 32768) {
        int ci = idx >> 7, co = idx & 127;
        e1t[idx] = e1w[co * 256 + ci];
    }
}

// One dilated gated layer over global j in [Jlo, Jlo+Jcnt).
// hin holds input cols starting at hinBase (stride hinStride per channel).
// Writes gated tail cols m=j-so in [M0,M1) to gsl (local m-M0, stride gStride),
// and (if doRes) h_next cols j to hout (local j-houtBase, stride houtStride).
__global__ __launch_bounds__(256) void k_layer_c(
    const float* __restrict__ hin, const int hinBase, const int hinStride,
    float* __restrict__ hout, const int houtBase, const int houtStride,
    float* __restrict__ gsl, const int gStride,
    const float* __restrict__ fw, const float* __restrict__ gw,
    const float* __restrict__ rw,
    const int Jlo, const int Jcnt, const int NpmP, const int padN,
    const int so_, const int M0, const int M1, const int doRes)
{
    const int jj = blockIdx.x * 256 + threadIdx.x;
    if (jj >= Jcnt) return;
    const int j = Jlo + jj;

    float r0[32], r1[32];
    const int a0  = j - padN;
    const int a0l = (a0 < 0 ? 0 : a0) - hinBase;
    const int a1l = (j + NpmP) - hinBase;
#pragma unroll
    for (int i = 0; i < 32; ++i) {
        float v = hin[i * hinStride + a0l];
        r0[i] = (a0 < 0) ? 0.f : v;
        r1[i] = hin[i * hinStride + a1l];
    }

    float gated[32];
#pragma unroll
    for (int o = 0; o < 32; ++o) {
        float f = 0.f, g = 0.f;
        const float* fwo = fw + o * 64;
        const float* gwo = gw + o * 64;
#pragma unroll
        for (int i = 0; i < 32; i += 2) {
            const float4 fv = *(const float4*)(fwo + 2 * i);
            const float4 gv = *(const float4*)(gwo + 2 * i);
            f = fmaf(fv.x, r0[i], f);     f = fmaf(fv.y, r1[i], f);
            f = fmaf(fv.z, r0[i + 1], f); f = fmaf(fv.w, r1[i + 1], f);
            g = fmaf(gv.x, r0[i], g);     g = fmaf(gv.y, r1[i], g);
            g = fmaf(gv.z, r0[i + 1], g); g = fmaf(gv.w, r1[i + 1], g);
        }
        gated[o] = tanhf(f) * (1.f / (1.f + expf(-g)));
    }

    const int m = j - so_;
    if (m >= M0 && m < M1) {
        const int ml = m - M0;
#pragma unroll
        for (int o = 0; o < 32; ++o) gsl[o * gStride + ml] = gated[o];
    }

    if (doRes) {
        const int jl = j - houtBase;
#pragma unroll
        for (int o = 0; o < 32; ++o) {
            float acc = r1[o];   // residual[:,:,K-1:] == tap-1 shift
            const float* rwo = rw + o * 32;
#pragma unroll
            for (int i = 0; i < 32; i += 4) {
                const float4 rv = *(const float4*)(rwo + i);
                acc = fmaf(rv.x, gated[i], acc);
                acc = fmaf(rv.y, gated[i + 1], acc);
                acc = fmaf(rv.z, gated[i + 2], acc);
                acc = fmaf(rv.w, gated[i + 3], acc);
            }
            hout[o * houtStride + jl] = acc;
        }
    }
}

// Fused: skip (K=192 over 6 gated tails) -> relu -> end1 (K=256) + bias -> relu -> y1
// Chunk-local: g slabs stride gs per channel, 32*gs per layer; y1 stride gs.
__global__ __launch_bounds__(256, 2) void k_skip_end1_c(
    const float* __restrict__ g, const float* __restrict__ swt,
    const float* __restrict__ e1t, const float* __restrict__ b1,
    float* __restrict__ y1, const int gs)
{
    __shared__ float gt[192 * 32];   // [k][m]
    __shared__ float st[256 * 36];   // relu(skip) [ch][m], padded stride 36

    const int tid = threadIdx.x;
    const int m0 = blockIdx.x * 32;

    for (int idx = tid; idx < 192 * 32; idx += 256) {
        int k = idx >> 5, m = idx & 31;
        gt[idx] = g[(k >> 5) * (32 * gs) + (k & 31) * gs + m0 + m];
    }
    __syncthreads();

    const int m = (tid & 7) * 4;
    {
        const int ch0 = (tid >> 3) * 8;
        float acc[8][4];
#pragma unroll
        for (int c = 0; c < 8; ++c)
#pragma unroll
            for (int q = 0; q < 4; ++q) acc[c][q] = 0.f;

        for (int k = 0; k < 192; ++k) {
            const float4 gv = *(const float4*)&gt[k * 32 + m];
            const float4 w0 = *(const float4*)&swt[k * 256 + ch0];
            const float4 w1 = *(const float4*)&swt[k * 256 + ch0 + 4];
            const float wv[8] = {w0.x, w0.y, w0.z, w0.w, w1.x, w1.y, w1.z, w1.w};
#pragma unroll
            for (int c = 0; c < 8; ++c) {
                acc[c][0] = fmaf(wv[c], gv.x, acc[c][0]);
                acc[c][1] = fmaf(wv[c], gv.y, acc[c][1]);
                acc[c][2] = fmaf(wv[c], gv.z, acc[c][2]);
                acc[c][3] = fmaf(wv[c], gv.w, acc[c][3]);
            }
        }
#pragma unroll
        for (int c = 0; c < 8; ++c) {
            float4 v;
            v.x = fmaxf(acc[c][0], 0.f);
            v.y = fmaxf(acc[c][1], 0.f);
            v.z = fmaxf(acc[c][2], 0.f);
            v.w = fmaxf(acc[c][3], 0.f);
            *(float4*)&st[(ch0 + c) * 36 + m] = v;
        }
    }
    __syncthreads();
    {
        const int co0 = (tid >> 3) * 4;
        float acc[4][4];
#pragma unroll
        for (int c = 0; c < 4; ++c)
#pragma unroll
            for (int q = 0; q < 4; ++q) acc[c][q] = 0.f;

        for (int ci = 0; ci < 256; ++ci) {
            const float4 sv = *(const float4*)&st[ci * 36 + m];
            const float4 wv = *(const float4*)&e1t[ci * 128 + co0];
            const float wa[4] = {wv.x, wv.y, wv.z, wv.w};
#pragma unroll
            for (int c = 0; c < 4; ++c) {
                acc[c][0] = fmaf(wa[c], sv.x, acc[c][0]);
                acc[c][1] = fmaf(wa[c], sv.y, acc[c][1]);
                acc[c][2] = fmaf(wa[c], sv.z, acc[c][2]);
                acc[c][3] = fmaf(wa[c], sv.w, acc[c][3]);
            }
        }
#pragma unroll
        for (int c = 0; c < 4; ++c) {
            const float bb = b1[co0 + c];
            float4 v;
            v.x = fmaxf(acc[c][0] + bb, 0.f);
            v.y = fmaxf(acc[c][1] + bb, 0.f);
            v.z = fmaxf(acc[c][2] + bb, 0.f);
            v.w = fmaxf(acc[c][3] + bb, 0.f);
            *(float4*)&y1[(co0 + c) * gs + m0 + m] = v;
        }
    }
}

// pool1: p1c[co][tl1*256+n] = max over r<3 of y1c[co][(2*tl1+r)*256+n]
__global__ __launch_bounds__(256) void k_pool1_c(const float* __restrict__ y1c,
                                                 float* __restrict__ p1c,
                                                 const int gs, const int p1s) {
    const int n = threadIdx.x, tl1 = blockIdx.x, co = blockIdx.y;
    const int base = co * gs + tl1 * 512 + n;
    float v = fmaxf(fmaxf(y1c[base], y1c[base + 256]), y1c[base + 512]);
    p1c[co * p1s + tl1 * 256 + n] = v;
}

// end2: 128 -> 32, relu(W*p1c + b), chunk-local cols
__global__ __launch_bounds__(256) void k_end2_c(const float* __restrict__ p1c,
                                                const float* __restrict__ w,
                                                const float* __restrict__ b,
                                                float* __restrict__ e2c,
                                                const int p1s) {
    const int mcol = blockIdx.x * 256 + threadIdx.x;
    float r[128];
#pragma unroll
    for (int i = 0; i < 128; ++i) r[i] = p1c[i * p1s + mcol];
#pragma unroll
    for (int o = 0; o < 32; ++o) {
        float acc = b[o];
        const float* wo = w + o * 128;
#pragma unroll
        for (int i = 0; i < 128; i += 4) {
            const float4 wv = *(const float4*)(wo + i);
            acc = fmaf(wv.x, r[i], acc);
            acc = fmaf(wv.y, r[i + 1], acc);
            acc = fmaf(wv.z, r[i + 2], acc);
            acc = fmaf(wv.w, r[i + 3], acc);
        }
        e2c[o * p1s + mcol] = fmaxf(acc, 0.f);
    }
}

// pool2: p2[co][(A+tl2)*256+n] = max over r<3 of e2c[co][(2*tl2+r)*256+n]
__global__ __launch_bounds__(256) void k_pool2_c(const float* __restrict__ e2c,
                                                 float* __restrict__ p2,
                                                 const int p1s, const int A) {
    const int n = threadIdx.x, tl2 = blockIdx.x, co = blockIdx.y;
    const int base = co * p1s + tl2 * 512 + n;
    float v = fmaxf(fmaxf(e2c[base], e2c[base + 256]), e2c[base + 512]);
    p2[co * 81152 + (A + tl2) * 256 + n] = v;
}

// FC1: (1024 x 10144) @ act, split-K by 8, atomic accumulate (raw, bias later)
__global__ __launch_bounds__(256) void k_fc1(const float* __restrict__ act,
                                             const float* __restrict__ w1,
                                             float* __restrict__ out) {
    const int b = threadIdx.x;
    const int o0 = blockIdx.x * 16;
    const int k0 = blockIdx.y * 1268;
    float acc[16];
#pragma unroll
    for (int oo = 0; oo < 16; ++oo) acc[oo] = 0.f;
    for (int k = k0; k < k0 + 1268; ++k) {
        const float a = act[k * 256 + b];
#pragma unroll
        for (int oo = 0; oo < 16; ++oo)
            acc[oo] = fmaf(w1[(o0 + oo) * 10144 + k], a, acc[oo]);
    }
#pragma unroll
    for (int oo = 0; oo < 16; ++oo) atomicAdd(&out[(o0 + oo) * 256 + b], acc[oo]);
}

// FC2: relu(fc1+b1) -> (256 x 1024), split-K by 4
__global__ __launch_bounds__(256) void k_fc2(const float* __restrict__ fc1raw,
                                             const float* __restrict__ fb1,
                                             const float* __restrict__ w2,
                                             float* __restrict__ out) {
    const int b = threadIdx.x;
    const int o0 = blockIdx.x * 16;
    const int k0 = blockIdx.y * 256;
    float acc[16];
#pragma unroll
    for (int oo = 0; oo < 16; ++oo) acc[oo] = 0.f;
    for (int k = k0; k < k0 + 256; ++k) {
        const float a = fmaxf(fc1raw[k * 256 + b] + fb1[k], 0.f);
#pragma unroll
        for (int oo = 0; oo < 16; ++oo)
            acc[oo] = fmaf(w2[(o0 + oo) * 1024 + k], a, acc[oo]);
    }
#pragma unroll
    for (int oo = 0; oo < 16; ++oo) atomicAdd(&out[(o0 + oo) * 256 + b], acc[oo]);
}

// FC3 + softmax + argmax -> d_out (logits[512], probs[512], yhat-as-float[256])
__global__ __launch_bounds__(256) void k_fc3(const float* __restrict__ fc2raw,
                                             const float* __restrict__ fb2,
                                             const float* __restrict__ w3,
                                             const float* __restrict__ b3,
                                             float* __restrict__ out) {
    const int b = threadIdx.x;
    float l0 = b3[0], l1 = b3[1];
    for (int k = 0; k < 256; ++k) {
        const float a = fmaxf(fc2raw[k * 256 + b] + fb2[k], 0.f);
        l0 = fmaf(w3[k], a, l0);
        l1 = fmaf(w3[256 + k], a, l1);
    }
    out[2 * b] = l0;
    out[2 * b + 1] = l1;
    const float mx = fmaxf(l0, l1);
    const float e0 = expf(l0 - mx), e1 = expf(l1 - mx);
    const float inv = 1.f / (e0 + e1);
    out[512 + 2 * b] = e0 * inv;
    out[513 + 2 * b] = e1 * inv;
    out[1024 + b] = (l1 > l0) ? 1.f : 0.f;
}

extern "C" void kernel_launch(void* const* d_in, const int* in_sizes, int n_in,
                              void* d_out, int out_size, void* d_ws, size_t ws_size,
                              hipStream_t stream) {
    const float* x        = (const float*)d_in[0];
    const float* start_w  = (const float*)d_in[1];
    const float* filter_w = (const float*)d_in[2];
    const float* gate_w   = (const float*)d_in[3];
    const float* res_w    = (const float*)d_in[4];
    const float* skip_w   = (const float*)d_in[5];
    const float* e1w      = (const float*)d_in[6];
    const float* e1b      = (const float*)d_in[7];
    const float* e2w      = (const float*)d_in[8];
    const float* e2b      = (const float*)d_in[9];
    const float* w1       = (const float*)d_in[10];
    const float* fb1      = (const float*)d_in[11];
    const float* w2       = (const float*)d_in[12];
    const float* fb2      = (const float*)d_in[13];
    const float* w3       = (const float*)d_in[14];
    const float* b3       = (const float*)d_in[15];

    float* ws = (float*)d_ws;

    // fixed-region float offsets
    const long o_h0  = 0;            // 32*327680 = 10,485,760
    const long o_p2  = 10485760;     // 32*81152  =  2,596,864
    const long o_fc1 = 13082624;     // 1024*256
    const long o_fc2 = 13344768;     // 256*256
    const long o_swt = 13410304;     // 192*256
    const long o_e1t = 13459456;     // 256*128
    const long o_G   = 13492224;

    // ---- plan chunks from ws_size ----
    long budget = (long)((double)ws_size * 0.94 / 4.0);
    int dB = 1;
    for (int d = 317; d >= 1; --d) {
        long mch = 256L * (4L * d + 3), hs = mch + 4096;
        long tot = o_G + 192L * mch + lmax_(128L * mch, 64L * hs);
        if (tot <= budget) { dB = d; break; }
    }
    int K = (317 + dB - 1) / dB;
    dB = (317 + K - 1) / K;                 // balanced chunk size
    const long MchA  = 256L * (4L * dB + 3);
    const long HSPAN = MchA + 4096;
    const long o_X   = o_G + 192L * MchA;
    const long P1S   = 256L * (2L * dB + 1);

    float* h0   = ws + o_h0;
    float* p2   = ws + o_p2;
    float* fc1r = ws + o_fc1;
    float* fc2r = ws + o_fc2;
    float* swt  = ws + o_swt;
    float* e1t  = ws + o_e1t;
    float* G    = ws + o_G;
    float* hA   = ws + o_X;
    float* hB   = ws + o_X + 32L * HSPAN;
    float* y1c  = ws + o_X;                 // aliases hA/hB (dead by then)
    float* p1c  = ws + o_G;                 // aliases G (dead after skip_end1)
    float* e2c  = ws + o_G + 128L * P1S;

    k_zero<<<1280, 256, 0, stream>>>(fc1r, 327680);   // fc1+fc2 contiguous
    k_start<<<1280, 256, 0, stream>>>(x, start_w, h0);
    k_prep<<<192, 256, 0, stream>>>(skip_w, e1w, swt, e1t);

    const int Mc[6]   = {327424, 327168, 326656, 326400, 326144, 325632};
    const int NpmP[6] = {256, 256, 512, 256, 256, 512};   // Np - padN
    const int pN[6]   = {0, 256, 512, 0, 256, 512};
    const int so_[6]  = {1792, 1536, 1024, 768, 512, 0};
    const int JloO[6] = {-1536, -1280, -768, -768, -512, 0};

    for (int c = 0; c < K; ++c) {
        const int A = c * dB;
        int B = A + dB; if (B > 317) B = 317;
        const int dBc = B - A;
        const int M0 = 1024 * A;
        int tmax = 4 * B + 3; if (tmax > 1272) tmax = 1272;
        const int Tt = tmax - 4 * A;
        const int M1 = M0 + 256 * Tt;

        int Jlo[6], Jhi[6];
        for (int q = 0; q < 6; ++q) {
            int lo = M0 + JloO[q]; if (lo < 0) lo = 0;
            int hi = M1 + so_[q];  if (hi > Mc[q]) hi = Mc[q];
            Jlo[q] = lo; Jhi[q] = hi;
        }

        for (int q = 0; q < 6; ++q) {
            const float* hin = (q == 0) ? h0 : ((q & 1) ? hA : hB);
            const int hinBase   = (q == 0) ? 0 : Jlo[q - 1];
            const int hinStride = (q == 0) ? MCAP : (int)HSPAN;
            float* hout = (q & 1) ? hB : hA;
            const int Jcnt = Jhi[q] - Jlo[q];
            k_layer_c<<<(Jcnt + 255) / 256, 256, 0, stream>>>(
                hin, hinBase, hinStride, hout, Jlo[q], (int)HSPAN,
                G + (long)q * 32 * MchA, (int)MchA,
                filter_w + q * 2048, gate_w + q * 2048, res_w + q * 1024,
                Jlo[q], Jcnt, NpmP[q], pN[q], so_[q], M0, M1, (q < 5) ? 1 : 0);
        }

        const int Mchc = 256 * Tt;
        k_skip_end1_c<<<Mchc / 32, 256, 0, stream>>>(G, swt, e1t, e1b, y1c, (int)MchA);
        const int T1c = 2 * dBc + 1;
        k_pool1_c<<<dim3(T1c, 128), 256, 0, stream>>>(y1c, p1c, (int)MchA, (int)P1S);
        k_end2_c<<<T1c, 256, 0, stream>>>(p1c, e2w, e2b, e2c, (int)P1S);
        k_pool2_c<<<dim3(dBc, 32), 256, 0, stream>>>(e2c, p2, (int)P1S, A);
    }

    k_fc1<<<dim3(64, 8), 256, 0, stream>>>(p2, w1, fc1r);
    k_fc2<<<dim3(16, 4), 256, 0, stream>>>(fc1r, fb1, w2, fc2r);
    k_fc3<<<1, 256, 0, stream>>>(fc2r, fb2, w3, b3, (float*)d_out);
}

// Round 3
// 2057.740 us; speedup vs baseline: 1.9962x; 1.9962x over previous
//
#include <hip/hip_runtime.h>
#include <math.h>

// ---------------------------------------------------------------------------
// WaveNet forward, f32 throughout (argmax output must match f32 reference).
// Flat layout for conv stages: (channel, time, batch) => buf[c][t*256+n] with
// the reference's dilate() being a pure reinterpretation (verified algebra);
// only leading zero-pads (padN cols) appear, handled at read time (a0 < 0).
//
// R2: k_layer stages weights in LDS (broadcast ds_read) instead of per-o
// uniform global loads (R1: s_load serialization, VALUBusy 6.5%); fc1/fc2
// replaced by tiled LDS GEMM (R1 k_fc1 was 851us latency-bound, VALUBusy 5.4%).
// ---------------------------------------------------------------------------

#define MCAP 327680

static inline long lmax_(long a, long b) { return a > b ? a : b; }

__global__ __launch_bounds__(256) void k_zero(float* __restrict__ p, int n) {
    int i = blockIdx.x * 256 + threadIdx.x;
    if (i < n) p[i] = 0.f;
}

// h0[o][t*256+n] = sum_i start_w[o,i] * x[n,i,t]
__global__ __launch_bounds__(256) void k_start(const float* __restrict__ x,
                                               const float* __restrict__ sw,
                                               float* __restrict__ h0) {
    int j = blockIdx.x * 256 + threadIdx.x;   // < 327680
    int t = j >> 8, n = j & 255;
    float xv[5];
#pragma unroll
    for (int i = 0; i < 5; ++i) xv[i] = x[n * 6400 + i * 1280 + t];
#pragma unroll
    for (int o = 0; o < 32; ++o) {
        float acc = 0.f;
#pragma unroll
        for (int i = 0; i < 5; ++i) acc = fmaf(sw[o * 5 + i], xv[i], acc);
        h0[o * MCAP + j] = acc;
    }
}

// transpose skip_w (6,256,32)->swt[(l*32+i)*256+ch], end1_w (128,256)->e1t[ci*128+co]
__global__ __launch_bounds__(256) void k_prep(const float* __restrict__ skw,
                                              const float* __restrict__ e1w,
                                              float* __restrict__ swt,
                                              float* __restrict__ e1t) {
    int idx = blockIdx.x * 256 + threadIdx.x;
    if (idx < 49152) {
        int k = idx >> 8, ch = idx & 255;
        int l = k >> 5, i = k & 31;
        swt[idx] = skw[l * 8192 + ch * 32 + i];
    }
    if (idx < 32768) {
        int ci = idx >> 7, co = idx & 127;
        e1t[idx] = e1w[co * 256 + ci];
    }
}

// One dilated gated layer over global j in [Jlo, Jlo+Jcnt).
// Weights staged in LDS; reads are wave-uniform broadcast ds_read_b128.
__global__ __launch_bounds__(256) void k_layer_c(
    const float* __restrict__ hin, const int hinBase, const int hinStride,
    float* __restrict__ hout, const int houtBase, const int houtStride,
    float* __restrict__ gsl, const int gStride,
    const float* __restrict__ fw, const float* __restrict__ gw,
    const float* __restrict__ rw,
    const int Jlo, const int Jcnt, const int NpmP, const int padN,
    const int so_, const int M0, const int M1, const int doRes)
{
    __shared__ float sfw[2048];
    __shared__ float sgw[2048];
    __shared__ float srw[1024];

    const int tid = threadIdx.x;
    for (int idx = tid; idx < 2048; idx += 256) {
        sfw[idx] = fw[idx];
        sgw[idx] = gw[idx];
    }
    for (int idx = tid; idx < 1024; idx += 256) srw[idx] = rw[idx];
    __syncthreads();

    const int jj = blockIdx.x * 256 + tid;
    if (jj >= Jcnt) return;
    const int j = Jlo + jj;

    float r0[32], r1[32];
    const int a0  = j - padN;
    const int a0l = (a0 < 0 ? 0 : a0) - hinBase;
    const int a1l = (j + NpmP) - hinBase;
#pragma unroll
    for (int i = 0; i < 32; ++i) {
        float v = hin[i * hinStride + a0l];
        r0[i] = (a0 < 0) ? 0.f : v;
        r1[i] = hin[i * hinStride + a1l];
    }

    float gated[32];
#pragma unroll 2
    for (int o = 0; o < 32; ++o) {
        float f = 0.f, g = 0.f;
        const float* fwo = &sfw[o * 64];
        const float* gwo = &sgw[o * 64];
#pragma unroll
        for (int i = 0; i < 32; i += 2) {
            const float4 fv = *(const float4*)(fwo + 2 * i);
            const float4 gv = *(const float4*)(gwo + 2 * i);
            f = fmaf(fv.x, r0[i], f);     f = fmaf(fv.y, r1[i], f);
            f = fmaf(fv.z, r0[i + 1], f); f = fmaf(fv.w, r1[i + 1], f);
            g = fmaf(gv.x, r0[i], g);     g = fmaf(gv.y, r1[i], g);
            g = fmaf(gv.z, r0[i + 1], g); g = fmaf(gv.w, r1[i + 1], g);
        }
        // tanh(f) = 1 - 2/(e^{2f}+1); sigmoid(g) = 1/(1+e^{-g})
        const float e2f = __expf(2.f * f);
        const float th  = 1.f - 2.f / (e2f + 1.f);
        const float sg  = 1.f / (1.f + __expf(-g));
        gated[o] = th * sg;
    }

    const int m = j - so_;
    if (m >= M0 && m < M1) {
        const int ml = m - M0;
#pragma unroll
        for (int o = 0; o < 32; ++o) gsl[o * gStride + ml] = gated[o];
    }

    if (doRes) {
        const int jl = j - houtBase;
#pragma unroll 2
        for (int o = 0; o < 32; ++o) {
            float acc = r1[o];   // residual[:,:,K-1:] == tap-1 shift
            const float* rwo = &srw[o * 32];
#pragma unroll
            for (int i = 0; i < 32; i += 4) {
                const float4 rv = *(const float4*)(rwo + i);
                acc = fmaf(rv.x, gated[i], acc);
                acc = fmaf(rv.y, gated[i + 1], acc);
                acc = fmaf(rv.z, gated[i + 2], acc);
                acc = fmaf(rv.w, gated[i + 3], acc);
            }
            hout[o * houtStride + jl] = acc;
        }
    }
}

// Fused: skip (K=192 over 6 gated tails) -> relu -> end1 (K=256) + bias -> relu -> y1
__global__ __launch_bounds__(256, 2) void k_skip_end1_c(
    const float* __restrict__ g, const float* __restrict__ swt,
    const float* __restrict__ e1t, const float* __restrict__ b1,
    float* __restrict__ y1, const int gs)
{
    __shared__ float gt[192 * 32];   // [k][m]
    __shared__ float st[256 * 36];   // relu(skip) [ch][m], padded stride 36

    const int tid = threadIdx.x;
    const int m0 = blockIdx.x * 32;

    for (int idx = tid; idx < 192 * 32; idx += 256) {
        int k = idx >> 5, m = idx & 31;
        gt[idx] = g[(k >> 5) * (32 * gs) + (k & 31) * gs + m0 + m];
    }
    __syncthreads();

    const int m = (tid & 7) * 4;
    {
        const int ch0 = (tid >> 3) * 8;
        float acc[8][4];
#pragma unroll
        for (int c = 0; c < 8; ++c)
#pragma unroll
            for (int q = 0; q < 4; ++q) acc[c][q] = 0.f;

        for (int k = 0; k < 192; ++k) {
            const float4 gv = *(const float4*)&gt[k * 32 + m];
            const float4 w0 = *(const float4*)&swt[k * 256 + ch0];
            const float4 w1 = *(const float4*)&swt[k * 256 + ch0 + 4];
            const float wv[8] = {w0.x, w0.y, w0.z, w0.w, w1.x, w1.y, w1.z, w1.w};
#pragma unroll
            for (int c = 0; c < 8; ++c) {
                acc[c][0] = fmaf(wv[c], gv.x, acc[c][0]);
                acc[c][1] = fmaf(wv[c], gv.y, acc[c][1]);
                acc[c][2] = fmaf(wv[c], gv.z, acc[c][2]);
                acc[c][3] = fmaf(wv[c], gv.w, acc[c][3]);
            }
        }
#pragma unroll
        for (int c = 0; c < 8; ++c) {
            float4 v;
            v.x = fmaxf(acc[c][0], 0.f);
            v.y = fmaxf(acc[c][1], 0.f);
            v.z = fmaxf(acc[c][2], 0.f);
            v.w = fmaxf(acc[c][3], 0.f);
            *(float4*)&st[(ch0 + c) * 36 + m] = v;
        }
    }
    __syncthreads();
    {
        const int co0 = (tid >> 3) * 4;
        float acc[4][4];
#pragma unroll
        for (int c = 0; c < 4; ++c)
#pragma unroll
            for (int q = 0; q < 4; ++q) acc[c][q] = 0.f;

        for (int ci = 0; ci < 256; ++ci) {
            const float4 sv = *(const float4*)&st[ci * 36 + m];
            const float4 wv = *(const float4*)&e1t[ci * 128 + co0];
            const float wa[4] = {wv.x, wv.y, wv.z, wv.w};
#pragma unroll
            for (int c = 0; c < 4; ++c) {
                acc[c][0] = fmaf(wa[c], sv.x, acc[c][0]);
                acc[c][1] = fmaf(wa[c], sv.y, acc[c][1]);
                acc[c][2] = fmaf(wa[c], sv.z, acc[c][2]);
                acc[c][3] = fmaf(wa[c], sv.w, acc[c][3]);
            }
        }
#pragma unroll
        for (int c = 0; c < 4; ++c) {
            const float bb = b1[co0 + c];
            float4 v;
            v.x = fmaxf(acc[c][0] + bb, 0.f);
            v.y = fmaxf(acc[c][1] + bb, 0.f);
            v.z = fmaxf(acc[c][2] + bb, 0.f);
            v.w = fmaxf(acc[c][3] + bb, 0.f);
            *(float4*)&y1[(co0 + c) * gs + m0 + m] = v;
        }
    }
}

__global__ __launch_bounds__(256) void k_pool1_c(const float* __restrict__ y1c,
                                                 float* __restrict__ p1c,
                                                 const int gs, const int p1s) {
    const int n = threadIdx.x, tl1 = blockIdx.x, co = blockIdx.y;
    const int base = co * gs + tl1 * 512 + n;
    float v = fmaxf(fmaxf(y1c[base], y1c[base + 256]), y1c[base + 512]);
    p1c[co * p1s + tl1 * 256 + n] = v;
}

__global__ __launch_bounds__(256) void k_end2_c(const float* __restrict__ p1c,
                                                const float* __restrict__ w,
                                                const float* __restrict__ b,
                                                float* __restrict__ e2c,
                                                const int p1s) {
    const int mcol = blockIdx.x * 256 + threadIdx.x;
    float r[128];
#pragma unroll
    for (int i = 0; i < 128; ++i) r[i] = p1c[i * p1s + mcol];
#pragma unroll
    for (int o = 0; o < 32; ++o) {
        float acc = b[o];
        const float* wo = w + o * 128;
#pragma unroll
        for (int i = 0; i < 128; i += 4) {
            const float4 wv = *(const float4*)(wo + i);
            acc = fmaf(wv.x, r[i], acc);
            acc = fmaf(wv.y, r[i + 1], acc);
            acc = fmaf(wv.z, r[i + 2], acc);
            acc = fmaf(wv.w, r[i + 3], acc);
        }
        e2c[o * p1s + mcol] = fmaxf(acc, 0.f);
    }
}

__global__ __launch_bounds__(256) void k_pool2_c(const float* __restrict__ e2c,
                                                 float* __restrict__ p2,
                                                 const int p1s, const int A) {
    const int n = threadIdx.x, tl2 = blockIdx.x, co = blockIdx.y;
    const int base = co * p1s + tl2 * 512 + n;
    float v = fmaxf(fmaxf(e2c[base], e2c[base + 256]), e2c[base + 512]);
    p2[co * 81152 + (A + tl2) * 256 + n] = v;
}

// Tiled GEMM: C[M x 256] += A[M x Ktot](row-major) * B[Ktot x 256](row-major)
// grid (M/64, 4, S); block 256; each z-slice handles k-range [z*KC, z*KC+KC).
// 64x64 tile, 32-k LDS chunks, 4x4 register tile, atomic epilogue (C pre-zeroed).
__global__ __launch_bounds__(256) void k_gemm64(const float* __restrict__ A,
                                                const float* __restrict__ B,
                                                float* __restrict__ C,
                                                const int Ktot, const int KC) {
    __shared__ float sA[32 * 68];   // [kk][o]
    __shared__ float sB[32 * 68];   // [kk][b]

    const int tid = threadIdx.x;
    const int o0 = blockIdx.x * 64;
    const int b0 = blockIdx.y * 64;
    const int k0 = blockIdx.z * KC;

    float acc[4][4];
#pragma unroll
    for (int i = 0; i < 4; ++i)
#pragma unroll
        for (int jq = 0; jq < 4; ++jq) acc[i][jq] = 0.f;

    const int ao  = tid >> 2;          // 0..63
    const int ak8 = (tid & 3) * 8;     // 0,8,16,24
    const int bk  = tid >> 3;          // 0..31
    const int bb8 = (tid & 7) * 8;     // 0..56
    const int to4 = (tid & 15) * 4;
    const int tb4 = (tid >> 4) * 4;

    for (int kc = 0; kc < KC; kc += 32) {
        const int kcLen = (KC - kc < 32) ? (KC - kc) : 32;
        // stage A (64o x 32k, transposed to [kk][o])
        const float* ap = A + (size_t)(o0 + ao) * Ktot + k0 + kc + ak8;
#pragma unroll
        for (int i = 0; i < 8; ++i) {
            float v = (ak8 + i < kcLen) ? ap[i] : 0.f;
            sA[(ak8 + i) * 68 + ao] = v;
        }
        // stage B (32k x 64b)
        if (bk < kcLen) {
            const float* bp = B + (size_t)(k0 + kc + bk) * 256 + b0 + bb8;
            const float4 v0 = *(const float4*)bp;
            const float4 v1 = *(const float4*)(bp + 4);
            *(float4*)&sB[bk * 68 + bb8] = v0;
            *(float4*)&sB[bk * 68 + bb8 + 4] = v1;
        } else {
            float4 z; z.x = z.y = z.z = z.w = 0.f;
            *(float4*)&sB[bk * 68 + bb8] = z;
            *(float4*)&sB[bk * 68 + bb8 + 4] = z;
        }
        __syncthreads();

#pragma unroll 8
        for (int kk = 0; kk < 32; ++kk) {
            const float4 av = *(const float4*)&sA[kk * 68 + to4];
            const float4 bv = *(const float4*)&sB[kk * 68 + tb4];
            const float aa[4] = {av.x, av.y, av.z, av.w};
#pragma unroll
            for (int i = 0; i < 4; ++i) {
                acc[i][0] = fmaf(aa[i], bv.x, acc[i][0]);
                acc[i][1] = fmaf(aa[i], bv.y, acc[i][1]);
                acc[i][2] = fmaf(aa[i], bv.z, acc[i][2]);
                acc[i][3] = fmaf(aa[i], bv.w, acc[i][3]);
            }
        }
        __syncthreads();
    }

#pragma unroll
    for (int i = 0; i < 4; ++i)
#pragma unroll
        for (int jq = 0; jq < 4; ++jq)
            atomicAdd(&C[(size_t)(o0 + to4 + i) * 256 + b0 + tb4 + jq], acc[i][jq]);
}

// act[k][b] = relu(raw[k][b] + bias[k])
__global__ __launch_bounds__(256) void k_actbias(const float* __restrict__ raw,
                                                 const float* __restrict__ bias,
                                                 float* __restrict__ out) {
    const int k = blockIdx.x, b = threadIdx.x;
    out[k * 256 + b] = fmaxf(raw[k * 256 + b] + bias[k], 0.f);
}

// FC3 + softmax + argmax -> d_out (logits[512], probs[512], yhat-as-float[256])
__global__ __launch_bounds__(256) void k_fc3(const float* __restrict__ fc2raw,
                                             const float* __restrict__ fb2,
                                             const float* __restrict__ w3,
                                             const float* __restrict__ b3,
                                             float* __restrict__ out) {
    const int b = threadIdx.x;
    float l0 = b3[0], l1 = b3[1];
    for (int k = 0; k < 256; ++k) {
        const float a = fmaxf(fc2raw[k * 256 + b] + fb2[k], 0.f);
        l0 = fmaf(w3[k], a, l0);
        l1 = fmaf(w3[256 + k], a, l1);
    }
    out[2 * b] = l0;
    out[2 * b + 1] = l1;
    const float mx = fmaxf(l0, l1);
    const float e0 = expf(l0 - mx), e1 = expf(l1 - mx);
    const float inv = 1.f / (e0 + e1);
    out[512 + 2 * b] = e0 * inv;
    out[513 + 2 * b] = e1 * inv;
    out[1024 + b] = (l1 > l0) ? 1.f : 0.f;
}

extern "C" void kernel_launch(void* const* d_in, const int* in_sizes, int n_in,
                              void* d_out, int out_size, void* d_ws, size_t ws_size,
                              hipStream_t stream) {
    const float* x        = (const float*)d_in[0];
    const float* start_w  = (const float*)d_in[1];
    const float* filter_w = (const float*)d_in[2];
    const float* gate_w   = (const float*)d_in[3];
    const float* res_w    = (const float*)d_in[4];
    const float* skip_w   = (const float*)d_in[5];
    const float* e1w      = (const float*)d_in[6];
    const float* e1b      = (const float*)d_in[7];
    const float* e2w      = (const float*)d_in[8];
    const float* e2b      = (const float*)d_in[9];
    const float* w1       = (const float*)d_in[10];
    const float* fb1      = (const float*)d_in[11];
    const float* w2       = (const float*)d_in[12];
    const float* fb2      = (const float*)d_in[13];
    const float* w3       = (const float*)d_in[14];
    const float* b3       = (const float*)d_in[15];

    float* ws = (float*)d_ws;

    // fixed-region float offsets
    const long o_h0   = 0;            // 32*327680 = 10,485,760
    const long o_p2   = 10485760;     // 32*81152  =  2,596,864
    const long o_fc1  = 13082624;     // 1024*256
    const long o_fc2  = 13344768;     // 256*256
    const long o_swt  = 13410304;     // 192*256
    const long o_e1t  = 13459456;     // 256*128
    const long o_act1 = 13492224;     // 1024*256
    const long o_G    = 13754368;

    // ---- plan chunks from ws_size ----
    long budget = (long)((double)ws_size * 0.94 / 4.0);
    int dB = 1;
    for (int d = 317; d >= 1; --d) {
        long mch = 256L * (4L * d + 3), hs = mch + 4096;
        long tot = o_G + 192L * mch + lmax_(128L * mch, 64L * hs);
        if (tot <= budget) { dB = d; break; }
    }
    int K = (317 + dB - 1) / dB;
    dB = (317 + K - 1) / K;                 // balanced chunk size
    const long MchA  = 256L * (4L * dB + 3);
    const long HSPAN = MchA + 4096;
    const long o_X   = o_G + 192L * MchA;
    const long P1S   = 256L * (2L * dB + 1);

    float* h0   = ws + o_h0;
    float* p2   = ws + o_p2;
    float* fc1r = ws + o_fc1;
    float* fc2r = ws + o_fc2;
    float* swt  = ws + o_swt;
    float* e1t  = ws + o_e1t;
    float* act1 = ws + o_act1;
    float* G    = ws + o_G;
    float* hA   = ws + o_X;
    float* hB   = ws + o_X + 32L * HSPAN;
    float* y1c  = ws + o_X;                 // aliases hA/hB (dead by then)
    float* p1c  = ws + o_G;                 // aliases G (dead after skip_end1)
    float* e2c  = ws + o_G + 128L * P1S;

    k_zero<<<1280, 256, 0, stream>>>(fc1r, 327680);   // fc1+fc2 contiguous
    k_start<<<1280, 256, 0, stream>>>(x, start_w, h0);
    k_prep<<<192, 256, 0, stream>>>(skip_w, e1w, swt, e1t);

    const int Mc[6]   = {327424, 327168, 326656, 326400, 326144, 325632};
    const int NpmP[6] = {256, 256, 512, 256, 256, 512};   // Np - padN
    const int pN[6]   = {0, 256, 512, 0, 256, 512};
    const int so_[6]  = {1792, 1536, 1024, 768, 512, 0};
    const int JloO[6] = {-1536, -1280, -768, -768, -512, 0};

    for (int c = 0; c < K; ++c) {
        const int A = c * dB;
        int B = A + dB; if (B > 317) B = 317;
        const int dBc = B - A;
        const int M0 = 1024 * A;
        int tmax = 4 * B + 3; if (tmax > 1272) tmax = 1272;
        const int Tt = tmax - 4 * A;
        const int M1 = M0 + 256 * Tt;

        int Jlo[6], Jhi[6];
        for (int q = 0; q < 6; ++q) {
            int lo = M0 + JloO[q]; if (lo < 0) lo = 0;
            int hi = M1 + so_[q];  if (hi > Mc[q]) hi = Mc[q];
            Jlo[q] = lo; Jhi[q] = hi;
        }

        for (int q = 0; q < 6; ++q) {
            const float* hin = (q == 0) ? h0 : ((q & 1) ? hA : hB);
            const int hinBase   = (q == 0) ? 0 : Jlo[q - 1];
            const int hinStride = (q == 0) ? MCAP : (int)HSPAN;
            float* hout = (q & 1) ? hB : hA;
            const int Jcnt = Jhi[q] - Jlo[q];
            k_layer_c<<<(Jcnt + 255) / 256, 256, 0, stream>>>(
                hin, hinBase, hinStride, hout, Jlo[q], (int)HSPAN,
                G + (long)q * 32 * MchA, (int)MchA,
                filter_w + q * 2048, gate_w + q * 2048, res_w + q * 1024,
                Jlo[q], Jcnt, NpmP[q], pN[q], so_[q], M0, M1, (q < 5) ? 1 : 0);
        }

        const int Mchc = 256 * Tt;
        k_skip_end1_c<<<Mchc / 32, 256, 0, stream>>>(G, swt, e1t, e1b, y1c, (int)MchA);
        const int T1c = 2 * dBc + 1;
        k_pool1_c<<<dim3(T1c, 128), 256, 0, stream>>>(y1c, p1c, (int)MchA, (int)P1S);
        k_end2_c<<<T1c, 256, 0, stream>>>(p1c, e2w, e2b, e2c, (int)P1S);
        k_pool2_c<<<dim3(dBc, 32), 256, 0, stream>>>(e2c, p2, (int)P1S, A);
    }

    // FC1: 1024x10144 @ p2 (10144x256), split-K 8
    k_gemm64<<<dim3(16, 4, 8), 256, 0, stream>>>(w1, p2, fc1r, 10144, 1268);
    k_actbias<<<1024, 256, 0, stream>>>(fc1r, fb1, act1);
    // FC2: 256x1024 @ act1 (1024x256), split-K 4
    k_gemm64<<<dim3(4, 4, 4), 256, 0, stream>>>(w2, act1, fc2r, 1024, 256);
    k_fc3<<<1, 256, 0, stream>>>(fc2r, fb2, w3, b3, (float*)d_out);
}

// Round 4
// 1983.056 us; speedup vs baseline: 2.0714x; 1.0377x over previous
//
#include <hip/hip_runtime.h>
#include <math.h>

// ---------------------------------------------------------------------------
// WaveNet forward, f32 throughout (argmax output must match f32 reference).
// Flat layout for conv stages: (channel, time, batch) => buf[c][t*256+n] with
// the reference's dilate() being a pure reinterpretation (verified algebra);
// only leading zero-pads (padN cols) appear, handled at stage time.
//
// R3->R4: k_layer_c rewritten as LDS-activation-tiled GEMM (the structure that
// measured 100% of f32 issue peak in k_skip_end1_c). R2/R3 version made every
// thread re-read all 2048 weights from LDS per column (latency-serialized
// ds_read->FMA, ~10x above issue bound). All tile boundaries are multiples of
// 64 (verified: Mc/Jlo/Jhi/padN/so_/M0/M1 all = 0 mod 64), so no column guards.
// ---------------------------------------------------------------------------

#define MCAP 327680

static inline long lmax_(long a, long b) { return a > b ? a : b; }

__global__ __launch_bounds__(256) void k_zero(float* __restrict__ p, int n) {
    int i = blockIdx.x * 256 + threadIdx.x;
    if (i < n) p[i] = 0.f;
}

// h0[o][t*256+n] = sum_i start_w[o,i] * x[n,i,t]
__global__ __launch_bounds__(256) void k_start(const float* __restrict__ x,
                                               const float* __restrict__ sw,
                                               float* __restrict__ h0) {
    int j = blockIdx.x * 256 + threadIdx.x;   // < 327680
    int t = j >> 8, n = j & 255;
    float xv[5];
#pragma unroll
    for (int i = 0; i < 5; ++i) xv[i] = x[n * 6400 + i * 1280 + t];
#pragma unroll
    for (int o = 0; o < 32; ++o) {
        float acc = 0.f;
#pragma unroll
        for (int i = 0; i < 5; ++i) acc = fmaf(sw[o * 5 + i], xv[i], acc);
        h0[o * MCAP + j] = acc;
    }
}

// Prepack weights:
//  swt[(l*32+i)*256+ch] = skip_w[l][ch][i]
//  e1t[ci*128+co]       = end1_w[co][ci]
//  wfgp[l][k*64+2o+fg]  : k<32 -> w[o][k][tap0], k>=32 -> w[o][k-32][tap1]; fg=0 filter,1 gate
//  rwt[l][i*32+o]       = res_w[l][o][i]
__global__ __launch_bounds__(256) void k_prep(const float* __restrict__ skw,
                                              const float* __restrict__ e1w,
                                              const float* __restrict__ fw,
                                              const float* __restrict__ gw,
                                              const float* __restrict__ rw,
                                              float* __restrict__ swt,
                                              float* __restrict__ e1t,
                                              float* __restrict__ wfgp,
                                              float* __restrict__ rwt) {
    int idx = blockIdx.x * 256 + threadIdx.x;
    if (idx < 49152) {
        int k = idx >> 8, ch = idx & 255;
        int l = k >> 5, i = k & 31;
        swt[idx] = skw[l * 8192 + ch * 32 + i];
    }
    if (idx < 32768) {
        int ci = idx >> 7, co = idx & 127;
        e1t[idx] = e1w[co * 256 + ci];
    }
    if (idx < 24576) {
        int l = idx >> 12, r = idx & 4095;
        int k = r >> 6, t = r & 63, o = t >> 1, fg = t & 1;
        const float* src = fg ? gw : fw;
        int i = (k < 32) ? k : (k - 32);
        int tap = (k < 32) ? 0 : 1;
        wfgp[idx] = src[l * 2048 + o * 64 + i * 2 + tap];
    }
    if (idx < 6144) {
        int l = idx >> 10, r = idx & 1023;
        int i = r >> 5, o = r & 31;
        rwt[idx] = rw[l * 1024 + o * 32 + i];
    }
}

// One dilated gated layer over global j in [Jlo, Jlo+Jcnt), Jcnt % 64 == 0.
// 64-col tile/block. LDS: rt[64k][68] acts (rows 0-31 tap0, 32-63 tap1),
// gt[32][68] gated. Thread = channel tc x 8 cols tm.
__global__ __launch_bounds__(256) void k_layer_c(
    const float* __restrict__ hin, const int hinBase, const int hinStride,
    float* __restrict__ hout, const int houtBase, const int houtStride,
    float* __restrict__ gsl, const int gStride,
    const float* __restrict__ wfgp, const float* __restrict__ rwt,
    const int Jlo, const int NpmP, const int padN,
    const int so_, const int M0, const int M1, const int doRes)
{
    __shared__ float rt[64 * 68];
    __shared__ float gt[32 * 68];

    const int tid = threadIdx.x;
    const int j0 = Jlo + blockIdx.x * 64;

    // ---- stage activation tile
    {
        const int r  = tid >> 2;          // 0..63
        const int c0 = (tid & 3) * 16;    // 0,16,32,48
        const int ch = r & 31;
        if (r < 32 && j0 < padN) {        // tile-uniform zero-pad region
            float4 z; z.x = z.y = z.z = z.w = 0.f;
#pragma unroll
            for (int q = 0; q < 4; ++q) *(float4*)&rt[r * 68 + c0 + 4 * q] = z;
        } else {
            const int off = (r < 32) ? (j0 - padN) : (j0 + NpmP);
            const float* p = hin + (size_t)ch * hinStride + (off - hinBase) + c0;
#pragma unroll
            for (int q = 0; q < 4; ++q)
                *(float4*)&rt[r * 68 + c0 + 4 * q] = *(const float4*)(p + 4 * q);
        }
    }
    __syncthreads();

    const int tc = tid >> 3;          // channel 0..31
    const int tm = (tid & 7) * 8;     // col base 0..56

    // ---- stage A: f,g for channel tc over 8 cols, K=64
    float fa[8], ga[8];
#pragma unroll
    for (int q = 0; q < 8; ++q) { fa[q] = 0.f; ga[q] = 0.f; }

#pragma unroll 4
    for (int k = 0; k < 64; ++k) {
        const float4 a0 = *(const float4*)&rt[k * 68 + tm];
        const float4 a1 = *(const float4*)&rt[k * 68 + tm + 4];
        const float2 wv = *(const float2*)&wfgp[k * 64 + 2 * tc];
        fa[0] = fmaf(wv.x, a0.x, fa[0]); ga[0] = fmaf(wv.y, a0.x, ga[0]);
        fa[1] = fmaf(wv.x, a0.y, fa[1]); ga[1] = fmaf(wv.y, a0.y, ga[1]);
        fa[2] = fmaf(wv.x, a0.z, fa[2]); ga[2] = fmaf(wv.y, a0.z, ga[2]);
        fa[3] = fmaf(wv.x, a0.w, fa[3]); ga[3] = fmaf(wv.y, a0.w, ga[3]);
        fa[4] = fmaf(wv.x, a1.x, fa[4]); ga[4] = fmaf(wv.y, a1.x, ga[4]);
        fa[5] = fmaf(wv.x, a1.y, fa[5]); ga[5] = fmaf(wv.y, a1.y, ga[5]);
        fa[6] = fmaf(wv.x, a1.z, fa[6]); ga[6] = fmaf(wv.y, a1.z, ga[6]);
        fa[7] = fmaf(wv.x, a1.w, fa[7]); ga[7] = fmaf(wv.y, a1.w, ga[7]);
    }

    float gd[8];
#pragma unroll
    for (int q = 0; q < 8; ++q) {
        const float e2f = __expf(2.f * fa[q]);
        const float th  = 1.f - 2.f / (e2f + 1.f);
        const float sg  = 1.f / (1.f + __expf(-ga[q]));
        gd[q] = th * sg;
    }

    float4 g0, g1;
    g0.x = gd[0]; g0.y = gd[1]; g0.z = gd[2]; g0.w = gd[3];
    g1.x = gd[4]; g1.y = gd[5]; g1.z = gd[6]; g1.w = gd[7];

    // gated tail -> gsl (tile-uniform range test)
    const int m0c = j0 - so_;
    if (m0c >= M0 && m0c < M1) {
        float* gp = gsl + (size_t)tc * gStride + (m0c - M0) + tm;
        *(float4*)gp = g0;
        *(float4*)(gp + 4) = g1;
    }

    if (doRes) {
        *(float4*)&gt[tc * 68 + tm] = g0;
        *(float4*)&gt[tc * 68 + tm + 4] = g1;
        __syncthreads();

        // ---- stage B: h_next[tc] = res_w . gated + r1[tc], K=32
        const float4 rv0 = *(const float4*)&rt[(32 + tc) * 68 + tm];
        const float4 rv1 = *(const float4*)&rt[(32 + tc) * 68 + tm + 4];
        float ac[8] = {rv0.x, rv0.y, rv0.z, rv0.w, rv1.x, rv1.y, rv1.z, rv1.w};

#pragma unroll 4
        for (int k = 0; k < 32; ++k) {
            const float4 b0 = *(const float4*)&gt[k * 68 + tm];
            const float4 b1 = *(const float4*)&gt[k * 68 + tm + 4];
            const float w = rwt[k * 32 + tc];
            ac[0] = fmaf(w, b0.x, ac[0]);
            ac[1] = fmaf(w, b0.y, ac[1]);
            ac[2] = fmaf(w, b0.z, ac[2]);
            ac[3] = fmaf(w, b0.w, ac[3]);
            ac[4] = fmaf(w, b1.x, ac[4]);
            ac[5] = fmaf(w, b1.y, ac[5]);
            ac[6] = fmaf(w, b1.z, ac[6]);
            ac[7] = fmaf(w, b1.w, ac[7]);
        }

        float* hp = hout + (size_t)tc * houtStride + (j0 - houtBase) + tm;
        float4 o0, o1;
        o0.x = ac[0]; o0.y = ac[1]; o0.z = ac[2]; o0.w = ac[3];
        o1.x = ac[4]; o1.y = ac[5]; o1.z = ac[6]; o1.w = ac[7];
        *(float4*)hp = o0;
        *(float4*)(hp + 4) = o1;
    }
}

// Fused: skip (K=192 over 6 gated tails) -> relu -> end1 (K=256) + bias -> relu -> y1
__global__ __launch_bounds__(256, 2) void k_skip_end1_c(
    const float* __restrict__ g, const float* __restrict__ swt,
    const float* __restrict__ e1t, const float* __restrict__ b1,
    float* __restrict__ y1, const int gs)
{
    __shared__ float gt[192 * 32];   // [k][m]
    __shared__ float st[256 * 36];   // relu(skip) [ch][m], padded stride 36

    const int tid = threadIdx.x;
    const int m0 = blockIdx.x * 32;

    for (int idx = tid; idx < 192 * 32; idx += 256) {
        int k = idx >> 5, m = idx & 31;
        gt[idx] = g[(k >> 5) * (32 * gs) + (k & 31) * gs + m0 + m];
    }
    __syncthreads();

    const int m = (tid & 7) * 4;
    {
        const int ch0 = (tid >> 3) * 8;
        float acc[8][4];
#pragma unroll
        for (int c = 0; c < 8; ++c)
#pragma unroll
            for (int q = 0; q < 4; ++q) acc[c][q] = 0.f;

        for (int k = 0; k < 192; ++k) {
            const float4 gv = *(const float4*)&gt[k * 32 + m];
            const float4 w0 = *(const float4*)&swt[k * 256 + ch0];
            const float4 w1 = *(const float4*)&swt[k * 256 + ch0 + 4];
            const float wv[8] = {w0.x, w0.y, w0.z, w0.w, w1.x, w1.y, w1.z, w1.w};
#pragma unroll
            for (int c = 0; c < 8; ++c) {
                acc[c][0] = fmaf(wv[c], gv.x, acc[c][0]);
                acc[c][1] = fmaf(wv[c], gv.y, acc[c][1]);
                acc[c][2] = fmaf(wv[c], gv.z, acc[c][2]);
                acc[c][3] = fmaf(wv[c], gv.w, acc[c][3]);
            }
        }
#pragma unroll
        for (int c = 0; c < 8; ++c) {
            float4 v;
            v.x = fmaxf(acc[c][0], 0.f);
            v.y = fmaxf(acc[c][1], 0.f);
            v.z = fmaxf(acc[c][2], 0.f);
            v.w = fmaxf(acc[c][3], 0.f);
            *(float4*)&st[(ch0 + c) * 36 + m] = v;
        }
    }
    __syncthreads();
    {
        const int co0 = (tid >> 3) * 4;
        float acc[4][4];
#pragma unroll
        for (int c = 0; c < 4; ++c)
#pragma unroll
            for (int q = 0; q < 4; ++q) acc[c][q] = 0.f;

        for (int ci = 0; ci < 256; ++ci) {
            const float4 sv = *(const float4*)&st[ci * 36 + m];
            const float4 wv = *(const float4*)&e1t[ci * 128 + co0];
            const float wa[4] = {wv.x, wv.y, wv.z, wv.w};
#pragma unroll
            for (int c = 0; c < 4; ++c) {
                acc[c][0] = fmaf(wa[c], sv.x, acc[c][0]);
                acc[c][1] = fmaf(wa[c], sv.y, acc[c][1]);
                acc[c][2] = fmaf(wa[c], sv.z, acc[c][2]);
                acc[c][3] = fmaf(wa[c], sv.w, acc[c][3]);
            }
        }
#pragma unroll
        for (int c = 0; c < 4; ++c) {
            const float bb = b1[co0 + c];
            float4 v;
            v.x = fmaxf(acc[c][0] + bb, 0.f);
            v.y = fmaxf(acc[c][1] + bb, 0.f);
            v.z = fmaxf(acc[c][2] + bb, 0.f);
            v.w = fmaxf(acc[c][3] + bb, 0.f);
            *(float4*)&y1[(co0 + c) * gs + m0 + m] = v;
        }
    }
}

__global__ __launch_bounds__(256) void k_pool1_c(const float* __restrict__ y1c,
                                                 float* __restrict__ p1c,
                                                 const int gs, const int p1s) {
    const int n = threadIdx.x, tl1 = blockIdx.x, co = blockIdx.y;
    const int base = co * gs + tl1 * 512 + n;
    float v = fmaxf(fmaxf(y1c[base], y1c[base + 256]), y1c[base + 512]);
    p1c[co * p1s + tl1 * 256 + n] = v;
}

__global__ __launch_bounds__(256) void k_end2_c(const float* __restrict__ p1c,
                                                const float* __restrict__ w,
                                                const float* __restrict__ b,
                                                float* __restrict__ e2c,
                                                const int p1s) {
    const int mcol = blockIdx.x * 256 + threadIdx.x;
    float r[128];
#pragma unroll
    for (int i = 0; i < 128; ++i) r[i] = p1c[i * p1s + mcol];
#pragma unroll
    for (int o = 0; o < 32; ++o) {
        float acc = b[o];
        const float* wo = w + o * 128;
#pragma unroll
        for (int i = 0; i < 128; i += 4) {
            const float4 wv = *(const float4*)(wo + i);
            acc = fmaf(wv.x, r[i], acc);
            acc = fmaf(wv.y, r[i + 1], acc);
            acc = fmaf(wv.z, r[i + 2], acc);
            acc = fmaf(wv.w, r[i + 3], acc);
        }
        e2c[o * p1s + mcol] = fmaxf(acc, 0.f);
    }
}

__global__ __launch_bounds__(256) void k_pool2_c(const float* __restrict__ e2c,
                                                 float* __restrict__ p2,
                                                 const int p1s, const int A) {
    const int n = threadIdx.x, tl2 = blockIdx.x, co = blockIdx.y;
    const int base = co * p1s + tl2 * 512 + n;
    float v = fmaxf(fmaxf(e2c[base], e2c[base + 256]), e2c[base + 512]);
    p2[co * 81152 + (A + tl2) * 256 + n] = v;
}

// Tiled GEMM: C[M x 256] += A[M x Ktot](row-major) * B[Ktot x 256](row-major)
__global__ __launch_bounds__(256) void k_gemm64(const float* __restrict__ A,
                                                const float* __restrict__ B,
                                                float* __restrict__ C,
                                                const int Ktot, const int KC) {
    __shared__ float sA[32 * 68];   // [kk][o]
    __shared__ float sB[32 * 68];   // [kk][b]

    const int tid = threadIdx.x;
    const int o0 = blockIdx.x * 64;
    const int b0 = blockIdx.y * 64;
    const int k0 = blockIdx.z * KC;

    float acc[4][4];
#pragma unroll
    for (int i = 0; i < 4; ++i)
#pragma unroll
        for (int jq = 0; jq < 4; ++jq) acc[i][jq] = 0.f;

    const int ao  = tid >> 2;          // 0..63
    const int ak8 = (tid & 3) * 8;     // 0,8,16,24
    const int bk  = tid >> 3;          // 0..31
    const int bb8 = (tid & 7) * 8;     // 0..56
    const int to4 = (tid & 15) * 4;
    const int tb4 = (tid >> 4) * 4;

    for (int kc = 0; kc < KC; kc += 32) {
        const int kcLen = (KC - kc < 32) ? (KC - kc) : 32;
        const float* ap = A + (size_t)(o0 + ao) * Ktot + k0 + kc + ak8;
#pragma unroll
        for (int i = 0; i < 8; ++i) {
            float v = (ak8 + i < kcLen) ? ap[i] : 0.f;
            sA[(ak8 + i) * 68 + ao] = v;
        }
        if (bk < kcLen) {
            const float* bp = B + (size_t)(k0 + kc + bk) * 256 + b0 + bb8;
            const float4 v0 = *(const float4*)bp;
            const float4 v1 = *(const float4*)(bp + 4);
            *(float4*)&sB[bk * 68 + bb8] = v0;
            *(float4*)&sB[bk * 68 + bb8 + 4] = v1;
        } else {
            float4 z; z.x = z.y = z.z = z.w = 0.f;
            *(float4*)&sB[bk * 68 + bb8] = z;
            *(float4*)&sB[bk * 68 + bb8 + 4] = z;
        }
        __syncthreads();

#pragma unroll 8
        for (int kk = 0; kk < 32; ++kk) {
            const float4 av = *(const float4*)&sA[kk * 68 + to4];
            const float4 bv = *(const float4*)&sB[kk * 68 + tb4];
            const float aa[4] = {av.x, av.y, av.z, av.w};
#pragma unroll
            for (int i = 0; i < 4; ++i) {
                acc[i][0] = fmaf(aa[i], bv.x, acc[i][0]);
                acc[i][1] = fmaf(aa[i], bv.y, acc[i][1]);
                acc[i][2] = fmaf(aa[i], bv.z, acc[i][2]);
                acc[i][3] = fmaf(aa[i], bv.w, acc[i][3]);
            }
        }
        __syncthreads();
    }

#pragma unroll
    for (int i = 0; i < 4; ++i)
#pragma unroll
        for (int jq = 0; jq < 4; ++jq)
            atomicAdd(&C[(size_t)(o0 + to4 + i) * 256 + b0 + tb4 + jq], acc[i][jq]);
}

__global__ __launch_bounds__(256) void k_actbias(const float* __restrict__ raw,
                                                 const float* __restrict__ bias,
                                                 float* __restrict__ out) {
    const int k = blockIdx.x, b = threadIdx.x;
    out[k * 256 + b] = fmaxf(raw[k * 256 + b] + bias[k], 0.f);
}

__global__ __launch_bounds__(256) void k_fc3(const float* __restrict__ fc2raw,
                                             const float* __restrict__ fb2,
                                             const float* __restrict__ w3,
                                             const float* __restrict__ b3,
                                             float* __restrict__ out) {
    const int b = threadIdx.x;
    float l0 = b3[0], l1 = b3[1];
    for (int k = 0; k < 256; ++k) {
        const float a = fmaxf(fc2raw[k * 256 + b] + fb2[k], 0.f);
        l0 = fmaf(w3[k], a, l0);
        l1 = fmaf(w3[256 + k], a, l1);
    }
    out[2 * b] = l0;
    out[2 * b + 1] = l1;
    const float mx = fmaxf(l0, l1);
    const float e0 = expf(l0 - mx), e1 = expf(l1 - mx);
    const float inv = 1.f / (e0 + e1);
    out[512 + 2 * b] = e0 * inv;
    out[513 + 2 * b] = e1 * inv;
    out[1024 + b] = (l1 > l0) ? 1.f : 0.f;
}

extern "C" void kernel_launch(void* const* d_in, const int* in_sizes, int n_in,
                              void* d_out, int out_size, void* d_ws, size_t ws_size,
                              hipStream_t stream) {
    const float* x        = (const float*)d_in[0];
    const float* start_w  = (const float*)d_in[1];
    const float* filter_w = (const float*)d_in[2];
    const float* gate_w   = (const float*)d_in[3];
    const float* res_w    = (const float*)d_in[4];
    const float* skip_w   = (const float*)d_in[5];
    const float* e1w      = (const float*)d_in[6];
    const float* e1b      = (const float*)d_in[7];
    const float* e2w      = (const float*)d_in[8];
    const float* e2b      = (const float*)d_in[9];
    const float* w1       = (const float*)d_in[10];
    const float* fb1      = (const float*)d_in[11];
    const float* w2       = (const float*)d_in[12];
    const float* fb2      = (const float*)d_in[13];
    const float* w3       = (const float*)d_in[14];
    const float* b3       = (const float*)d_in[15];

    float* ws = (float*)d_ws;

    // fixed-region float offsets
    const long o_h0   = 0;            // 32*327680 = 10,485,760
    const long o_p2   = 10485760;     // 32*81152  =  2,596,864
    const long o_fc1  = 13082624;     // 1024*256
    const long o_fc2  = 13344768;     // 256*256
    const long o_swt  = 13410304;     // 192*256
    const long o_e1t  = 13459456;     // 256*128
    const long o_wfgp = 13492224;     // 6*4096
    const long o_rwt  = 13516800;     // 6*1024
    const long o_act1 = 13522944;     // 1024*256
    const long o_G    = 13785088;

    // ---- plan chunks from ws_size ----
    long budget = (long)((double)ws_size * 0.94 / 4.0);
    int dB = 1;
    for (int d = 317; d >= 1; --d) {
        long mch = 256L * (4L * d + 3), hs = mch + 4096;
        long tot = o_G + 192L * mch + lmax_(128L * mch, 64L * hs);
        if (tot <= budget) { dB = d; break; }
    }
    int K = (317 + dB - 1) / dB;
    dB = (317 + K - 1) / K;                 // balanced chunk size
    const long MchA  = 256L * (4L * dB + 3);
    const long HSPAN = MchA + 4096;
    const long o_X   = o_G + 192L * MchA;
    const long P1S   = 256L * (2L * dB + 1);

    float* h0   = ws + o_h0;
    float* p2   = ws + o_p2;
    float* fc1r = ws + o_fc1;
    float* fc2r = ws + o_fc2;
    float* swt  = ws + o_swt;
    float* e1t  = ws + o_e1t;
    float* wfgp = ws + o_wfgp;
    float* rwt  = ws + o_rwt;
    float* act1 = ws + o_act1;
    float* G    = ws + o_G;
    float* hA   = ws + o_X;
    float* hB   = ws + o_X + 32L * HSPAN;
    float* y1c  = ws + o_X;                 // aliases hA/hB (dead by then)
    float* p1c  = ws + o_G;                 // aliases G (dead after skip_end1)
    float* e2c  = ws + o_G + 128L * P1S;

    k_zero<<<1280, 256, 0, stream>>>(fc1r, 327680);   // fc1+fc2 contiguous
    k_start<<<1280, 256, 0, stream>>>(x, start_w, h0);
    k_prep<<<192, 256, 0, stream>>>(skip_w, e1w, filter_w, gate_w, res_w,
                                    swt, e1t, wfgp, rwt);

    const int Mc[6]   = {327424, 327168, 326656, 326400, 326144, 325632};
    const int NpmP[6] = {256, 256, 512, 256, 256, 512};   // Np - padN
    const int pN[6]   = {0, 256, 512, 0, 256, 512};
    const int so_[6]  = {1792, 1536, 1024, 768, 512, 0};
    const int JloO[6] = {-1536, -1280, -768, -768, -512, 0};

    for (int c = 0; c < K; ++c) {
        const int A = c * dB;
        int B = A + dB; if (B > 317) B = 317;
        const int dBc = B - A;
        const int M0 = 1024 * A;
        int tmax = 4 * B + 3; if (tmax > 1272) tmax = 1272;
        const int Tt = tmax - 4 * A;
        const int M1 = M0 + 256 * Tt;

        int Jlo[6], Jhi[6];
        for (int q = 0; q < 6; ++q) {
            int lo = M0 + JloO[q]; if (lo < 0) lo = 0;
            int hi = M1 + so_[q];  if (hi > Mc[q]) hi = Mc[q];
            Jlo[q] = lo; Jhi[q] = hi;
        }

        for (int q = 0; q < 6; ++q) {
            const float* hin = (q == 0) ? h0 : ((q & 1) ? hA : hB);
            const int hinBase   = (q == 0) ? 0 : Jlo[q - 1];
            const int hinStride = (q == 0) ? MCAP : (int)HSPAN;
            float* hout = (q & 1) ? hB : hA;
            const int Jcnt = Jhi[q] - Jlo[q];     // always % 64 == 0
            k_layer_c<<<Jcnt / 64, 256, 0, stream>>>(
                hin, hinBase, hinStride, hout, Jlo[q], (int)HSPAN,
                G + (long)q * 32 * MchA, (int)MchA,
                wfgp + q * 4096, rwt + q * 1024,
                Jlo[q], NpmP[q], pN[q], so_[q], M0, M1, (q < 5) ? 1 : 0);
        }

        const int Mchc = 256 * Tt;
        k_skip_end1_c<<<Mchc / 32, 256, 0, stream>>>(G, swt, e1t, e1b, y1c, (int)MchA);
        const int T1c = 2 * dBc + 1;
        k_pool1_c<<<dim3(T1c, 128), 256, 0, stream>>>(y1c, p1c, (int)MchA, (int)P1S);
        k_end2_c<<<T1c, 256, 0, stream>>>(p1c, e2w, e2b, e2c, (int)P1S);
        k_pool2_c<<<dim3(dBc, 32), 256, 0, stream>>>(e2c, p2, (int)P1S, A);
    }

    // FC1: 1024x10144 @ p2 (10144x256), split-K 8
    k_gemm64<<<dim3(16, 4, 8), 256, 0, stream>>>(w1, p2, fc1r, 10144, 1268);
    k_actbias<<<1024, 256, 0, stream>>>(fc1r, fb1, act1);
    // FC2: 256x1024 @ act1 (1024x256), split-K 4
    k_gemm64<<<dim3(4, 4, 4), 256, 0, stream>>>(w2, act1, fc2r, 1024, 256);
    k_fc3<<<1, 256, 0, stream>>>(fc2r, fb2, w3, b3, (float*)d_out);
}

// Round 5
// 1340.573 us; speedup vs baseline: 3.0642x; 1.4793x over previous
//
#include <hip/hip_runtime.h>
#include <math.h>

// ---------------------------------------------------------------------------
// WaveNet forward. Conv stages f32; skip+end1 fused GEMM uses split-bf16 MFMA
// (3-term: hi*hi + hi*lo + lo*hi, rel err ~2^-18 -> ~1e-4 on logits vs 2e-2
// threshold). Flat layout (channel, time, batch) => buf[c][t*256+n]; dilate()
// is a pure reinterpretation (verified algebra).
// R5: k_skip_end1 was at the f32 VALU issue ceiling (339 us predicted = 335
// measured) -> MFMA is the only path. Everything else unchanged from R4 for
// attribution (top-5 shows only the argmax-duration kernel across replays).
// ---------------------------------------------------------------------------

#define MCAP 327680

typedef short v8s __attribute__((ext_vector_type(8)));
typedef float v4f __attribute__((ext_vector_type(4)));

static inline long lmax_(long a, long b) { return a > b ? a : b; }

__device__ inline unsigned short rnbf(float x) {
    unsigned u = __float_as_uint(x);
    return (unsigned short)((u + 0x7FFFu + ((u >> 16) & 1u)) >> 16);
}
__device__ inline void split2(float v, unsigned short& h, unsigned short& l) {
    h = rnbf(v);
    const float hf = __uint_as_float(((unsigned)h) << 16);
    l = rnbf(v - hf);
}

__global__ __launch_bounds__(256) void k_zero(float* __restrict__ p, int n) {
    int i = blockIdx.x * 256 + threadIdx.x;
    if (i < n) p[i] = 0.f;
}

// h0[o][t*256+n] = sum_i start_w[o,i] * x[n,i,t]
__global__ __launch_bounds__(256) void k_start(const float* __restrict__ x,
                                               const float* __restrict__ sw,
                                               float* __restrict__ h0) {
    int j = blockIdx.x * 256 + threadIdx.x;   // < 327680
    int t = j >> 8, n = j & 255;
    float xv[5];
#pragma unroll
    for (int i = 0; i < 5; ++i) xv[i] = x[n * 6400 + i * 1280 + t];
#pragma unroll
    for (int o = 0; o < 32; ++o) {
        float acc = 0.f;
#pragma unroll
        for (int i = 0; i < 5; ++i) acc = fmaf(sw[o * 5 + i], xv[i], acc);
        h0[o * MCAP + j] = acc;
    }
}

// Prepack weights:
//  swt_hi/lo[ch*192 + k] : split bf16 of skip_w[l][ch][i], k = l*32+i
//  e1t_hi/lo[co*256 + ci]: split bf16 of end1_w[co][ci]
//  wfgp[l][k*64+2o+fg]   : k<32 -> w[o][k][tap0], else tap1; fg=0 filt,1 gate
//  rwt[l][i*32+o]        = res_w[l][o][i]
__global__ __launch_bounds__(256) void k_prep(const float* __restrict__ skw,
                                              const float* __restrict__ e1w,
                                              const float* __restrict__ fw,
                                              const float* __restrict__ gw,
                                              const float* __restrict__ rw,
                                              unsigned short* __restrict__ swt_hi,
                                              unsigned short* __restrict__ swt_lo,
                                              unsigned short* __restrict__ e1t_hi,
                                              unsigned short* __restrict__ e1t_lo,
                                              float* __restrict__ wfgp,
                                              float* __restrict__ rwt) {
    int idx = blockIdx.x * 256 + threadIdx.x;
    if (idx < 49152) {            // 256 ch * 192 k
        int ch = idx / 192, k = idx - ch * 192;
        int l = k >> 5, i = k & 31;
        unsigned short h, lo;
        split2(skw[l * 8192 + ch * 32 + i], h, lo);
        swt_hi[idx] = h; swt_lo[idx] = lo;
    }
    if (idx < 32768) {            // 128 co * 256 ci (e1w already row-major)
        unsigned short h, lo;
        split2(e1w[idx], h, lo);
        e1t_hi[idx] = h; e1t_lo[idx] = lo;
    }
    if (idx < 24576) {
        int l = idx >> 12, r = idx & 4095;
        int k = r >> 6, t = r & 63, o = t >> 1, fg = t & 1;
        const float* src = fg ? gw : fw;
        int i = (k < 32) ? k : (k - 32);
        int tap = (k < 32) ? 0 : 1;
        wfgp[idx] = src[l * 2048 + o * 64 + i * 2 + tap];
    }
    if (idx < 6144) {
        int l = idx >> 10, r = idx & 1023;
        int i = r >> 5, o = r & 31;
        rwt[idx] = rw[l * 1024 + o * 32 + i];
    }
}

// One dilated gated layer over global j in [Jlo, Jlo+Jcnt), Jcnt % 64 == 0.
__global__ __launch_bounds__(256) void k_layer_c(
    const float* __restrict__ hin, const int hinBase, const int hinStride,
    float* __restrict__ hout, const int houtBase, const int houtStride,
    float* __restrict__ gsl, const int gStride,
    const float* __restrict__ wfgp, const float* __restrict__ rwt,
    const int Jlo, const int NpmP, const int padN,
    const int so_, const int M0, const int M1, const int doRes)
{
    __shared__ float rt[64 * 68];
    __shared__ float gt[32 * 68];

    const int tid = threadIdx.x;
    const int j0 = Jlo + blockIdx.x * 64;

    {
        const int r  = tid >> 2;
        const int c0 = (tid & 3) * 16;
        const int ch = r & 31;
        if (r < 32 && j0 < padN) {
            float4 z; z.x = z.y = z.z = z.w = 0.f;
#pragma unroll
            for (int q = 0; q < 4; ++q) *(float4*)&rt[r * 68 + c0 + 4 * q] = z;
        } else {
            const int off = (r < 32) ? (j0 - padN) : (j0 + NpmP);
            const float* p = hin + (size_t)ch * hinStride + (off - hinBase) + c0;
#pragma unroll
            for (int q = 0; q < 4; ++q)
                *(float4*)&rt[r * 68 + c0 + 4 * q] = *(const float4*)(p + 4 * q);
        }
    }
    __syncthreads();

    const int tc = tid >> 3;
    const int tm = (tid & 7) * 8;

    float fa[8], ga[8];
#pragma unroll
    for (int q = 0; q < 8; ++q) { fa[q] = 0.f; ga[q] = 0.f; }

#pragma unroll 4
    for (int k = 0; k < 64; ++k) {
        const float4 a0 = *(const float4*)&rt[k * 68 + tm];
        const float4 a1 = *(const float4*)&rt[k * 68 + tm + 4];
        const float2 wv = *(const float2*)&wfgp[k * 64 + 2 * tc];
        fa[0] = fmaf(wv.x, a0.x, fa[0]); ga[0] = fmaf(wv.y, a0.x, ga[0]);
        fa[1] = fmaf(wv.x, a0.y, fa[1]); ga[1] = fmaf(wv.y, a0.y, ga[1]);
        fa[2] = fmaf(wv.x, a0.z, fa[2]); ga[2] = fmaf(wv.y, a0.z, ga[2]);
        fa[3] = fmaf(wv.x, a0.w, fa[3]); ga[3] = fmaf(wv.y, a0.w, ga[3]);
        fa[4] = fmaf(wv.x, a1.x, fa[4]); ga[4] = fmaf(wv.y, a1.x, ga[4]);
        fa[5] = fmaf(wv.x, a1.y, fa[5]); ga[5] = fmaf(wv.y, a1.y, ga[5]);
        fa[6] = fmaf(wv.x, a1.z, fa[6]); ga[6] = fmaf(wv.y, a1.z, ga[6]);
        fa[7] = fmaf(wv.x, a1.w, fa[7]); ga[7] = fmaf(wv.y, a1.w, ga[7]);
    }

    float gd[8];
#pragma unroll
    for (int q = 0; q < 8; ++q) {
        const float e2f = __expf(2.f * fa[q]);
        const float th  = 1.f - 2.f / (e2f + 1.f);
        const float sg  = 1.f / (1.f + __expf(-ga[q]));
        gd[q] = th * sg;
    }

    float4 g0, g1;
    g0.x = gd[0]; g0.y = gd[1]; g0.z = gd[2]; g0.w = gd[3];
    g1.x = gd[4]; g1.y = gd[5]; g1.z = gd[6]; g1.w = gd[7];

    const int m0c = j0 - so_;
    if (m0c >= M0 && m0c < M1) {
        float* gp = gsl + (size_t)tc * gStride + (m0c - M0) + tm;
        *(float4*)gp = g0;
        *(float4*)(gp + 4) = g1;
    }

    if (doRes) {
        *(float4*)&gt[tc * 68 + tm] = g0;
        *(float4*)&gt[tc * 68 + tm + 4] = g1;
        __syncthreads();

        const float4 rv0 = *(const float4*)&rt[(32 + tc) * 68 + tm];
        const float4 rv1 = *(const float4*)&rt[(32 + tc) * 68 + tm + 4];
        float ac[8] = {rv0.x, rv0.y, rv0.z, rv0.w, rv1.x, rv1.y, rv1.z, rv1.w};

#pragma unroll 4
        for (int k = 0; k < 32; ++k) {
            const float4 b0 = *(const float4*)&gt[k * 68 + tm];
            const float4 b1 = *(const float4*)&gt[k * 68 + tm + 4];
            const float w = rwt[k * 32 + tc];
            ac[0] = fmaf(w, b0.x, ac[0]);
            ac[1] = fmaf(w, b0.y, ac[1]);
            ac[2] = fmaf(w, b0.z, ac[2]);
            ac[3] = fmaf(w, b0.w, ac[3]);
            ac[4] = fmaf(w, b1.x, ac[4]);
            ac[5] = fmaf(w, b1.y, ac[5]);
            ac[6] = fmaf(w, b1.z, ac[6]);
            ac[7] = fmaf(w, b1.w, ac[7]);
        }

        float* hp = hout + (size_t)tc * houtStride + (j0 - houtBase) + tm;
        float4 o0, o1;
        o0.x = ac[0]; o0.y = ac[1]; o0.z = ac[2]; o0.w = ac[3];
        o1.x = ac[4]; o1.y = ac[5]; o1.z = ac[6]; o1.w = ac[7];
        *(float4*)hp = o0;
        *(float4*)(hp + 4) = o1;
    }
}

// Fused skip (K=192) -> relu -> end1 (K=256) + bias -> relu -> y1, via
// split-bf16 MFMA (16x16x32). Block = 256 thr = 4 waves, 64-col tile.
// Phase 1: C1[256ch x 64] ; wave w owns ch-tiles 4w..4w+3, n-tiles 0..3.
// Phase 2: y1[128co x 64] ; wave w owns co-tiles 2w..2w+1, n-tiles 0..3.
// LDS union: gt_hi/lo[64][200] (phase1 B) -> st_hi/lo[64][264] (phase2 B).
__global__ __launch_bounds__(256, 2) void k_skip_end1_m(
    const float* __restrict__ g,
    const unsigned short* __restrict__ swt_hi, const unsigned short* __restrict__ swt_lo,
    const unsigned short* __restrict__ e1t_hi, const unsigned short* __restrict__ e1t_lo,
    const float* __restrict__ b1, float* __restrict__ y1, const int gs)
{
    __shared__ unsigned short U[33792];
    unsigned short* gt_hi = U;              // 64*200
    unsigned short* gt_lo = U + 12800;
    unsigned short* st_hi = U;              // 64*264
    unsigned short* st_lo = U + 16896;

    const int tid  = threadIdx.x;
    const int m0   = blockIdx.x * 64;
    const int lane = tid & 63;
    const int w    = tid >> 6;
    const int l15  = lane & 15;
    const int q8   = (lane >> 4) * 8;
    const int rbase = (lane >> 4) * 4;

    // ---- stage G (192 x 64) as split bf16, [col][k] k-contiguous
    {
        const int scol = tid & 63;
        const int ks0  = (tid >> 6) * 8;    // 0,8,16,24
        for (int kc = 0; kc < 192; kc += 32) {
            alignas(16) unsigned short h8[8], l8[8];
#pragma unroll
            for (int j = 0; j < 8; ++j) {
                const int k = kc + ks0 + j;
                const float v = g[(size_t)(k >> 5) * 32 * gs + (size_t)(k & 31) * gs + m0 + scol];
                split2(v, h8[j], l8[j]);
            }
            *(v8s*)&gt_hi[scol * 200 + kc + ks0] = *(v8s*)h8;
            *(v8s*)&gt_lo[scol * 200 + kc + ks0] = *(v8s*)l8;
        }
    }
    __syncthreads();

    // ---- phase 1: skip GEMM, 256x64 tile
    v4f acc1[4][4];
#pragma unroll
    for (int a = 0; a < 4; ++a)
#pragma unroll
        for (int b = 0; b < 4; ++b) acc1[a][b] = (v4f)(0.f);

    for (int kc = 0; kc < 192; kc += 32) {
        v8s ah[4], al[4], bh[4], bl[4];
#pragma unroll
        for (int t = 0; t < 4; ++t) {
            const int row = (w * 64 + t * 16 + l15) * 192 + kc + q8;
            ah[t] = *(const v8s*)&swt_hi[row];
            al[t] = *(const v8s*)&swt_lo[row];
            const int bo = (t * 16 + l15) * 200 + kc + q8;
            bh[t] = *(const v8s*)&gt_hi[bo];
            bl[t] = *(const v8s*)&gt_lo[bo];
        }
#pragma unroll
        for (int ct = 0; ct < 4; ++ct)
#pragma unroll
            for (int nt = 0; nt < 4; ++nt) {
                acc1[ct][nt] = __builtin_amdgcn_mfma_f32_16x16x32_bf16(ah[ct], bh[nt], acc1[ct][nt], 0, 0, 0);
                acc1[ct][nt] = __builtin_amdgcn_mfma_f32_16x16x32_bf16(ah[ct], bl[nt], acc1[ct][nt], 0, 0, 0);
                acc1[ct][nt] = __builtin_amdgcn_mfma_f32_16x16x32_bf16(al[ct], bh[nt], acc1[ct][nt], 0, 0, 0);
            }
    }
    __syncthreads();   // all gt reads done; st aliases gt

    // ---- relu + split -> st[col][ci]
#pragma unroll
    for (int ct = 0; ct < 4; ++ct)
#pragma unroll
        for (int nt = 0; nt < 4; ++nt) {
            alignas(8) unsigned short sh[4], sl[4];
#pragma unroll
            for (int r = 0; r < 4; ++r) {
                const float v = fmaxf(acc1[ct][nt][r], 0.f);
                split2(v, sh[r], sl[r]);
            }
            const int ci  = w * 64 + ct * 16 + rbase;
            const int col = nt * 16 + l15;
            *(uint2*)&st_hi[col * 264 + ci] = *(uint2*)sh;
            *(uint2*)&st_lo[col * 264 + ci] = *(uint2*)sl;
        }
    __syncthreads();

    // ---- phase 2: end1 GEMM, 128x64 tile
    v4f acc2[2][4];
#pragma unroll
    for (int a = 0; a < 2; ++a)
#pragma unroll
        for (int b = 0; b < 4; ++b) acc2[a][b] = (v4f)(0.f);

    for (int kc = 0; kc < 256; kc += 32) {
        v8s ah[2], al[2], bh[4], bl[4];
#pragma unroll
        for (int t = 0; t < 2; ++t) {
            const int row = (w * 32 + t * 16 + l15) * 256 + kc + q8;
            ah[t] = *(const v8s*)&e1t_hi[row];
            al[t] = *(const v8s*)&e1t_lo[row];
        }
#pragma unroll
        for (int t = 0; t < 4; ++t) {
            const int bo = (t * 16 + l15) * 264 + kc + q8;
            bh[t] = *(const v8s*)&st_hi[bo];
            bl[t] = *(const v8s*)&st_lo[bo];
        }
#pragma unroll
        for (int ct = 0; ct < 2; ++ct)
#pragma unroll
            for (int nt = 0; nt < 4; ++nt) {
                acc2[ct][nt] = __builtin_amdgcn_mfma_f32_16x16x32_bf16(ah[ct], bh[nt], acc2[ct][nt], 0, 0, 0);
                acc2[ct][nt] = __builtin_amdgcn_mfma_f32_16x16x32_bf16(ah[ct], bl[nt], acc2[ct][nt], 0, 0, 0);
                acc2[ct][nt] = __builtin_amdgcn_mfma_f32_16x16x32_bf16(al[ct], bh[nt], acc2[ct][nt], 0, 0, 0);
            }
    }

    // ---- bias + relu -> y1 (f32)
#pragma unroll
    for (int ct = 0; ct < 2; ++ct) {
        const int cobase = w * 32 + ct * 16 + rbase;
        float bb[4];
#pragma unroll
        for (int r = 0; r < 4; ++r) bb[r] = b1[cobase + r];
#pragma unroll
        for (int nt = 0; nt < 4; ++nt) {
            const int col = m0 + nt * 16 + l15;
#pragma unroll
            for (int r = 0; r < 4; ++r)
                y1[(size_t)(cobase + r) * gs + col] = fmaxf(acc2[ct][nt][r] + bb[r], 0.f);
        }
    }
}

__global__ __launch_bounds__(256) void k_pool1_c(const float* __restrict__ y1c,
                                                 float* __restrict__ p1c,
                                                 const int gs, const int p1s) {
    const int n = threadIdx.x, tl1 = blockIdx.x, co = blockIdx.y;
    const int base = co * gs + tl1 * 512 + n;
    float v = fmaxf(fmaxf(y1c[base], y1c[base + 256]), y1c[base + 512]);
    p1c[co * p1s + tl1 * 256 + n] = v;
}

__global__ __launch_bounds__(256) void k_end2_c(const float* __restrict__ p1c,
                                                const float* __restrict__ w,
                                                const float* __restrict__ b,
                                                float* __restrict__ e2c,
                                                const int p1s) {
    const int mcol = blockIdx.x * 256 + threadIdx.x;
    float r[128];
#pragma unroll
    for (int i = 0; i < 128; ++i) r[i] = p1c[i * p1s + mcol];
#pragma unroll
    for (int o = 0; o < 32; ++o) {
        float acc = b[o];
        const float* wo = w + o * 128;
#pragma unroll
        for (int i = 0; i < 128; i += 4) {
            const float4 wv = *(const float4*)(wo + i);
            acc = fmaf(wv.x, r[i], acc);
            acc = fmaf(wv.y, r[i + 1], acc);
            acc = fmaf(wv.z, r[i + 2], acc);
            acc = fmaf(wv.w, r[i + 3], acc);
        }
        e2c[o * p1s + mcol] = fmaxf(acc, 0.f);
    }
}

__global__ __launch_bounds__(256) void k_pool2_c(const float* __restrict__ e2c,
                                                 float* __restrict__ p2,
                                                 const int p1s, const int A) {
    const int n = threadIdx.x, tl2 = blockIdx.x, co = blockIdx.y;
    const int base = co * p1s + tl2 * 512 + n;
    float v = fmaxf(fmaxf(e2c[base], e2c[base + 256]), e2c[base + 512]);
    p2[co * 81152 + (A + tl2) * 256 + n] = v;
}

// Tiled GEMM: C[M x 256] += A[M x Ktot](row-major) * B[Ktot x 256](row-major)
__global__ __launch_bounds__(256) void k_gemm64(const float* __restrict__ A,
                                                const float* __restrict__ B,
                                                float* __restrict__ C,
                                                const int Ktot, const int KC) {
    __shared__ float sA[32 * 68];
    __shared__ float sB[32 * 68];

    const int tid = threadIdx.x;
    const int o0 = blockIdx.x * 64;
    const int b0 = blockIdx.y * 64;
    const int k0 = blockIdx.z * KC;

    float acc[4][4];
#pragma unroll
    for (int i = 0; i < 4; ++i)
#pragma unroll
        for (int jq = 0; jq < 4; ++jq) acc[i][jq] = 0.f;

    const int ao  = tid >> 2;
    const int ak8 = (tid & 3) * 8;
    const int bk  = tid >> 3;
    const int bb8 = (tid & 7) * 8;
    const int to4 = (tid & 15) * 4;
    const int tb4 = (tid >> 4) * 4;

    for (int kc = 0; kc < KC; kc += 32) {
        const int kcLen = (KC - kc < 32) ? (KC - kc) : 32;
        const float* ap = A + (size_t)(o0 + ao) * Ktot + k0 + kc + ak8;
#pragma unroll
        for (int i = 0; i < 8; ++i) {
            float v = (ak8 + i < kcLen) ? ap[i] : 0.f;
            sA[(ak8 + i) * 68 + ao] = v;
        }
        if (bk < kcLen) {
            const float* bp = B + (size_t)(k0 + kc + bk) * 256 + b0 + bb8;
            const float4 v0 = *(const float4*)bp;
            const float4 v1 = *(const float4*)(bp + 4);
            *(float4*)&sB[bk * 68 + bb8] = v0;
            *(float4*)&sB[bk * 68 + bb8 + 4] = v1;
        } else {
            float4 z; z.x = z.y = z.z = z.w = 0.f;
            *(float4*)&sB[bk * 68 + bb8] = z;
            *(float4*)&sB[bk * 68 + bb8 + 4] = z;
        }
        __syncthreads();

#pragma unroll 8
        for (int kk = 0; kk < 32; ++kk) {
            const float4 av = *(const float4*)&sA[kk * 68 + to4];
            const float4 bv = *(const float4*)&sB[kk * 68 + tb4];
            const float aa[4] = {av.x, av.y, av.z, av.w};
#pragma unroll
            for (int i = 0; i < 4; ++i) {
                acc[i][0] = fmaf(aa[i], bv.x, acc[i][0]);
                acc[i][1] = fmaf(aa[i], bv.y, acc[i][1]);
                acc[i][2] = fmaf(aa[i], bv.z, acc[i][2]);
                acc[i][3] = fmaf(aa[i], bv.w, acc[i][3]);
            }
        }
        __syncthreads();
    }

#pragma unroll
    for (int i = 0; i < 4; ++i)
#pragma unroll
        for (int jq = 0; jq < 4; ++jq)
            atomicAdd(&C[(size_t)(o0 + to4 + i) * 256 + b0 + tb4 + jq], acc[i][jq]);
}

__global__ __launch_bounds__(256) void k_actbias(const float* __restrict__ raw,
                                                 const float* __restrict__ bias,
                                                 float* __restrict__ out) {
    const int k = blockIdx.x, b = threadIdx.x;
    out[k * 256 + b] = fmaxf(raw[k * 256 + b] + bias[k], 0.f);
}

__global__ __launch_bounds__(256) void k_fc3(const float* __restrict__ fc2raw,
                                             const float* __restrict__ fb2,
                                             const float* __restrict__ w3,
                                             const float* __restrict__ b3,
                                             float* __restrict__ out) {
    const int b = threadIdx.x;
    float l0 = b3[0], l1 = b3[1];
    for (int k = 0; k < 256; ++k) {
        const float a = fmaxf(fc2raw[k * 256 + b] + fb2[k], 0.f);
        l0 = fmaf(w3[k], a, l0);
        l1 = fmaf(w3[256 + k], a, l1);
    }
    out[2 * b] = l0;
    out[2 * b + 1] = l1;
    const float mx = fmaxf(l0, l1);
    const float e0 = expf(l0 - mx), e1 = expf(l1 - mx);
    const float inv = 1.f / (e0 + e1);
    out[512 + 2 * b] = e0 * inv;
    out[513 + 2 * b] = e1 * inv;
    out[1024 + b] = (l1 > l0) ? 1.f : 0.f;
}

extern "C" void kernel_launch(void* const* d_in, const int* in_sizes, int n_in,
                              void* d_out, int out_size, void* d_ws, size_t ws_size,
                              hipStream_t stream) {
    const float* x        = (const float*)d_in[0];
    const float* start_w  = (const float*)d_in[1];
    const float* filter_w = (const float*)d_in[2];
    const float* gate_w   = (const float*)d_in[3];
    const float* res_w    = (const float*)d_in[4];
    const float* skip_w   = (const float*)d_in[5];
    const float* e1w      = (const float*)d_in[6];
    const float* e1b      = (const float*)d_in[7];
    const float* e2w      = (const float*)d_in[8];
    const float* e2b      = (const float*)d_in[9];
    const float* w1       = (const float*)d_in[10];
    const float* fb1      = (const float*)d_in[11];
    const float* w2       = (const float*)d_in[12];
    const float* fb2      = (const float*)d_in[13];
    const float* w3       = (const float*)d_in[14];
    const float* b3       = (const float*)d_in[15];

    float* ws = (float*)d_ws;

    // fixed-region float offsets
    const long o_h0   = 0;            // 32*327680
    const long o_p2   = 10485760;     // 32*81152
    const long o_fc1  = 13082624;     // 1024*256
    const long o_fc2  = 13344768;     // 256*256
    const long o_wbf  = 13410304;     // 163840 u16 = 81920 floats (split weights)
    const long o_wfgp = 13492224;     // 6*4096
    const long o_rwt  = 13516800;     // 6*1024
    const long o_act1 = 13522944;     // 1024*256
    const long o_G    = 13785088;

    // ---- plan chunks from ws_size ----
    long budget = (long)((double)ws_size * 0.94 / 4.0);
    int dB = 1;
    for (int d = 317; d >= 1; --d) {
        long mch = 256L * (4L * d + 3), hs = mch + 4096;
        long tot = o_G + 192L * mch + lmax_(128L * mch, 64L * hs);
        if (tot <= budget) { dB = d; break; }
    }
    int K = (317 + dB - 1) / dB;
    dB = (317 + K - 1) / K;
    const long MchA  = 256L * (4L * dB + 3);
    const long HSPAN = MchA + 4096;
    const long o_X   = o_G + 192L * MchA;
    const long P1S   = 256L * (2L * dB + 1);

    float* h0   = ws + o_h0;
    float* p2   = ws + o_p2;
    float* fc1r = ws + o_fc1;
    float* fc2r = ws + o_fc2;
    unsigned short* swt_hi = (unsigned short*)(ws + o_wbf);
    unsigned short* swt_lo = swt_hi + 49152;
    unsigned short* e1t_hi = swt_lo + 49152;
    unsigned short* e1t_lo = e1t_hi + 32768;
    float* wfgp = ws + o_wfgp;
    float* rwt  = ws + o_rwt;
    float* act1 = ws + o_act1;
    float* G    = ws + o_G;
    float* hA   = ws + o_X;
    float* hB   = ws + o_X + 32L * HSPAN;
    float* y1c  = ws + o_X;                 // aliases hA/hB (dead by then)
    float* p1c  = ws + o_G;                 // aliases G (dead after skip_end1)
    float* e2c  = ws + o_G + 128L * P1S;

    k_zero<<<1280, 256, 0, stream>>>(fc1r, 327680);
    k_start<<<1280, 256, 0, stream>>>(x, start_w, h0);
    k_prep<<<192, 256, 0, stream>>>(skip_w, e1w, filter_w, gate_w, res_w,
                                    swt_hi, swt_lo, e1t_hi, e1t_lo, wfgp, rwt);

    const int Mc[6]   = {327424, 327168, 326656, 326400, 326144, 325632};
    const int NpmP[6] = {256, 256, 512, 256, 256, 512};
    const int pN[6]   = {0, 256, 512, 0, 256, 512};
    const int so_[6]  = {1792, 1536, 1024, 768, 512, 0};
    const int JloO[6] = {-1536, -1280, -768, -768, -512, 0};

    for (int c = 0; c < K; ++c) {
        const int A = c * dB;
        int B = A + dB; if (B > 317) B = 317;
        const int dBc = B - A;
        const int M0 = 1024 * A;
        int tmax = 4 * B + 3; if (tmax > 1272) tmax = 1272;
        const int Tt = tmax - 4 * A;
        const int M1 = M0 + 256 * Tt;

        int Jlo[6], Jhi[6];
        for (int q = 0; q < 6; ++q) {
            int lo = M0 + JloO[q]; if (lo < 0) lo = 0;
            int hi = M1 + so_[q];  if (hi > Mc[q]) hi = Mc[q];
            Jlo[q] = lo; Jhi[q] = hi;
        }

        for (int q = 0; q < 6; ++q) {
            const float* hin = (q == 0) ? h0 : ((q & 1) ? hA : hB);
            const int hinBase   = (q == 0) ? 0 : Jlo[q - 1];
            const int hinStride = (q == 0) ? MCAP : (int)HSPAN;
            float* hout = (q & 1) ? hB : hA;
            const int Jcnt = Jhi[q] - Jlo[q];     // % 64 == 0
            k_layer_c<<<Jcnt / 64, 256, 0, stream>>>(
                hin, hinBase, hinStride, hout, Jlo[q], (int)HSPAN,
                G + (long)q * 32 * MchA, (int)MchA,
                wfgp + q * 4096, rwt + q * 1024,
                Jlo[q], NpmP[q], pN[q], so_[q], M0, M1, (q < 5) ? 1 : 0);
        }

        const int Mchc = 256 * Tt;                 // % 64 == 0
        k_skip_end1_m<<<Mchc / 64, 256, 0, stream>>>(
            G, swt_hi, swt_lo, e1t_hi, e1t_lo, e1b, y1c, (int)MchA);
        const int T1c = 2 * dBc + 1;
        k_pool1_c<<<dim3(T1c, 128), 256, 0, stream>>>(y1c, p1c, (int)MchA, (int)P1S);
        k_end2_c<<<T1c, 256, 0, stream>>>(p1c, e2w, e2b, e2c, (int)P1S);
        k_pool2_c<<<dim3(dBc, 32), 256, 0, stream>>>(e2c, p2, (int)P1S, A);
    }

    k_gemm64<<<dim3(16, 4, 8), 256, 0, stream>>>(w1, p2, fc1r, 10144, 1268);
    k_actbias<<<1024, 256, 0, stream>>>(fc1r, fb1, act1);
    k_gemm64<<<dim3(4, 4, 4), 256, 0, stream>>>(w2, act1, fc2r, 1024, 256);
    k_fc3<<<1, 256, 0, stream>>>(fc2r, fb2, w3, b3, (float*)d_out);
}

// Round 6
// 1161.188 us; speedup vs baseline: 3.5375x; 1.1545x over previous
//
#include <hip/hip_runtime.h>
#include <math.h>

// ---------------------------------------------------------------------------
// WaveNet forward. Layers + skip/end1 via split-bf16 MFMA (3-term / 2-chain
// splits, rel err ~2^-16 -> ~1e-4 on logits vs 2e-2 threshold). Flat layout
// (channel, time, batch) => buf[c][t*256+n]; dilate() is a reinterpretation.
// R6: k_layer_c -> k_layer_m (MFMA; layers were ~60% of runtime, f32 VALU
// floor 38us vs HBM floor 27us each); k_gemm64 sA stride 68->65 (5.2M 4-way
// bank conflicts measured: 8*68 % 32 == 0) and split-K 16.
// ---------------------------------------------------------------------------

#define MCAP 327680

typedef short v8s __attribute__((ext_vector_type(8)));
typedef float v4f __attribute__((ext_vector_type(4)));

static inline long lmax_(long a, long b) { return a > b ? a : b; }

__device__ inline unsigned short rnbf(float x) {
    unsigned u = __float_as_uint(x);
    return (unsigned short)((u + 0x7FFFu + ((u >> 16) & 1u)) >> 16);
}
__device__ inline void split2(float v, unsigned short& h, unsigned short& l) {
    h = rnbf(v);
    const float hf = __uint_as_float(((unsigned)h) << 16);
    l = rnbf(v - hf);
}

__global__ __launch_bounds__(256) void k_zero(float* __restrict__ p, int n) {
    int i = blockIdx.x * 256 + threadIdx.x;
    if (i < n) p[i] = 0.f;
}

__global__ __launch_bounds__(256) void k_start(const float* __restrict__ x,
                                               const float* __restrict__ sw,
                                               float* __restrict__ h0) {
    int j = blockIdx.x * 256 + threadIdx.x;
    int t = j >> 8, n = j & 255;
    float xv[5];
#pragma unroll
    for (int i = 0; i < 5; ++i) xv[i] = x[n * 6400 + i * 1280 + t];
#pragma unroll
    for (int o = 0; o < 32; ++o) {
        float acc = 0.f;
#pragma unroll
        for (int i = 0; i < 5; ++i) acc = fmaf(sw[o * 5 + i], xv[i], acc);
        h0[o * MCAP + j] = acc;
    }
}

// Prepack weights (split bf16): see R6 header comment.
__global__ __launch_bounds__(256) void k_prep(const float* __restrict__ skw,
                                              const float* __restrict__ e1w,
                                              const float* __restrict__ fw,
                                              const float* __restrict__ gw,
                                              const float* __restrict__ rw,
                                              unsigned short* __restrict__ swt_hi,
                                              unsigned short* __restrict__ swt_lo,
                                              unsigned short* __restrict__ e1t_hi,
                                              unsigned short* __restrict__ e1t_lo,
                                              unsigned short* __restrict__ wfg_hi,
                                              unsigned short* __restrict__ wfg_lo,
                                              unsigned short* __restrict__ wr_hi,
                                              unsigned short* __restrict__ wr_lo) {
    int idx = blockIdx.x * 256 + threadIdx.x;
    if (idx < 49152) {
        int ch = idx / 192, k = idx - ch * 192;
        int l = k >> 5, i = k & 31;
        unsigned short h, lo;
        split2(skw[l * 8192 + ch * 32 + i], h, lo);
        swt_hi[idx] = h; swt_lo[idx] = lo;
    }
    if (idx < 32768) {
        unsigned short h, lo;
        split2(e1w[idx], h, lo);
        e1t_hi[idx] = h; e1t_lo[idx] = lo;
    }
    if (idx < 24576) {          // 6 layers * 64 rows * 64 k
        int l = idx >> 12, r = idx & 4095;
        int row = r >> 6, k = r & 63;
        int o = row & 31, i = k & 31, tap = k >> 5;
        const float* src = (row < 32) ? fw : gw;
        unsigned short h, lo;
        split2(src[l * 2048 + o * 64 + i * 2 + tap], h, lo);
        wfg_hi[idx] = h; wfg_lo[idx] = lo;
    }
    if (idx < 12288) {          // 6 layers * 32 o * 64 k (W duplicated halves)
        int l = idx >> 11, r = idx & 2047;
        int o = r >> 6, k = r & 63, i = k & 31;
        unsigned short h, lo;
        split2(rw[l * 1024 + o * 32 + i], h, lo);
        wr_hi[idx] = h; wr_lo[idx] = lo;
    }
}

// One dilated gated layer via split-bf16 MFMA. 128-col tile, Jcnt % 128 == 0.
__global__ __launch_bounds__(256) void k_layer_m(
    const float* __restrict__ hin, const int hinBase, const int hinStride,
    float* __restrict__ hout, const int houtBase, const int houtStride,
    float* __restrict__ gsl, const int gStride,
    const unsigned short* __restrict__ wfg_hi, const unsigned short* __restrict__ wfg_lo,
    const unsigned short* __restrict__ wr_hi, const unsigned short* __restrict__ wr_lo,
    const int Jlo, const int NpmP, const int padN,
    const int so_, const int M0, const int M1, const int doRes)
{
    __shared__ unsigned short AT[128 * 136]; // [col][k]: 0..63 hi, 64..127 lo
    __shared__ unsigned short GT[128 * 72];  // [col][k]: 0..31 ghi, 32..63 glo

    const int tid = threadIdx.x;
    const int j0 = Jlo + blockIdx.x * 128;

    {
        const int col = tid & 127;
        const int kg = tid >> 7;            // 0: tap0, 1: tap1
        unsigned short* bh = &AT[col * 136 + kg * 32];
        unsigned short* bl = &AT[col * 136 + 64 + kg * 32];
        if (kg == 0 && j0 < padN) {
            uint4 z; z.x = z.y = z.z = z.w = 0u;
#pragma unroll
            for (int ch = 0; ch < 32; ch += 8) {
                *(uint4*)&bh[ch] = z;
                *(uint4*)&bl[ch] = z;
            }
        } else {
            const int off = (kg == 0) ? (j0 - padN) : (j0 + NpmP);
            const float* p = hin + (off - hinBase) + col;
#pragma unroll
            for (int ch = 0; ch < 32; ch += 8) {
                alignas(16) unsigned short h8[8], l8[8];
#pragma unroll
                for (int u = 0; u < 8; ++u)
                    split2(p[(size_t)(ch + u) * hinStride], h8[u], l8[u]);
                *(uint4*)&bh[ch] = *(uint4*)h8;
                *(uint4*)&bl[ch] = *(uint4*)l8;
            }
        }
    }
    __syncthreads();

    const int lane = tid & 63;
    const int w    = tid >> 6;
    const int ch2  = w >> 1;
    const int mh   = w & 1;
    const int l15  = lane & 15;
    const int quad = lane >> 4;
    const int q8   = quad * 8;
    const int colb = ch2 * 64;

    v4f accf[4], accg[4];
#pragma unroll
    for (int nt = 0; nt < 4; ++nt) { accf[nt] = (v4f)(0.f); accg[nt] = (v4f)(0.f); }

#pragma unroll
    for (int kt = 0; kt < 2; ++kt) {
        const int frow = (mh * 16 + l15) * 64 + kt * 32 + q8;
        const int grow = (32 + mh * 16 + l15) * 64 + kt * 32 + q8;
        const v8s afh = *(const v8s*)&wfg_hi[frow];
        const v8s afl = *(const v8s*)&wfg_lo[frow];
        const v8s agh = *(const v8s*)&wfg_hi[grow];
        const v8s agl = *(const v8s*)&wfg_lo[grow];
#pragma unroll
        for (int nt = 0; nt < 4; ++nt) {
            const int col = colb + nt * 16 + l15;
            const v8s bh = *(const v8s*)&AT[col * 136 + kt * 32 + q8];
            const v8s bl = *(const v8s*)&AT[col * 136 + 64 + kt * 32 + q8];
            accf[nt] = __builtin_amdgcn_mfma_f32_16x16x32_bf16(afh, bh, accf[nt], 0, 0, 0);
            accf[nt] = __builtin_amdgcn_mfma_f32_16x16x32_bf16(afh, bl, accf[nt], 0, 0, 0);
            accf[nt] = __builtin_amdgcn_mfma_f32_16x16x32_bf16(afl, bh, accf[nt], 0, 0, 0);
            accg[nt] = __builtin_amdgcn_mfma_f32_16x16x32_bf16(agh, bh, accg[nt], 0, 0, 0);
            accg[nt] = __builtin_amdgcn_mfma_f32_16x16x32_bf16(agh, bl, accg[nt], 0, 0, 0);
            accg[nt] = __builtin_amdgcn_mfma_f32_16x16x32_bf16(agl, bh, accg[nt], 0, 0, 0);
        }
    }

    float gated[4][4];
#pragma unroll
    for (int nt = 0; nt < 4; ++nt)
#pragma unroll
        for (int r = 0; r < 4; ++r) {
            const float f = accf[nt][r];
            const float g = accg[nt][r];
            const float th = 1.f - 2.f / (__expf(2.f * f) + 1.f);
            const float sg = 1.f / (1.f + __expf(-g));
            gated[nt][r] = th * sg;
        }

    const int m0c = j0 - so_;
    if (m0c >= M0 && m0c < M1) {
#pragma unroll
        for (int nt = 0; nt < 4; ++nt)
#pragma unroll
            for (int r = 0; r < 4; ++r) {
                const int ch = mh * 16 + quad * 4 + r;
                const int m = (m0c - M0) + colb + nt * 16 + l15;
                gsl[(size_t)ch * gStride + m] = gated[nt][r];
            }
    }

    if (doRes) {
#pragma unroll
        for (int nt = 0; nt < 4; ++nt)
#pragma unroll
            for (int r = 0; r < 4; ++r) {
                const int ch = mh * 16 + quad * 4 + r;
                const int col = colb + nt * 16 + l15;
                unsigned short h, lo;
                split2(gated[nt][r], h, lo);
                GT[col * 72 + ch] = h;
                GT[col * 72 + 32 + ch] = lo;
            }
        __syncthreads();

        v4f accr[4];
#pragma unroll
        for (int nt = 0; nt < 4; ++nt) accr[nt] = (v4f)(0.f);
#pragma unroll
        for (int kt = 0; kt < 2; ++kt) {
            const int row = (mh * 16 + l15) * 64 + kt * 32 + q8;
            const v8s arh = *(const v8s*)&wr_hi[row];
            const v8s arl = *(const v8s*)&wr_lo[row];
#pragma unroll
            for (int nt = 0; nt < 4; ++nt) {
                const int col = colb + nt * 16 + l15;
                const v8s b = *(const v8s*)&GT[col * 72 + kt * 32 + q8];
                accr[nt] = __builtin_amdgcn_mfma_f32_16x16x32_bf16(arh, b, accr[nt], 0, 0, 0);
                accr[nt] = __builtin_amdgcn_mfma_f32_16x16x32_bf16(arl, b, accr[nt], 0, 0, 0);
            }
        }

#pragma unroll
        for (int nt = 0; nt < 4; ++nt)
#pragma unroll
            for (int r = 0; r < 4; ++r) {
                const int o = mh * 16 + quad * 4 + r;
                const int col = colb + nt * 16 + l15;
                const unsigned hh = AT[col * 136 + 32 + o];
                const unsigned ll = AT[col * 136 + 64 + 32 + o];
                const float tap1 = __uint_as_float(hh << 16) + __uint_as_float(ll << 16);
                hout[(size_t)o * houtStride + (j0 - houtBase) + col] = accr[nt][r] + tap1;
            }
    }
}

// Fused skip -> relu -> end1 + bias -> relu -> y1 (split-bf16 MFMA), from R5.
__global__ __launch_bounds__(256, 2) void k_skip_end1_m(
    const float* __restrict__ g,
    const unsigned short* __restrict__ swt_hi, const unsigned short* __restrict__ swt_lo,
    const unsigned short* __restrict__ e1t_hi, const unsigned short* __restrict__ e1t_lo,
    const float* __restrict__ b1, float* __restrict__ y1, const int gs)
{
    __shared__ unsigned short U[33792];
    unsigned short* gt_hi = U;
    unsigned short* gt_lo = U + 12800;
    unsigned short* st_hi = U;
    unsigned short* st_lo = U + 16896;

    const int tid  = threadIdx.x;
    const int m0   = blockIdx.x * 64;
    const int lane = tid & 63;
    const int w    = tid >> 6;
    const int l15  = lane & 15;
    const int q8   = (lane >> 4) * 8;
    const int rbase = (lane >> 4) * 4;

    {
        const int scol = tid & 63;
        const int ks0  = (tid >> 6) * 8;
        for (int kc = 0; kc < 192; kc += 32) {
            alignas(16) unsigned short h8[8], l8[8];
#pragma unroll
            for (int j = 0; j < 8; ++j) {
                const int k = kc + ks0 + j;
                const float v = g[(size_t)(k >> 5) * 32 * gs + (size_t)(k & 31) * gs + m0 + scol];
                split2(v, h8[j], l8[j]);
            }
            *(v8s*)&gt_hi[scol * 200 + kc + ks0] = *(v8s*)h8;
            *(v8s*)&gt_lo[scol * 200 + kc + ks0] = *(v8s*)l8;
        }
    }
    __syncthreads();

    v4f acc1[4][4];
#pragma unroll
    for (int a = 0; a < 4; ++a)
#pragma unroll
        for (int b = 0; b < 4; ++b) acc1[a][b] = (v4f)(0.f);

    for (int kc = 0; kc < 192; kc += 32) {
        v8s ah[4], al[4], bh[4], bl[4];
#pragma unroll
        for (int t = 0; t < 4; ++t) {
            const int row = (w * 64 + t * 16 + l15) * 192 + kc + q8;
            ah[t] = *(const v8s*)&swt_hi[row];
            al[t] = *(const v8s*)&swt_lo[row];
            const int bo = (t * 16 + l15) * 200 + kc + q8;
            bh[t] = *(const v8s*)&gt_hi[bo];
            bl[t] = *(const v8s*)&gt_lo[bo];
        }
#pragma unroll
        for (int ct = 0; ct < 4; ++ct)
#pragma unroll
            for (int nt = 0; nt < 4; ++nt) {
                acc1[ct][nt] = __builtin_amdgcn_mfma_f32_16x16x32_bf16(ah[ct], bh[nt], acc1[ct][nt], 0, 0, 0);
                acc1[ct][nt] = __builtin_amdgcn_mfma_f32_16x16x32_bf16(ah[ct], bl[nt], acc1[ct][nt], 0, 0, 0);
                acc1[ct][nt] = __builtin_amdgcn_mfma_f32_16x16x32_bf16(al[ct], bh[nt], acc1[ct][nt], 0, 0, 0);
            }
    }
    __syncthreads();

#pragma unroll
    for (int ct = 0; ct < 4; ++ct)
#pragma unroll
        for (int nt = 0; nt < 4; ++nt) {
            alignas(8) unsigned short sh[4], sl[4];
#pragma unroll
            for (int r = 0; r < 4; ++r) {
                const float v = fmaxf(acc1[ct][nt][r], 0.f);
                split2(v, sh[r], sl[r]);
            }
            const int ci  = w * 64 + ct * 16 + rbase;
            const int col = nt * 16 + l15;
            *(uint2*)&st_hi[col * 264 + ci] = *(uint2*)sh;
            *(uint2*)&st_lo[col * 264 + ci] = *(uint2*)sl;
        }
    __syncthreads();

    v4f acc2[2][4];
#pragma unroll
    for (int a = 0; a < 2; ++a)
#pragma unroll
        for (int b = 0; b < 4; ++b) acc2[a][b] = (v4f)(0.f);

    for (int kc = 0; kc < 256; kc += 32) {
        v8s ah[2], al[2], bh[4], bl[4];
#pragma unroll
        for (int t = 0; t < 2; ++t) {
            const int row = (w * 32 + t * 16 + l15) * 256 + kc + q8;
            ah[t] = *(const v8s*)&e1t_hi[row];
            al[t] = *(const v8s*)&e1t_lo[row];
        }
#pragma unroll
        for (int t = 0; t < 4; ++t) {
            const int bo = (t * 16 + l15) * 264 + kc + q8;
            bh[t] = *(const v8s*)&st_hi[bo];
            bl[t] = *(const v8s*)&st_lo[bo];
        }
#pragma unroll
        for (int ct = 0; ct < 2; ++ct)
#pragma unroll
            for (int nt = 0; nt < 4; ++nt) {
                acc2[ct][nt] = __builtin_amdgcn_mfma_f32_16x16x32_bf16(ah[ct], bh[nt], acc2[ct][nt], 0, 0, 0);
                acc2[ct][nt] = __builtin_amdgcn_mfma_f32_16x16x32_bf16(ah[ct], bl[nt], acc2[ct][nt], 0, 0, 0);
                acc2[ct][nt] = __builtin_amdgcn_mfma_f32_16x16x32_bf16(al[ct], bh[nt], acc2[ct][nt], 0, 0, 0);
            }
    }

#pragma unroll
    for (int ct = 0; ct < 2; ++ct) {
        const int cobase = w * 32 + ct * 16 + rbase;
        float bb[4];
#pragma unroll
        for (int r = 0; r < 4; ++r) bb[r] = b1[cobase + r];
#pragma unroll
        for (int nt = 0; nt < 4; ++nt) {
            const int col = m0 + nt * 16 + l15;
#pragma unroll
            for (int r = 0; r < 4; ++r)
                y1[(size_t)(cobase + r) * gs + col] = fmaxf(acc2[ct][nt][r] + bb[r], 0.f);
        }
    }
}

__global__ __launch_bounds__(256) void k_pool1_c(const float* __restrict__ y1c,
                                                 float* __restrict__ p1c,
                                                 const int gs, const int p1s) {
    const int n = threadIdx.x, tl1 = blockIdx.x, co = blockIdx.y;
    const int base = co * gs + tl1 * 512 + n;
    float v = fmaxf(fmaxf(y1c[base], y1c[base + 256]), y1c[base + 512]);
    p1c[co * p1s + tl1 * 256 + n] = v;
}

__global__ __launch_bounds__(256) void k_end2_c(const float* __restrict__ p1c,
                                                const float* __restrict__ w,
                                                const float* __restrict__ b,
                                                float* __restrict__ e2c,
                                                const int p1s) {
    const int mcol = blockIdx.x * 256 + threadIdx.x;
    float r[128];
#pragma unroll
    for (int i = 0; i < 128; ++i) r[i] = p1c[i * p1s + mcol];
#pragma unroll
    for (int o = 0; o < 32; ++o) {
        float acc = b[o];
        const float* wo = w + o * 128;
#pragma unroll
        for (int i = 0; i < 128; i += 4) {
            const float4 wv = *(const float4*)(wo + i);
            acc = fmaf(wv.x, r[i], acc);
            acc = fmaf(wv.y, r[i + 1], acc);
            acc = fmaf(wv.z, r[i + 2], acc);
            acc = fmaf(wv.w, r[i + 3], acc);
        }
        e2c[o * p1s + mcol] = fmaxf(acc, 0.f);
    }
}

__global__ __launch_bounds__(256) void k_pool2_c(const float* __restrict__ e2c,
                                                 float* __restrict__ p2,
                                                 const int p1s, const int A) {
    const int n = threadIdx.x, tl2 = blockIdx.x, co = blockIdx.y;
    const int base = co * p1s + tl2 * 512 + n;
    float v = fmaxf(fmaxf(e2c[base], e2c[base + 256]), e2c[base + 512]);
    p2[co * 81152 + (A + tl2) * 256 + n] = v;
}

// Tiled GEMM: C[M x 256] += A[M x Ktot](rm) * B[Ktot x 256](rm); sA stride 65.
__global__ __launch_bounds__(256) void k_gemm64(const float* __restrict__ A,
                                                const float* __restrict__ B,
                                                float* __restrict__ C,
                                                const int Ktot, const int KC) {
    __shared__ float sA[32 * 65];
    __shared__ float sB[32 * 68];

    const int tid = threadIdx.x;
    const int o0 = blockIdx.x * 64;
    const int b0 = blockIdx.y * 64;
    const int k0 = blockIdx.z * KC;

    float acc[4][4];
#pragma unroll
    for (int i = 0; i < 4; ++i)
#pragma unroll
        for (int jq = 0; jq < 4; ++jq) acc[i][jq] = 0.f;

    const int ao  = tid >> 2;
    const int ak8 = (tid & 3) * 8;
    const int bk  = tid >> 3;
    const int bb8 = (tid & 7) * 8;
    const int to4 = (tid & 15) * 4;
    const int tb4 = (tid >> 4) * 4;

    for (int kc = 0; kc < KC; kc += 32) {
        const int kcLen = (KC - kc < 32) ? (KC - kc) : 32;
        const float* ap = A + (size_t)(o0 + ao) * Ktot + k0 + kc + ak8;
#pragma unroll
        for (int i = 0; i < 8; ++i) {
            float v = (ak8 + i < kcLen) ? ap[i] : 0.f;
            sA[(ak8 + i) * 65 + ao] = v;
        }
        if (bk < kcLen) {
            const float* bp = B + (size_t)(k0 + kc + bk) * 256 + b0 + bb8;
            const float4 v0 = *(const float4*)bp;
            const float4 v1 = *(const float4*)(bp + 4);
            *(float4*)&sB[bk * 68 + bb8] = v0;
            *(float4*)&sB[bk * 68 + bb8 + 4] = v1;
        } else {
            float4 z; z.x = z.y = z.z = z.w = 0.f;
            *(float4*)&sB[bk * 68 + bb8] = z;
            *(float4*)&sB[bk * 68 + bb8 + 4] = z;
        }
        __syncthreads();

#pragma unroll 8
        for (int kk = 0; kk < 32; ++kk) {
            const float4 av = *(const float4*)&sA[kk * 65 + to4];
            const float4 bv = *(const float4*)&sB[kk * 68 + tb4];
            const float aa[4] = {av.x, av.y, av.z, av.w};
#pragma unroll
            for (int i = 0; i < 4; ++i) {
                acc[i][0] = fmaf(aa[i], bv.x, acc[i][0]);
                acc[i][1] = fmaf(aa[i], bv.y, acc[i][1]);
                acc[i][2] = fmaf(aa[i], bv.z, acc[i][2]);
                acc[i][3] = fmaf(aa[i], bv.w, acc[i][3]);
            }
        }
        __syncthreads();
    }

#pragma unroll
    for (int i = 0; i < 4; ++i)
#pragma unroll
        for (int jq = 0; jq < 4; ++jq)
            atomicAdd(&C[(size_t)(o0 + to4 + i) * 256 + b0 + tb4 + jq], acc[i][jq]);
}

__global__ __launch_bounds__(256) void k_actbias(const float* __restrict__ raw,
                                                 const float* __restrict__ bias,
                                                 float* __restrict__ out) {
    const int k = blockIdx.x, b = threadIdx.x;
    out[k * 256 + b] = fmaxf(raw[k * 256 + b] + bias[k], 0.f);
}

__global__ __launch_bounds__(256) void k_fc3(const float* __restrict__ fc2raw,
                                             const float* __restrict__ fb2,
                                             const float* __restrict__ w3,
                                             const float* __restrict__ b3,
                                             float* __restrict__ out) {
    const int b = threadIdx.x;
    float l0 = b3[0], l1 = b3[1];
    for (int k = 0; k < 256; ++k) {
        const float a = fmaxf(fc2raw[k * 256 + b] + fb2[k], 0.f);
        l0 = fmaf(w3[k], a, l0);
        l1 = fmaf(w3[256 + k], a, l1);
    }
    out[2 * b] = l0;
    out[2 * b + 1] = l1;
    const float mx = fmaxf(l0, l1);
    const float e0 = expf(l0 - mx), e1 = expf(l1 - mx);
    const float inv = 1.f / (e0 + e1);
    out[512 + 2 * b] = e0 * inv;
    out[513 + 2 * b] = e1 * inv;
    out[1024 + b] = (l1 > l0) ? 1.f : 0.f;
}

extern "C" void kernel_launch(void* const* d_in, const int* in_sizes, int n_in,
                              void* d_out, int out_size, void* d_ws, size_t ws_size,
                              hipStream_t stream) {
    const float* x        = (const float*)d_in[0];
    const float* start_w  = (const float*)d_in[1];
    const float* filter_w = (const float*)d_in[2];
    const float* gate_w   = (const float*)d_in[3];
    const float* res_w    = (const float*)d_in[4];
    const float* skip_w   = (const float*)d_in[5];
    const float* e1w      = (const float*)d_in[6];
    const float* e1b      = (const float*)d_in[7];
    const float* e2w      = (const float*)d_in[8];
    const float* e2b      = (const float*)d_in[9];
    const float* w1       = (const float*)d_in[10];
    const float* fb1      = (const float*)d_in[11];
    const float* w2       = (const float*)d_in[12];
    const float* fb2      = (const float*)d_in[13];
    const float* w3       = (const float*)d_in[14];
    const float* b3       = (const float*)d_in[15];

    float* ws = (float*)d_ws;

    const long o_h0   = 0;
    const long o_p2   = 10485760;
    const long o_fc1  = 13082624;
    const long o_fc2  = 13344768;
    const long o_wbf  = 13410304;
    const long o_wfg  = 13492224;
    const long o_wr   = 13516800;
    const long o_act1 = 13529088;
    const long o_G    = 13791232;

    long budget = (long)((double)ws_size * 0.94 / 4.0);
    int dB = 1;
    for (int d = 317; d >= 1; --d) {
        long mch = 256L * (4L * d + 3), hs = mch + 4096;
        long tot = o_G + 192L * mch + lmax_(128L * mch, 64L * hs);
        if (tot <= budget) { dB = d; break; }
    }
    int K = (317 + dB - 1) / dB;
    dB = (317 + K - 1) / K;
    const long MchA  = 256L * (4L * dB + 3);
    const long HSPAN = MchA + 4096;
    const long o_X   = o_G + 192L * MchA;
    const long P1S   = 256L * (2L * dB + 1);

    float* h0   = ws + o_h0;
    float* p2   = ws + o_p2;
    float* fc1r = ws + o_fc1;
    float* fc2r = ws + o_fc2;
    unsigned short* swt_hi = (unsigned short*)(ws + o_wbf);
    unsigned short* swt_lo = swt_hi + 49152;
    unsigned short* e1t_hi = swt_lo + 49152;
    unsigned short* e1t_lo = e1t_hi + 32768;
    unsigned short* wfg_hi = (unsigned short*)(ws + o_wfg);
    unsigned short* wfg_lo = wfg_hi + 24576;
    unsigned short* wr_hi  = (unsigned short*)(ws + o_wr);
    unsigned short* wr_lo  = wr_hi + 12288;
    float* act1 = ws + o_act1;
    float* G    = ws + o_G;
    float* hA   = ws + o_X;
    float* hB   = ws + o_X + 32L * HSPAN;
    float* y1c  = ws + o_X;
    float* p1c  = ws + o_G;
    float* e2c  = ws + o_G + 128L * P1S;

    k_zero<<<1280, 256, 0, stream>>>(fc1r, 327680);
    k_start<<<1280, 256, 0, stream>>>(x, start_w, h0);
    k_prep<<<192, 256, 0, stream>>>(skip_w, e1w, filter_w, gate_w, res_w,
                                    swt_hi, swt_lo, e1t_hi, e1t_lo,
                                    wfg_hi, wfg_lo, wr_hi, wr_lo);

    const int Mc[6]   = {327424, 327168, 326656, 326400, 326144, 325632};
    const int NpmP[6] = {256, 256, 512, 256, 256, 512};
    const int pN[6]   = {0, 256, 512, 0, 256, 512};
    const int so_[6]  = {1792, 1536, 1024, 768, 512, 0};
    const int JloO[6] = {-1536, -1280, -768, -768, -512, 0};

    for (int c = 0; c < K; ++c) {
        const int A = c * dB;
        int B = A + dB; if (B > 317) B = 317;
        const int dBc = B - A;
        const int M0 = 1024 * A;
        int tmax = 4 * B + 3; if (tmax > 1272) tmax = 1272;
        const int Tt = tmax - 4 * A;
        const int M1 = M0 + 256 * Tt;

        int Jlo[6], Jhi[6];
        for (int q = 0; q < 6; ++q) {
            int lo = M0 + JloO[q]; if (lo < 0) lo = 0;
            int hi = M1 + so_[q];  if (hi > Mc[q]) hi = Mc[q];
            Jlo[q] = lo; Jhi[q] = hi;
        }

        for (int q = 0; q < 6; ++q) {
            const float* hin = (q == 0) ? h0 : ((q & 1) ? hA : hB);
            const int hinBase   = (q == 0) ? 0 : Jlo[q - 1];
            const int hinStride = (q == 0) ? MCAP : (int)HSPAN;
            float* hout = (q & 1) ? hB : hA;
            const int Jcnt = Jhi[q] - Jlo[q];     // % 128 == 0
            k_layer_m<<<Jcnt / 128, 256, 0, stream>>>(
                hin, hinBase, hinStride, hout, Jlo[q], (int)HSPAN,
                G + (long)q * 32 * MchA, (int)MchA,
                wfg_hi + q * 4096, wfg_lo + q * 4096,
                wr_hi + q * 2048, wr_lo + q * 2048,
                Jlo[q], NpmP[q], pN[q], so_[q], M0, M1, (q < 5) ? 1 : 0);
        }

        const int Mchc = 256 * Tt;
        k_skip_end1_m<<<Mchc / 64, 256, 0, stream>>>(
            G, swt_hi, swt_lo, e1t_hi, e1t_lo, e1b, y1c, (int)MchA);
        const int T1c = 2 * dBc + 1;
        k_pool1_c<<<dim3(T1c, 128), 256, 0, stream>>>(y1c, p1c, (int)MchA, (int)P1S);
        k_end2_c<<<T1c, 256, 0, stream>>>(p1c, e2w, e2b, e2c, (int)P1S);
        k_pool2_c<<<dim3(dBc, 32), 256, 0, stream>>>(e2c, p2, (int)P1S, A);
    }

    k_gemm64<<<dim3(16, 4, 16), 256, 0, stream>>>(w1, p2, fc1r, 10144, 634);
    k_actbias<<<1024, 256, 0, stream>>>(fc1r, fb1, act1);
    k_gemm64<<<dim3(4, 4, 4), 256, 0, stream>>>(w2, act1, fc2r, 1024, 256);
    k_fc3<<<1, 256, 0, stream>>>(fc2r, fb2, w3, b3, (float*)d_out);
}

// Round 7
// 898.283 us; speedup vs baseline: 4.5729x; 1.2927x over previous
//
#include <hip/hip_runtime.h>
#include <math.h>

// ---------------------------------------------------------------------------
// WaveNet forward. Layers, skip/end1, end2(+fused pool1), FC1 all via
// split-bf16 MFMA (3-term hi*hi+hi*lo+lo*hi, rel err ~2^-16). Flat layout
// (channel, time, batch) => buf[c][t*256+n]; dilate() is a reinterpretation.
// R7: FC1 f32-VALU gemm64 was pinned at 169us (5x its 34us issue floor,
// VALUBusy 26%) -> k_fc1_m MFMA. pool1+end2 fused into k_pe2_m (kills p1
// buffer: -166MB traffic, -1 dispatch). Layers/SE unchanged for attribution.
// ---------------------------------------------------------------------------

#define MCAP 327680

typedef short v8s __attribute__((ext_vector_type(8)));
typedef float v4f __attribute__((ext_vector_type(4)));

static inline long lmax_(long a, long b) { return a > b ? a : b; }

__device__ inline unsigned short rnbf(float x) {
    unsigned u = __float_as_uint(x);
    return (unsigned short)((u + 0x7FFFu + ((u >> 16) & 1u)) >> 16);
}
__device__ inline void split2(float v, unsigned short& h, unsigned short& l) {
    h = rnbf(v);
    const float hf = __uint_as_float(((unsigned)h) << 16);
    l = rnbf(v - hf);
}

__global__ __launch_bounds__(256) void k_zero(float* __restrict__ p, int n) {
    int i = blockIdx.x * 256 + threadIdx.x;
    if (i < n) p[i] = 0.f;
}

__global__ __launch_bounds__(256) void k_start(const float* __restrict__ x,
                                               const float* __restrict__ sw,
                                               float* __restrict__ h0) {
    int j = blockIdx.x * 256 + threadIdx.x;
    int t = j >> 8, n = j & 255;
    float xv[5];
#pragma unroll
    for (int i = 0; i < 5; ++i) xv[i] = x[n * 6400 + i * 1280 + t];
#pragma unroll
    for (int o = 0; o < 32; ++o) {
        float acc = 0.f;
#pragma unroll
        for (int i = 0; i < 5; ++i) acc = fmaf(sw[o * 5 + i], xv[i], acc);
        h0[o * MCAP + j] = acc;
    }
}

// Prepack small weights (split bf16).
__global__ __launch_bounds__(256) void k_prep(const float* __restrict__ skw,
                                              const float* __restrict__ e1w,
                                              const float* __restrict__ fw,
                                              const float* __restrict__ gw,
                                              const float* __restrict__ rw,
                                              const float* __restrict__ e2w,
                                              unsigned short* __restrict__ swt_hi,
                                              unsigned short* __restrict__ swt_lo,
                                              unsigned short* __restrict__ e1t_hi,
                                              unsigned short* __restrict__ e1t_lo,
                                              unsigned short* __restrict__ wfg_hi,
                                              unsigned short* __restrict__ wfg_lo,
                                              unsigned short* __restrict__ wr_hi,
                                              unsigned short* __restrict__ wr_lo,
                                              unsigned short* __restrict__ e2s_hi,
                                              unsigned short* __restrict__ e2s_lo) {
    int idx = blockIdx.x * 256 + threadIdx.x;
    if (idx < 49152) {
        int ch = idx / 192, k = idx - ch * 192;
        int l = k >> 5, i = k & 31;
        unsigned short h, lo;
        split2(skw[l * 8192 + ch * 32 + i], h, lo);
        swt_hi[idx] = h; swt_lo[idx] = lo;
    }
    if (idx < 32768) {
        unsigned short h, lo;
        split2(e1w[idx], h, lo);
        e1t_hi[idx] = h; e1t_lo[idx] = lo;
    }
    if (idx < 24576) {
        int l = idx >> 12, r = idx & 4095;
        int row = r >> 6, k = r & 63;
        int o = row & 31, i = k & 31, tap = k >> 5;
        const float* src = (row < 32) ? fw : gw;
        unsigned short h, lo;
        split2(src[l * 2048 + o * 64 + i * 2 + tap], h, lo);
        wfg_hi[idx] = h; wfg_lo[idx] = lo;
    }
    if (idx < 12288) {
        int l = idx >> 11, r = idx & 2047;
        int o = r >> 6, k = r & 63, i = k & 31;
        unsigned short h, lo;
        split2(rw[l * 1024 + o * 32 + i], h, lo);
        wr_hi[idx] = h; wr_lo[idx] = lo;
    }
    if (idx < 4096) {               // end2 weights (32 co x 128 ci, row-major)
        unsigned short h, lo;
        split2(e2w[idx], h, lo);
        e2s_hi[idx] = h; e2s_lo[idx] = lo;
    }
}

// Split fc1 weights (1024 x 10144, row-major, k-contiguous).
__global__ __launch_bounds__(256) void k_prep_w1(const float* __restrict__ w1,
                                                 unsigned short* __restrict__ hi,
                                                 unsigned short* __restrict__ lo) {
    int idx = blockIdx.x * 256 + threadIdx.x;
    if (idx < 10387456) {
        unsigned short h, l;
        split2(w1[idx], h, l);
        hi[idx] = h; lo[idx] = l;
    }
}

// One dilated gated layer via split-bf16 MFMA. 128-col tile, Jcnt % 128 == 0.
__global__ __launch_bounds__(256) void k_layer_m(
    const float* __restrict__ hin, const int hinBase, const int hinStride,
    float* __restrict__ hout, const int houtBase, const int houtStride,
    float* __restrict__ gsl, const int gStride,
    const unsigned short* __restrict__ wfg_hi, const unsigned short* __restrict__ wfg_lo,
    const unsigned short* __restrict__ wr_hi, const unsigned short* __restrict__ wr_lo,
    const int Jlo, const int NpmP, const int padN,
    const int so_, const int M0, const int M1, const int doRes)
{
    __shared__ unsigned short AT[128 * 136];
    __shared__ unsigned short GT[128 * 72];

    const int tid = threadIdx.x;
    const int j0 = Jlo + blockIdx.x * 128;

    {
        const int col = tid & 127;
        const int kg = tid >> 7;
        unsigned short* bh = &AT[col * 136 + kg * 32];
        unsigned short* bl = &AT[col * 136 + 64 + kg * 32];
        if (kg == 0 && j0 < padN) {
            uint4 z; z.x = z.y = z.z = z.w = 0u;
#pragma unroll
            for (int ch = 0; ch < 32; ch += 8) {
                *(uint4*)&bh[ch] = z;
                *(uint4*)&bl[ch] = z;
            }
        } else {
            const int off = (kg == 0) ? (j0 - padN) : (j0 + NpmP);
            const float* p = hin + (off - hinBase) + col;
#pragma unroll
            for (int ch = 0; ch < 32; ch += 8) {
                alignas(16) unsigned short h8[8], l8[8];
#pragma unroll
                for (int u = 0; u < 8; ++u)
                    split2(p[(size_t)(ch + u) * hinStride], h8[u], l8[u]);
                *(uint4*)&bh[ch] = *(uint4*)h8;
                *(uint4*)&bl[ch] = *(uint4*)l8;
            }
        }
    }
    __syncthreads();

    const int lane = tid & 63;
    const int w    = tid >> 6;
    const int ch2  = w >> 1;
    const int mh   = w & 1;
    const int l15  = lane & 15;
    const int quad = lane >> 4;
    const int q8   = quad * 8;
    const int colb = ch2 * 64;

    v4f accf[4], accg[4];
#pragma unroll
    for (int nt = 0; nt < 4; ++nt) { accf[nt] = (v4f)(0.f); accg[nt] = (v4f)(0.f); }

#pragma unroll
    for (int kt = 0; kt < 2; ++kt) {
        const int frow = (mh * 16 + l15) * 64 + kt * 32 + q8;
        const int grow = (32 + mh * 16 + l15) * 64 + kt * 32 + q8;
        const v8s afh = *(const v8s*)&wfg_hi[frow];
        const v8s afl = *(const v8s*)&wfg_lo[frow];
        const v8s agh = *(const v8s*)&wfg_hi[grow];
        const v8s agl = *(const v8s*)&wfg_lo[grow];
#pragma unroll
        for (int nt = 0; nt < 4; ++nt) {
            const int col = colb + nt * 16 + l15;
            const v8s bh = *(const v8s*)&AT[col * 136 + kt * 32 + q8];
            const v8s bl = *(const v8s*)&AT[col * 136 + 64 + kt * 32 + q8];
            accf[nt] = __builtin_amdgcn_mfma_f32_16x16x32_bf16(afh, bh, accf[nt], 0, 0, 0);
            accf[nt] = __builtin_amdgcn_mfma_f32_16x16x32_bf16(afh, bl, accf[nt], 0, 0, 0);
            accf[nt] = __builtin_amdgcn_mfma_f32_16x16x32_bf16(afl, bh, accf[nt], 0, 0, 0);
            accg[nt] = __builtin_amdgcn_mfma_f32_16x16x32_bf16(agh, bh, accg[nt], 0, 0, 0);
            accg[nt] = __builtin_amdgcn_mfma_f32_16x16x32_bf16(agh, bl, accg[nt], 0, 0, 0);
            accg[nt] = __builtin_amdgcn_mfma_f32_16x16x32_bf16(agl, bh, accg[nt], 0, 0, 0);
        }
    }

    float gated[4][4];
#pragma unroll
    for (int nt = 0; nt < 4; ++nt)
#pragma unroll
        for (int r = 0; r < 4; ++r) {
            const float f = accf[nt][r];
            const float g = accg[nt][r];
            const float th = 1.f - 2.f / (__expf(2.f * f) + 1.f);
            const float sg = 1.f / (1.f + __expf(-g));
            gated[nt][r] = th * sg;
        }

    const int m0c = j0 - so_;
    if (m0c >= M0 && m0c < M1) {
#pragma unroll
        for (int nt = 0; nt < 4; ++nt)
#pragma unroll
            for (int r = 0; r < 4; ++r) {
                const int ch = mh * 16 + quad * 4 + r;
                const int m = (m0c - M0) + colb + nt * 16 + l15;
                gsl[(size_t)ch * gStride + m] = gated[nt][r];
            }
    }

    if (doRes) {
#pragma unroll
        for (int nt = 0; nt < 4; ++nt)
#pragma unroll
            for (int r = 0; r < 4; ++r) {
                const int ch = mh * 16 + quad * 4 + r;
                const int col = colb + nt * 16 + l15;
                unsigned short h, lo;
                split2(gated[nt][r], h, lo);
                GT[col * 72 + ch] = h;
                GT[col * 72 + 32 + ch] = lo;
            }
        __syncthreads();

        v4f accr[4];
#pragma unroll
        for (int nt = 0; nt < 4; ++nt) accr[nt] = (v4f)(0.f);
#pragma unroll
        for (int kt = 0; kt < 2; ++kt) {
            const int row = (mh * 16 + l15) * 64 + kt * 32 + q8;
            const v8s arh = *(const v8s*)&wr_hi[row];
            const v8s arl = *(const v8s*)&wr_lo[row];
#pragma unroll
            for (int nt = 0; nt < 4; ++nt) {
                const int col = colb + nt * 16 + l15;
                const v8s b = *(const v8s*)&GT[col * 72 + kt * 32 + q8];
                accr[nt] = __builtin_amdgcn_mfma_f32_16x16x32_bf16(arh, b, accr[nt], 0, 0, 0);
                accr[nt] = __builtin_amdgcn_mfma_f32_16x16x32_bf16(arl, b, accr[nt], 0, 0, 0);
            }
        }

#pragma unroll
        for (int nt = 0; nt < 4; ++nt)
#pragma unroll
            for (int r = 0; r < 4; ++r) {
                const int o = mh * 16 + quad * 4 + r;
                const int col = colb + nt * 16 + l15;
                const unsigned hh = AT[col * 136 + 32 + o];
                const unsigned ll = AT[col * 136 + 64 + 32 + o];
                const float tap1 = __uint_as_float(hh << 16) + __uint_as_float(ll << 16);
                hout[(size_t)o * houtStride + (j0 - houtBase) + col] = accr[nt][r] + tap1;
            }
    }
}

// Fused skip -> relu -> end1 + bias -> relu -> y1 (split-bf16 MFMA).
__global__ __launch_bounds__(256, 2) void k_skip_end1_m(
    const float* __restrict__ g,
    const unsigned short* __restrict__ swt_hi, const unsigned short* __restrict__ swt_lo,
    const unsigned short* __restrict__ e1t_hi, const unsigned short* __restrict__ e1t_lo,
    const float* __restrict__ b1, float* __restrict__ y1, const int gs)
{
    __shared__ unsigned short U[33792];
    unsigned short* gt_hi = U;
    unsigned short* gt_lo = U + 12800;
    unsigned short* st_hi = U;
    unsigned short* st_lo = U + 16896;

    const int tid  = threadIdx.x;
    const int m0   = blockIdx.x * 64;
    const int lane = tid & 63;
    const int w    = tid >> 6;
    const int l15  = lane & 15;
    const int q8   = (lane >> 4) * 8;
    const int rbase = (lane >> 4) * 4;

    {
        const int scol = tid & 63;
        const int ks0  = (tid >> 6) * 8;
        for (int kc = 0; kc < 192; kc += 32) {
            alignas(16) unsigned short h8[8], l8[8];
#pragma unroll
            for (int j = 0; j < 8; ++j) {
                const int k = kc + ks0 + j;
                const float v = g[(size_t)(k >> 5) * 32 * gs + (size_t)(k & 31) * gs + m0 + scol];
                split2(v, h8[j], l8[j]);
            }
            *(v8s*)&gt_hi[scol * 200 + kc + ks0] = *(v8s*)h8;
            *(v8s*)&gt_lo[scol * 200 + kc + ks0] = *(v8s*)l8;
        }
    }
    __syncthreads();

    v4f acc1[4][4];
#pragma unroll
    for (int a = 0; a < 4; ++a)
#pragma unroll
        for (int b = 0; b < 4; ++b) acc1[a][b] = (v4f)(0.f);

    for (int kc = 0; kc < 192; kc += 32) {
        v8s ah[4], al[4], bh[4], bl[4];
#pragma unroll
        for (int t = 0; t < 4; ++t) {
            const int row = (w * 64 + t * 16 + l15) * 192 + kc + q8;
            ah[t] = *(const v8s*)&swt_hi[row];
            al[t] = *(const v8s*)&swt_lo[row];
            const int bo = (t * 16 + l15) * 200 + kc + q8;
            bh[t] = *(const v8s*)&gt_hi[bo];
            bl[t] = *(const v8s*)&gt_lo[bo];
        }
#pragma unroll
        for (int ct = 0; ct < 4; ++ct)
#pragma unroll
            for (int nt = 0; nt < 4; ++nt) {
                acc1[ct][nt] = __builtin_amdgcn_mfma_f32_16x16x32_bf16(ah[ct], bh[nt], acc1[ct][nt], 0, 0, 0);
                acc1[ct][nt] = __builtin_amdgcn_mfma_f32_16x16x32_bf16(ah[ct], bl[nt], acc1[ct][nt], 0, 0, 0);
                acc1[ct][nt] = __builtin_amdgcn_mfma_f32_16x16x32_bf16(al[ct], bh[nt], acc1[ct][nt], 0, 0, 0);
            }
    }
    __syncthreads();

#pragma unroll
    for (int ct = 0; ct < 4; ++ct)
#pragma unroll
        for (int nt = 0; nt < 4; ++nt) {
            alignas(8) unsigned short sh[4], sl[4];
#pragma unroll
            for (int r = 0; r < 4; ++r) {
                const float v = fmaxf(acc1[ct][nt][r], 0.f);
                split2(v, sh[r], sl[r]);
            }
            const int ci  = w * 64 + ct * 16 + rbase;
            const int col = nt * 16 + l15;
            *(uint2*)&st_hi[col * 264 + ci] = *(uint2*)sh;
            *(uint2*)&st_lo[col * 264 + ci] = *(uint2*)sl;
        }
    __syncthreads();

    v4f acc2[2][4];
#pragma unroll
    for (int a = 0; a < 2; ++a)
#pragma unroll
        for (int b = 0; b < 4; ++b) acc2[a][b] = (v4f)(0.f);

    for (int kc = 0; kc < 256; kc += 32) {
        v8s ah[2], al[2], bh[4], bl[4];
#pragma unroll
        for (int t = 0; t < 2; ++t) {
            const int row = (w * 32 + t * 16 + l15) * 256 + kc + q8;
            ah[t] = *(const v8s*)&e1t_hi[row];
            al[t] = *(const v8s*)&e1t_lo[row];
        }
#pragma unroll
        for (int t = 0; t < 4; ++t) {
            const int bo = (t * 16 + l15) * 264 + kc + q8;
            bh[t] = *(const v8s*)&st_hi[bo];
            bl[t] = *(const v8s*)&st_lo[bo];
        }
#pragma unroll
        for (int ct = 0; ct < 2; ++ct)
#pragma unroll
            for (int nt = 0; nt < 4; ++nt) {
                acc2[ct][nt] = __builtin_amdgcn_mfma_f32_16x16x32_bf16(ah[ct], bh[nt], acc2[ct][nt], 0, 0, 0);
                acc2[ct][nt] = __builtin_amdgcn_mfma_f32_16x16x32_bf16(ah[ct], bl[nt], acc2[ct][nt], 0, 0, 0);
                acc2[ct][nt] = __builtin_amdgcn_mfma_f32_16x16x32_bf16(al[ct], bh[nt], acc2[ct][nt], 0, 0, 0);
            }
    }

#pragma unroll
    for (int ct = 0; ct < 2; ++ct) {
        const int cobase = w * 32 + ct * 16 + rbase;
        float bb[4];
#pragma unroll
        for (int r = 0; r < 4; ++r) bb[r] = b1[cobase + r];
#pragma unroll
        for (int nt = 0; nt < 4; ++nt) {
            const int col = m0 + nt * 16 + l15;
#pragma unroll
            for (int r = 0; r < 4; ++r)
                y1[(size_t)(cobase + r) * gs + col] = fmaxf(acc2[ct][nt][r] + bb[r], 0.f);
        }
    }
}

// Fused maxpool3s2 + end2 (128->32) via split-bf16 MFMA. 64 pooled cols/block.
// Stage SP[col][136]: pooled relu-domain values, K=128 ci. Wave w: co-half
// mh=w&1 (rows mh*16..), col-half colh=w>>1 (2 nt of 16 cols).
__global__ __launch_bounds__(256) void k_pe2_m(
    const float* __restrict__ y1c,
    const unsigned short* __restrict__ e2s_hi, const unsigned short* __restrict__ e2s_lo,
    const float* __restrict__ b2, float* __restrict__ e2c,
    const int gs, const int p1s)
{
    __shared__ unsigned short SP[2 * 64 * 136];
    unsigned short* sp_hi = SP;
    unsigned short* sp_lo = SP + 64 * 136;

    const int tid = threadIdx.x;
    const int m0 = blockIdx.x * 64;     // pooled col base (t1*256+n domain)
    const int tp = m0 >> 8;             // constant within block (m0 % 256 <= 192)
    const int nb = m0 & 255;

    {
        const int col = tid & 63;
        const int cig = tid >> 6;        // 0..3 -> ci groups of 32
        const int base = 2 * tp * 256 + nb + col;
#pragma unroll
        for (int u8 = 0; u8 < 4; ++u8) {
            alignas(16) unsigned short h8[8], l8[8];
#pragma unroll
            for (int u = 0; u < 8; ++u) {
                const int ci = cig * 32 + u8 * 8 + u;
                const float* yp = y1c + (size_t)ci * gs + base;
                const float v = fmaxf(fmaxf(yp[0], yp[256]), yp[512]);
                split2(v, h8[u], l8[u]);
            }
            *(uint4*)&sp_hi[col * 136 + cig * 32 + u8 * 8] = *(uint4*)h8;
            *(uint4*)&sp_lo[col * 136 + cig * 32 + u8 * 8] = *(uint4*)l8;
        }
    }
    __syncthreads();

    const int lane = tid & 63;
    const int w    = tid >> 6;
    const int mh   = w & 1;
    const int colh = w >> 1;
    const int l15  = lane & 15;
    const int quad = lane >> 4;
    const int q8   = quad * 8;

    v4f acc[2];
    acc[0] = (v4f)(0.f); acc[1] = (v4f)(0.f);

#pragma unroll
    for (int kc = 0; kc < 128; kc += 32) {
        const int row = (mh * 16 + l15) * 128 + kc + q8;
        const v8s ah = *(const v8s*)&e2s_hi[row];
        const v8s al = *(const v8s*)&e2s_lo[row];
#pragma unroll
        for (int nt = 0; nt < 2; ++nt) {
            const int col = colh * 32 + nt * 16 + l15;
            const v8s bh = *(const v8s*)&sp_hi[col * 136 + kc + q8];
            const v8s bl = *(const v8s*)&sp_lo[col * 136 + kc + q8];
            acc[nt] = __builtin_amdgcn_mfma_f32_16x16x32_bf16(ah, bh, acc[nt], 0, 0, 0);
            acc[nt] = __builtin_amdgcn_mfma_f32_16x16x32_bf16(ah, bl, acc[nt], 0, 0, 0);
            acc[nt] = __builtin_amdgcn_mfma_f32_16x16x32_bf16(al, bh, acc[nt], 0, 0, 0);
        }
    }

#pragma unroll
    for (int nt = 0; nt < 2; ++nt)
#pragma unroll
        for (int r = 0; r < 4; ++r) {
            const int co = mh * 16 + quad * 4 + r;
            const int col = m0 + colh * 32 + nt * 16 + l15;
            e2c[(size_t)co * p1s + col] = fmaxf(acc[nt][r] + b2[co], 0.f);
        }
}

__global__ __launch_bounds__(256) void k_pool2_c(const float* __restrict__ e2c,
                                                 float* __restrict__ p2,
                                                 const int p1s, const int A) {
    const int n = threadIdx.x, tl2 = blockIdx.x, co = blockIdx.y;
    const int base = co * p1s + tl2 * 512 + n;
    float v = fmaxf(fmaxf(e2c[base], e2c[base + 256]), e2c[base + 512]);
    p2[co * 81152 + (A + tl2) * 256 + n] = v;
}

// FC1 via split-bf16 MFMA: C[1024 x 256] += W1[1024 x 10144] @ P2[10144 x 256].
// grid (16, 4, 8): 64x64 tile, z = split-K over 1280-k slices. Atomic epilogue.
__global__ __launch_bounds__(256) void k_fc1_m(
    const unsigned short* __restrict__ w1s_hi, const unsigned short* __restrict__ w1s_lo,
    const float* __restrict__ p2, float* __restrict__ out)
{
    __shared__ unsigned short SB[2 * 64 * 40];
    unsigned short* sb_hi = SB;
    unsigned short* sb_lo = SB + 64 * 40;

    const int tid = threadIdx.x;
    const int o0 = blockIdx.x * 64;
    const int b0 = blockIdx.y * 64;
    const int k0 = blockIdx.z * 1280;
    const int kend = (k0 + 1280 < 10144) ? (k0 + 1280) : 10144;
    const int nch = (kend - k0) >> 5;

    const int lane = tid & 63;
    const int w    = tid >> 6;
    const int l15  = lane & 15;
    const int quad = lane >> 4;
    const int q8   = quad * 8;
    const int scol = tid & 63;
    const int kq   = tid >> 6;

    v4f acc[4];
#pragma unroll
    for (int nt = 0; nt < 4; ++nt) acc[nt] = (v4f)(0.f);

    for (int c = 0; c < nch; ++c) {
        const int kc = k0 + c * 32;
        alignas(16) unsigned short h8[8], l8[8];
#pragma unroll
        for (int j = 0; j < 8; ++j) {
            const float v = p2[(size_t)(kc + kq * 8 + j) * 256 + b0 + scol];
            split2(v, h8[j], l8[j]);
        }
        __syncthreads();
        *(v8s*)&sb_hi[scol * 40 + kq * 8] = *(v8s*)h8;
        *(v8s*)&sb_lo[scol * 40 + kq * 8] = *(v8s*)l8;
        __syncthreads();

        const int arow = (o0 + w * 16 + l15) * 10144 + kc + q8;
        const v8s ah = *(const v8s*)&w1s_hi[arow];
        const v8s al = *(const v8s*)&w1s_lo[arow];
#pragma unroll
        for (int nt = 0; nt < 4; ++nt) {
            const v8s bh = *(const v8s*)&sb_hi[(nt * 16 + l15) * 40 + q8];
            const v8s bl = *(const v8s*)&sb_lo[(nt * 16 + l15) * 40 + q8];
            acc[nt] = __builtin_amdgcn_mfma_f32_16x16x32_bf16(ah, bh, acc[nt], 0, 0, 0);
            acc[nt] = __builtin_amdgcn_mfma_f32_16x16x32_bf16(ah, bl, acc[nt], 0, 0, 0);
            acc[nt] = __builtin_amdgcn_mfma_f32_16x16x32_bf16(al, bh, acc[nt], 0, 0, 0);
        }
    }

#pragma unroll
    for (int nt = 0; nt < 4; ++nt)
#pragma unroll
        for (int r = 0; r < 4; ++r)
            atomicAdd(&out[(size_t)(o0 + w * 16 + quad * 4 + r) * 256 + b0 + nt * 16 + l15],
                      acc[nt][r]);
}

// Tiled f32 GEMM (used for FC2 only): C[M x 256] += A[M x Ktot] * B[Ktot x 256]
__global__ __launch_bounds__(256) void k_gemm64(const float* __restrict__ A,
                                                const float* __restrict__ B,
                                                float* __restrict__ C,
                                                const int Ktot, const int KC) {
    __shared__ float sA[32 * 65];
    __shared__ float sB[32 * 68];

    const int tid = threadIdx.x;
    const int o0 = blockIdx.x * 64;
    const int b0 = blockIdx.y * 64;
    const int k0 = blockIdx.z * KC;

    float acc[4][4];
#pragma unroll
    for (int i = 0; i < 4; ++i)
#pragma unroll
        for (int jq = 0; jq < 4; ++jq) acc[i][jq] = 0.f;

    const int ao  = tid >> 2;
    const int ak8 = (tid & 3) * 8;
    const int bk  = tid >> 3;
    const int bb8 = (tid & 7) * 8;
    const int to4 = (tid & 15) * 4;
    const int tb4 = (tid >> 4) * 4;

    for (int kc = 0; kc < KC; kc += 32) {
        const int kcLen = (KC - kc < 32) ? (KC - kc) : 32;
        const float* ap = A + (size_t)(o0 + ao) * Ktot + k0 + kc + ak8;
#pragma unroll
        for (int i = 0; i < 8; ++i) {
            float v = (ak8 + i < kcLen) ? ap[i] : 0.f;
            sA[(ak8 + i) * 65 + ao] = v;
        }
        if (bk < kcLen) {
            const float* bp = B + (size_t)(k0 + kc + bk) * 256 + b0 + bb8;
            const float4 v0 = *(const float4*)bp;
            const float4 v1 = *(const float4*)(bp + 4);
            *(float4*)&sB[bk * 68 + bb8] = v0;
            *(float4*)&sB[bk * 68 + bb8 + 4] = v1;
        } else {
            float4 z; z.x = z.y = z.z = z.w = 0.f;
            *(float4*)&sB[bk * 68 + bb8] = z;
            *(float4*)&sB[bk * 68 + bb8 + 4] = z;
        }
        __syncthreads();

#pragma unroll 8
        for (int kk = 0; kk < 32; ++kk) {
            const float4 av = *(const float4*)&sA[kk * 65 + to4];
            const float4 bv = *(const float4*)&sB[kk * 68 + tb4];
            const float aa[4] = {av.x, av.y, av.z, av.w};
#pragma unroll
            for (int i = 0; i < 4; ++i) {
                acc[i][0] = fmaf(aa[i], bv.x, acc[i][0]);
                acc[i][1] = fmaf(aa[i], bv.y, acc[i][1]);
                acc[i][2] = fmaf(aa[i], bv.z, acc[i][2]);
                acc[i][3] = fmaf(aa[i], bv.w, acc[i][3]);
            }
        }
        __syncthreads();
    }

#pragma unroll
    for (int i = 0; i < 4; ++i)
#pragma unroll
        for (int jq = 0; jq < 4; ++jq)
            atomicAdd(&C[(size_t)(o0 + to4 + i) * 256 + b0 + tb4 + jq], acc[i][jq]);
}

__global__ __launch_bounds__(256) void k_actbias(const float* __restrict__ raw,
                                                 const float* __restrict__ bias,
                                                 float* __restrict__ out) {
    const int k = blockIdx.x, b = threadIdx.x;
    out[k * 256 + b] = fmaxf(raw[k * 256 + b] + bias[k], 0.f);
}

__global__ __launch_bounds__(256) void k_fc3(const float* __restrict__ fc2raw,
                                             const float* __restrict__ fb2,
                                             const float* __restrict__ w3,
                                             const float* __restrict__ b3,
                                             float* __restrict__ out) {
    const int b = threadIdx.x;
    float l0 = b3[0], l1 = b3[1];
    for (int k = 0; k < 256; ++k) {
        const float a = fmaxf(fc2raw[k * 256 + b] + fb2[k], 0.f);
        l0 = fmaf(w3[k], a, l0);
        l1 = fmaf(w3[256 + k], a, l1);
    }
    out[2 * b] = l0;
    out[2 * b + 1] = l1;
    const float mx = fmaxf(l0, l1);
    const float e0 = expf(l0 - mx), e1 = expf(l1 - mx);
    const float inv = 1.f / (e0 + e1);
    out[512 + 2 * b] = e0 * inv;
    out[513 + 2 * b] = e1 * inv;
    out[1024 + b] = (l1 > l0) ? 1.f : 0.f;
}

extern "C" void kernel_launch(void* const* d_in, const int* in_sizes, int n_in,
                              void* d_out, int out_size, void* d_ws, size_t ws_size,
                              hipStream_t stream) {
    const float* x        = (const float*)d_in[0];
    const float* start_w  = (const float*)d_in[1];
    const float* filter_w = (const float*)d_in[2];
    const float* gate_w   = (const float*)d_in[3];
    const float* res_w    = (const float*)d_in[4];
    const float* skip_w   = (const float*)d_in[5];
    const float* e1w      = (const float*)d_in[6];
    const float* e1b      = (const float*)d_in[7];
    const float* e2w      = (const float*)d_in[8];
    const float* e2b      = (const float*)d_in[9];
    const float* w1       = (const float*)d_in[10];
    const float* fb1      = (const float*)d_in[11];
    const float* w2       = (const float*)d_in[12];
    const float* fb2      = (const float*)d_in[13];
    const float* w3       = (const float*)d_in[14];
    const float* b3       = (const float*)d_in[15];

    float* ws = (float*)d_ws;

    const long o_h0   = 0;            // 10,485,760
    const long o_p2   = 10485760;     // 2,596,864
    const long o_fc1  = 13082624;     // 262,144
    const long o_fc2  = 13344768;     // 65,536
    const long o_wbf  = 13410304;     // 81,920 (skip/end1 splits)
    const long o_wfg  = 13492224;     // 24,576
    const long o_wr   = 13516800;     // 12,288
    const long o_e2s  = 13529088;     // 4,096 (end2 splits)
    const long o_act1 = 13533184;     // 262,144
    const long o_w1s  = 13795328;     // 10,387,456 (w1 hi+lo u16)
    const long o_G    = 24182784;

    long budget = (long)((double)ws_size * 0.94 / 4.0);
    int dB = 1;
    for (int d = 317; d >= 1; --d) {
        long mch = 256L * (4L * d + 3), hs = mch + 4096;
        long tot = o_G + 192L * mch + lmax_(128L * mch, 64L * hs);
        if (tot <= budget) { dB = d; break; }
    }
    int K = (317 + dB - 1) / dB;
    dB = (317 + K - 1) / K;
    const long MchA  = 256L * (4L * dB + 3);
    const long HSPAN = MchA + 4096;
    const long o_X   = o_G + 192L * MchA;
    const long P1S   = 256L * (2L * dB + 1);

    float* h0   = ws + o_h0;
    float* p2   = ws + o_p2;
    float* fc1r = ws + o_fc1;
    float* fc2r = ws + o_fc2;
    unsigned short* swt_hi = (unsigned short*)(ws + o_wbf);
    unsigned short* swt_lo = swt_hi + 49152;
    unsigned short* e1t_hi = swt_lo + 49152;
    unsigned short* e1t_lo = e1t_hi + 32768;
    unsigned short* wfg_hi = (unsigned short*)(ws + o_wfg);
    unsigned short* wfg_lo = wfg_hi + 24576;
    unsigned short* wr_hi  = (unsigned short*)(ws + o_wr);
    unsigned short* wr_lo  = wr_hi + 12288;
    unsigned short* e2s_hi = (unsigned short*)(ws + o_e2s);
    unsigned short* e2s_lo = e2s_hi + 4096;
    unsigned short* w1s_hi = (unsigned short*)(ws + o_w1s);
    unsigned short* w1s_lo = w1s_hi + 10387456;
    float* act1 = ws + o_act1;
    float* G    = ws + o_G;
    float* hA   = ws + o_X;
    float* hB   = ws + o_X + 32L * HSPAN;
    float* y1c  = ws + o_X;                 // aliases hA/hB (dead by then)
    float* e2c  = ws + o_G;                 // aliases G (dead after skip_end1)

    k_zero<<<1280, 256, 0, stream>>>(fc1r, 327680);
    k_start<<<1280, 256, 0, stream>>>(x, start_w, h0);
    k_prep<<<192, 256, 0, stream>>>(skip_w, e1w, filter_w, gate_w, res_w, e2w,
                                    swt_hi, swt_lo, e1t_hi, e1t_lo,
                                    wfg_hi, wfg_lo, wr_hi, wr_lo,
                                    e2s_hi, e2s_lo);
    k_prep_w1<<<40576, 256, 0, stream>>>(w1, w1s_hi, w1s_lo);

    const int Mc[6]   = {327424, 327168, 326656, 326400, 326144, 325632};
    const int NpmP[6] = {256, 256, 512, 256, 256, 512};
    const int pN[6]   = {0, 256, 512, 0, 256, 512};
    const int so_[6]  = {1792, 1536, 1024, 768, 512, 0};
    const int JloO[6] = {-1536, -1280, -768, -768, -512, 0};

    for (int c = 0; c < K; ++c) {
        const int A = c * dB;
        int B = A + dB; if (B > 317) B = 317;
        const int dBc = B - A;
        const int M0 = 1024 * A;
        int tmax = 4 * B + 3; if (tmax > 1272) tmax = 1272;
        const int Tt = tmax - 4 * A;
        const int M1 = M0 + 256 * Tt;

        int Jlo[6], Jhi[6];
        for (int q = 0; q < 6; ++q) {
            int lo = M0 + JloO[q]; if (lo < 0) lo = 0;
            int hi = M1 + so_[q];  if (hi > Mc[q]) hi = Mc[q];
            Jlo[q] = lo; Jhi[q] = hi;
        }

        for (int q = 0; q < 6; ++q) {
            const float* hin = (q == 0) ? h0 : ((q & 1) ? hA : hB);
            const int hinBase   = (q == 0) ? 0 : Jlo[q - 1];
            const int hinStride = (q == 0) ? MCAP : (int)HSPAN;
            float* hout = (q & 1) ? hB : hA;
            const int Jcnt = Jhi[q] - Jlo[q];     // % 128 == 0
            k_layer_m<<<Jcnt / 128, 256, 0, stream>>>(
                hin, hinBase, hinStride, hout, Jlo[q], (int)HSPAN,
                G + (long)q * 32 * MchA, (int)MchA,
                wfg_hi + q * 4096, wfg_lo + q * 4096,
                wr_hi + q * 2048, wr_lo + q * 2048,
                Jlo[q], NpmP[q], pN[q], so_[q], M0, M1, (q < 5) ? 1 : 0);
        }

        const int Mchc = 256 * Tt;
        k_skip_end1_m<<<Mchc / 64, 256, 0, stream>>>(
            G, swt_hi, swt_lo, e1t_hi, e1t_lo, e1b, y1c, (int)MchA);
        const int T1c = 2 * dBc + 1;
        k_pe2_m<<<T1c * 4, 256, 0, stream>>>(
            y1c, e2s_hi, e2s_lo, e2b, e2c, (int)MchA, (int)P1S);
        k_pool2_c<<<dim3(dBc, 32), 256, 0, stream>>>(e2c, p2, (int)P1S, A);
    }

    k_fc1_m<<<dim3(16, 4, 8), 256, 0, stream>>>(w1s_hi, w1s_lo, p2, fc1r);
    k_actbias<<<1024, 256, 0, stream>>>(fc1r, fb1, act1);
    k_gemm64<<<dim3(4, 4, 4), 256, 0, stream>>>(w2, act1, fc2r, 1024, 256);
    k_fc3<<<1, 256, 0, stream>>>(fc2r, fb2, w3, b3, (float*)d_out);
}

// Round 8
// 878.411 us; speedup vs baseline: 4.6764x; 1.0226x over previous
//
#include <hip/hip_runtime.h>
#include <math.h>

// ---------------------------------------------------------------------------
// WaveNet forward. Layers, skip/end1, end2(+fused pool1), FC1 all via
// split-bf16 MFMA (3-term hi*hi+hi*lo+lo*hi, rel err ~2^-16). Flat layout
// (channel, time, batch) => buf[c][t*256+n]; dilate() is a reinterpretation.
// R8: all split-bf16 activations (h ping-pong, G slab) stored PRE-SPLIT as
// packed u32 (lo<<16 | hi), written once at the producer. Removes ~400 VALU
// split2/thread from layer staging and ~300 from skip_end1 staging; halves
// layer staging load count. Bit-identical math to R7 (split-at-write ==
// split-at-read). Layers were ~65% of runtime at 100us each vs 25us HBM floor.
// ---------------------------------------------------------------------------

#define MCAP 327680

typedef short v8s __attribute__((ext_vector_type(8)));
typedef float v4f __attribute__((ext_vector_type(4)));

static inline long lmax_(long a, long b) { return a > b ? a : b; }

__device__ inline unsigned short rnbf(float x) {
    unsigned u = __float_as_uint(x);
    return (unsigned short)((u + 0x7FFFu + ((u >> 16) & 1u)) >> 16);
}
__device__ inline void split2(float v, unsigned short& h, unsigned short& l) {
    h = rnbf(v);
    const float hf = __uint_as_float(((unsigned)h) << 16);
    l = rnbf(v - hf);
}
__device__ inline unsigned packsplit(float v) {
    unsigned short h, l;
    split2(v, h, l);
    return ((unsigned)l << 16) | (unsigned)h;
}

__global__ __launch_bounds__(256) void k_zero(float* __restrict__ p, int n) {
    int i = blockIdx.x * 256 + threadIdx.x;
    if (i < n) p[i] = 0.f;
}

// h0[o][t*256+n] = packsplit(sum_i start_w[o,i] * x[n,i,t])
__global__ __launch_bounds__(256) void k_start(const float* __restrict__ x,
                                               const float* __restrict__ sw,
                                               unsigned* __restrict__ h0) {
    int j = blockIdx.x * 256 + threadIdx.x;
    int t = j >> 8, n = j & 255;
    float xv[5];
#pragma unroll
    for (int i = 0; i < 5; ++i) xv[i] = x[n * 6400 + i * 1280 + t];
#pragma unroll
    for (int o = 0; o < 32; ++o) {
        float acc = 0.f;
#pragma unroll
        for (int i = 0; i < 5; ++i) acc = fmaf(sw[o * 5 + i], xv[i], acc);
        h0[o * MCAP + j] = packsplit(acc);
    }
}

// Prepack small weights (split bf16).
__global__ __launch_bounds__(256) void k_prep(const float* __restrict__ skw,
                                              const float* __restrict__ e1w,
                                              const float* __restrict__ fw,
                                              const float* __restrict__ gw,
                                              const float* __restrict__ rw,
                                              const float* __restrict__ e2w,
                                              unsigned short* __restrict__ swt_hi,
                                              unsigned short* __restrict__ swt_lo,
                                              unsigned short* __restrict__ e1t_hi,
                                              unsigned short* __restrict__ e1t_lo,
                                              unsigned short* __restrict__ wfg_hi,
                                              unsigned short* __restrict__ wfg_lo,
                                              unsigned short* __restrict__ wr_hi,
                                              unsigned short* __restrict__ wr_lo,
                                              unsigned short* __restrict__ e2s_hi,
                                              unsigned short* __restrict__ e2s_lo) {
    int idx = blockIdx.x * 256 + threadIdx.x;
    if (idx < 49152) {
        int ch = idx / 192, k = idx - ch * 192;
        int l = k >> 5, i = k & 31;
        unsigned short h, lo;
        split2(skw[l * 8192 + ch * 32 + i], h, lo);
        swt_hi[idx] = h; swt_lo[idx] = lo;
    }
    if (idx < 32768) {
        unsigned short h, lo;
        split2(e1w[idx], h, lo);
        e1t_hi[idx] = h; e1t_lo[idx] = lo;
    }
    if (idx < 24576) {
        int l = idx >> 12, r = idx & 4095;
        int row = r >> 6, k = r & 63;
        int o = row & 31, i = k & 31, tap = k >> 5;
        const float* src = (row < 32) ? fw : gw;
        unsigned short h, lo;
        split2(src[l * 2048 + o * 64 + i * 2 + tap], h, lo);
        wfg_hi[idx] = h; wfg_lo[idx] = lo;
    }
    if (idx < 12288) {
        int l = idx >> 11, r = idx & 2047;
        int o = r >> 6, k = r & 63, i = k & 31;
        unsigned short h, lo;
        split2(rw[l * 1024 + o * 32 + i], h, lo);
        wr_hi[idx] = h; wr_lo[idx] = lo;
    }
    if (idx < 4096) {
        unsigned short h, lo;
        split2(e2w[idx], h, lo);
        e2s_hi[idx] = h; e2s_lo[idx] = lo;
    }
}

// Split fc1 weights (1024 x 10144, row-major, k-contiguous).
__global__ __launch_bounds__(256) void k_prep_w1(const float* __restrict__ w1,
                                                 unsigned short* __restrict__ hi,
                                                 unsigned short* __restrict__ lo) {
    int idx = blockIdx.x * 256 + threadIdx.x;
    if (idx < 10387456) {
        unsigned short h, l;
        split2(w1[idx], h, l);
        hi[idx] = h; lo[idx] = l;
    }
}

// One dilated gated layer via split-bf16 MFMA. 128-col tile, Jcnt % 128 == 0.
// hin/hout/gsl hold packed-split u32 activations.
__global__ __launch_bounds__(256) void k_layer_m(
    const unsigned* __restrict__ hin, const int hinBase, const int hinStride,
    unsigned* __restrict__ hout, const int houtBase, const int houtStride,
    unsigned* __restrict__ gsl, const int gStride,
    const unsigned short* __restrict__ wfg_hi, const unsigned short* __restrict__ wfg_lo,
    const unsigned short* __restrict__ wr_hi, const unsigned short* __restrict__ wr_lo,
    const int Jlo, const int NpmP, const int padN,
    const int so_, const int M0, const int M1, const int doRes)
{
    __shared__ unsigned short AT[128 * 136];
    __shared__ unsigned short GT[128 * 72];

    const int tid = threadIdx.x;
    const int j0 = Jlo + blockIdx.x * 128;

    {
        const int col = tid & 127;
        const int kg = tid >> 7;
        unsigned short* bh = &AT[col * 136 + kg * 32];
        unsigned short* bl = &AT[col * 136 + 64 + kg * 32];
        if (kg == 0 && j0 < padN) {
            uint4 z; z.x = z.y = z.z = z.w = 0u;
#pragma unroll
            for (int ch = 0; ch < 32; ch += 8) {
                *(uint4*)&bh[ch] = z;
                *(uint4*)&bl[ch] = z;
            }
        } else {
            const int off = (kg == 0) ? (j0 - padN) : (j0 + NpmP);
            const unsigned* p = hin + (off - hinBase) + col;
#pragma unroll
            for (int ch = 0; ch < 32; ch += 8) {
                alignas(16) unsigned short h8[8], l8[8];
#pragma unroll
                for (int u = 0; u < 8; ++u) {
                    const unsigned v = p[(size_t)(ch + u) * hinStride];
                    h8[u] = (unsigned short)(v & 0xffffu);
                    l8[u] = (unsigned short)(v >> 16);
                }
                *(uint4*)&bh[ch] = *(uint4*)h8;
                *(uint4*)&bl[ch] = *(uint4*)l8;
            }
        }
    }
    __syncthreads();

    const int lane = tid & 63;
    const int w    = tid >> 6;
    const int ch2  = w >> 1;
    const int mh   = w & 1;
    const int l15  = lane & 15;
    const int quad = lane >> 4;
    const int q8   = quad * 8;
    const int colb = ch2 * 64;

    v4f accf[4], accg[4];
#pragma unroll
    for (int nt = 0; nt < 4; ++nt) { accf[nt] = (v4f)(0.f); accg[nt] = (v4f)(0.f); }

#pragma unroll
    for (int kt = 0; kt < 2; ++kt) {
        const int frow = (mh * 16 + l15) * 64 + kt * 32 + q8;
        const int grow = (32 + mh * 16 + l15) * 64 + kt * 32 + q8;
        const v8s afh = *(const v8s*)&wfg_hi[frow];
        const v8s afl = *(const v8s*)&wfg_lo[frow];
        const v8s agh = *(const v8s*)&wfg_hi[grow];
        const v8s agl = *(const v8s*)&wfg_lo[grow];
#pragma unroll
        for (int nt = 0; nt < 4; ++nt) {
            const int col = colb + nt * 16 + l15;
            const v8s bh = *(const v8s*)&AT[col * 136 + kt * 32 + q8];
            const v8s bl = *(const v8s*)&AT[col * 136 + 64 + kt * 32 + q8];
            accf[nt] = __builtin_amdgcn_mfma_f32_16x16x32_bf16(afh, bh, accf[nt], 0, 0, 0);
            accf[nt] = __builtin_amdgcn_mfma_f32_16x16x32_bf16(afh, bl, accf[nt], 0, 0, 0);
            accf[nt] = __builtin_amdgcn_mfma_f32_16x16x32_bf16(afl, bh, accf[nt], 0, 0, 0);
            accg[nt] = __builtin_amdgcn_mfma_f32_16x16x32_bf16(agh, bh, accg[nt], 0, 0, 0);
            accg[nt] = __builtin_amdgcn_mfma_f32_16x16x32_bf16(agh, bl, accg[nt], 0, 0, 0);
            accg[nt] = __builtin_amdgcn_mfma_f32_16x16x32_bf16(agl, bh, accg[nt], 0, 0, 0);
        }
    }

    // gate + split (split reused for G store and GT staging)
    unsigned short gh[4][4], gl[4][4];
#pragma unroll
    for (int nt = 0; nt < 4; ++nt)
#pragma unroll
        for (int r = 0; r < 4; ++r) {
            const float f = accf[nt][r];
            const float g = accg[nt][r];
            const float th = 1.f - 2.f / (__expf(2.f * f) + 1.f);
            const float sg = 1.f / (1.f + __expf(-g));
            split2(th * sg, gh[nt][r], gl[nt][r]);
        }

    const int m0c = j0 - so_;
    if (m0c >= M0 && m0c < M1) {
#pragma unroll
        for (int nt = 0; nt < 4; ++nt)
#pragma unroll
            for (int r = 0; r < 4; ++r) {
                const int ch = mh * 16 + quad * 4 + r;
                const int m = (m0c - M0) + colb + nt * 16 + l15;
                gsl[(size_t)ch * gStride + m] =
                    ((unsigned)gl[nt][r] << 16) | (unsigned)gh[nt][r];
            }
    }

    if (doRes) {
#pragma unroll
        for (int nt = 0; nt < 4; ++nt)
#pragma unroll
            for (int r = 0; r < 4; ++r) {
                const int ch = mh * 16 + quad * 4 + r;
                const int col = colb + nt * 16 + l15;
                GT[col * 72 + ch] = gh[nt][r];
                GT[col * 72 + 32 + ch] = gl[nt][r];
            }
        __syncthreads();

        v4f accr[4];
#pragma unroll
        for (int nt = 0; nt < 4; ++nt) accr[nt] = (v4f)(0.f);
#pragma unroll
        for (int kt = 0; kt < 2; ++kt) {
            const int row = (mh * 16 + l15) * 64 + kt * 32 + q8;
            const v8s arh = *(const v8s*)&wr_hi[row];
            const v8s arl = *(const v8s*)&wr_lo[row];
#pragma unroll
            for (int nt = 0; nt < 4; ++nt) {
                const int col = colb + nt * 16 + l15;
                const v8s b = *(const v8s*)&GT[col * 72 + kt * 32 + q8];
                accr[nt] = __builtin_amdgcn_mfma_f32_16x16x32_bf16(arh, b, accr[nt], 0, 0, 0);
                accr[nt] = __builtin_amdgcn_mfma_f32_16x16x32_bf16(arl, b, accr[nt], 0, 0, 0);
            }
        }

#pragma unroll
        for (int nt = 0; nt < 4; ++nt)
#pragma unroll
            for (int r = 0; r < 4; ++r) {
                const int o = mh * 16 + quad * 4 + r;
                const int col = colb + nt * 16 + l15;
                const unsigned hh = AT[col * 136 + 32 + o];
                const unsigned ll = AT[col * 136 + 64 + 32 + o];
                const float tap1 = __uint_as_float(hh << 16) + __uint_as_float(ll << 16);
                hout[(size_t)o * houtStride + (j0 - houtBase) + col] =
                    packsplit(accr[nt][r] + tap1);
            }
    }
}

// Fused skip -> relu -> end1 + bias -> relu -> y1 (split-bf16 MFMA).
// g holds packed-split u32 gated values.
__global__ __launch_bounds__(256, 2) void k_skip_end1_m(
    const unsigned* __restrict__ g,
    const unsigned short* __restrict__ swt_hi, const unsigned short* __restrict__ swt_lo,
    const unsigned short* __restrict__ e1t_hi, const unsigned short* __restrict__ e1t_lo,
    const float* __restrict__ b1, float* __restrict__ y1, const int gs)
{
    __shared__ unsigned short U[33792];
    unsigned short* gt_hi = U;
    unsigned short* gt_lo = U + 12800;
    unsigned short* st_hi = U;
    unsigned short* st_lo = U + 16896;

    const int tid  = threadIdx.x;
    const int m0   = blockIdx.x * 64;
    const int lane = tid & 63;
    const int w    = tid >> 6;
    const int l15  = lane & 15;
    const int q8   = (lane >> 4) * 8;
    const int rbase = (lane >> 4) * 4;

    {
        const int scol = tid & 63;
        const int ks0  = (tid >> 6) * 8;
        for (int kc = 0; kc < 192; kc += 32) {
            alignas(16) unsigned short h8[8], l8[8];
#pragma unroll
            for (int j = 0; j < 8; ++j) {
                const int k = kc + ks0 + j;
                const unsigned v = g[(size_t)(k >> 5) * 32 * gs + (size_t)(k & 31) * gs + m0 + scol];
                h8[j] = (unsigned short)(v & 0xffffu);
                l8[j] = (unsigned short)(v >> 16);
            }
            *(v8s*)&gt_hi[scol * 200 + kc + ks0] = *(v8s*)h8;
            *(v8s*)&gt_lo[scol * 200 + kc + ks0] = *(v8s*)l8;
        }
    }
    __syncthreads();

    v4f acc1[4][4];
#pragma unroll
    for (int a = 0; a < 4; ++a)
#pragma unroll
        for (int b = 0; b < 4; ++b) acc1[a][b] = (v4f)(0.f);

    for (int kc = 0; kc < 192; kc += 32) {
        v8s ah[4], al[4], bh[4], bl[4];
#pragma unroll
        for (int t = 0; t < 4; ++t) {
            const int row = (w * 64 + t * 16 + l15) * 192 + kc + q8;
            ah[t] = *(const v8s*)&swt_hi[row];
            al[t] = *(const v8s*)&swt_lo[row];
            const int bo = (t * 16 + l15) * 200 + kc + q8;
            bh[t] = *(const v8s*)&gt_hi[bo];
            bl[t] = *(const v8s*)&gt_lo[bo];
        }
#pragma unroll
        for (int ct = 0; ct < 4; ++ct)
#pragma unroll
            for (int nt = 0; nt < 4; ++nt) {
                acc1[ct][nt] = __builtin_amdgcn_mfma_f32_16x16x32_bf16(ah[ct], bh[nt], acc1[ct][nt], 0, 0, 0);
                acc1[ct][nt] = __builtin_amdgcn_mfma_f32_16x16x32_bf16(ah[ct], bl[nt], acc1[ct][nt], 0, 0, 0);
                acc1[ct][nt] = __builtin_amdgcn_mfma_f32_16x16x32_bf16(al[ct], bh[nt], acc1[ct][nt], 0, 0, 0);
            }
    }
    __syncthreads();

#pragma unroll
    for (int ct = 0; ct < 4; ++ct)
#pragma unroll
        for (int nt = 0; nt < 4; ++nt) {
            alignas(8) unsigned short sh[4], sl[4];
#pragma unroll
            for (int r = 0; r < 4; ++r) {
                const float v = fmaxf(acc1[ct][nt][r], 0.f);
                split2(v, sh[r], sl[r]);
            }
            const int ci  = w * 64 + ct * 16 + rbase;
            const int col = nt * 16 + l15;
            *(uint2*)&st_hi[col * 264 + ci] = *(uint2*)sh;
            *(uint2*)&st_lo[col * 264 + ci] = *(uint2*)sl;
        }
    __syncthreads();

    v4f acc2[2][4];
#pragma unroll
    for (int a = 0; a < 2; ++a)
#pragma unroll
        for (int b = 0; b < 4; ++b) acc2[a][b] = (v4f)(0.f);

    for (int kc = 0; kc < 256; kc += 32) {
        v8s ah[2], al[2], bh[4], bl[4];
#pragma unroll
        for (int t = 0; t < 2; ++t) {
            const int row = (w * 32 + t * 16 + l15) * 256 + kc + q8;
            ah[t] = *(const v8s*)&e1t_hi[row];
            al[t] = *(const v8s*)&e1t_lo[row];
        }
#pragma unroll
        for (int t = 0; t < 4; ++t) {
            const int bo = (t * 16 + l15) * 264 + kc + q8;
            bh[t] = *(const v8s*)&st_hi[bo];
            bl[t] = *(const v8s*)&st_lo[bo];
        }
#pragma unroll
        for (int ct = 0; ct < 2; ++ct)
#pragma unroll
            for (int nt = 0; nt < 4; ++nt) {
                acc2[ct][nt] = __builtin_amdgcn_mfma_f32_16x16x32_bf16(ah[ct], bh[nt], acc2[ct][nt], 0, 0, 0);
                acc2[ct][nt] = __builtin_amdgcn_mfma_f32_16x16x32_bf16(ah[ct], bl[nt], acc2[ct][nt], 0, 0, 0);
                acc2[ct][nt] = __builtin_amdgcn_mfma_f32_16x16x32_bf16(al[ct], bh[nt], acc2[ct][nt], 0, 0, 0);
            }
    }

#pragma unroll
    for (int ct = 0; ct < 2; ++ct) {
        const int cobase = w * 32 + ct * 16 + rbase;
        float bb[4];
#pragma unroll
        for (int r = 0; r < 4; ++r) bb[r] = b1[cobase + r];
#pragma unroll
        for (int nt = 0; nt < 4; ++nt) {
            const int col = m0 + nt * 16 + l15;
#pragma unroll
            for (int r = 0; r < 4; ++r)
                y1[(size_t)(cobase + r) * gs + col] = fmaxf(acc2[ct][nt][r] + bb[r], 0.f);
        }
    }
}

// Fused maxpool3s2 + end2 (128->32) via split-bf16 MFMA. 64 pooled cols/block.
__global__ __launch_bounds__(256) void k_pe2_m(
    const float* __restrict__ y1c,
    const unsigned short* __restrict__ e2s_hi, const unsigned short* __restrict__ e2s_lo,
    const float* __restrict__ b2, float* __restrict__ e2c,
    const int gs, const int p1s)
{
    __shared__ unsigned short SP[2 * 64 * 136];
    unsigned short* sp_hi = SP;
    unsigned short* sp_lo = SP + 64 * 136;

    const int tid = threadIdx.x;
    const int m0 = blockIdx.x * 64;
    const int tp = m0 >> 8;
    const int nb = m0 & 255;

    {
        const int col = tid & 63;
        const int cig = tid >> 6;
        const int base = 2 * tp * 256 + nb + col;
#pragma unroll
        for (int u8 = 0; u8 < 4; ++u8) {
            alignas(16) unsigned short h8[8], l8[8];
#pragma unroll
            for (int u = 0; u < 8; ++u) {
                const int ci = cig * 32 + u8 * 8 + u;
                const float* yp = y1c + (size_t)ci * gs + base;
                const float v = fmaxf(fmaxf(yp[0], yp[256]), yp[512]);
                split2(v, h8[u], l8[u]);
            }
            *(uint4*)&sp_hi[col * 136 + cig * 32 + u8 * 8] = *(uint4*)h8;
            *(uint4*)&sp_lo[col * 136 + cig * 32 + u8 * 8] = *(uint4*)l8;
        }
    }
    __syncthreads();

    const int lane = tid & 63;
    const int w    = tid >> 6;
    const int mh   = w & 1;
    const int colh = w >> 1;
    const int l15  = lane & 15;
    const int quad = lane >> 4;
    const int q8   = quad * 8;

    v4f acc[2];
    acc[0] = (v4f)(0.f); acc[1] = (v4f)(0.f);

#pragma unroll
    for (int kc = 0; kc < 128; kc += 32) {
        const int row = (mh * 16 + l15) * 128 + kc + q8;
        const v8s ah = *(const v8s*)&e2s_hi[row];
        const v8s al = *(const v8s*)&e2s_lo[row];
#pragma unroll
        for (int nt = 0; nt < 2; ++nt) {
            const int col = colh * 32 + nt * 16 + l15;
            const v8s bh = *(const v8s*)&sp_hi[col * 136 + kc + q8];
            const v8s bl = *(const v8s*)&sp_lo[col * 136 + kc + q8];
            acc[nt] = __builtin_amdgcn_mfma_f32_16x16x32_bf16(ah, bh, acc[nt], 0, 0, 0);
            acc[nt] = __builtin_amdgcn_mfma_f32_16x16x32_bf16(ah, bl, acc[nt], 0, 0, 0);
            acc[nt] = __builtin_amdgcn_mfma_f32_16x16x32_bf16(al, bh, acc[nt], 0, 0, 0);
        }
    }

#pragma unroll
    for (int nt = 0; nt < 2; ++nt)
#pragma unroll
        for (int r = 0; r < 4; ++r) {
            const int co = mh * 16 + quad * 4 + r;
            const int col = m0 + colh * 32 + nt * 16 + l15;
            e2c[(size_t)co * p1s + col] = fmaxf(acc[nt][r] + b2[co], 0.f);
        }
}

__global__ __launch_bounds__(256) void k_pool2_c(const float* __restrict__ e2c,
                                                 float* __restrict__ p2,
                                                 const int p1s, const int A) {
    const int n = threadIdx.x, tl2 = blockIdx.x, co = blockIdx.y;
    const int base = co * p1s + tl2 * 512 + n;
    float v = fmaxf(fmaxf(e2c[base], e2c[base + 256]), e2c[base + 512]);
    p2[co * 81152 + (A + tl2) * 256 + n] = v;
}

// FC1 via split-bf16 MFMA: C[1024 x 256] += W1[1024 x 10144] @ P2[10144 x 256].
__global__ __launch_bounds__(256) void k_fc1_m(
    const unsigned short* __restrict__ w1s_hi, const unsigned short* __restrict__ w1s_lo,
    const float* __restrict__ p2, float* __restrict__ out)
{
    __shared__ unsigned short SB[2 * 64 * 40];
    unsigned short* sb_hi = SB;
    unsigned short* sb_lo = SB + 64 * 40;

    const int tid = threadIdx.x;
    const int o0 = blockIdx.x * 64;
    const int b0 = blockIdx.y * 64;
    const int k0 = blockIdx.z * 1280;
    const int kend = (k0 + 1280 < 10144) ? (k0 + 1280) : 10144;
    const int nch = (kend - k0) >> 5;

    const int lane = tid & 63;
    const int w    = tid >> 6;
    const int l15  = lane & 15;
    const int quad = lane >> 4;
    const int q8   = quad * 8;
    const int scol = tid & 63;
    const int kq   = tid >> 6;

    v4f acc[4];
#pragma unroll
    for (int nt = 0; nt < 4; ++nt) acc[nt] = (v4f)(0.f);

    for (int c = 0; c < nch; ++c) {
        const int kc = k0 + c * 32;
        alignas(16) unsigned short h8[8], l8[8];
#pragma unroll
        for (int j = 0; j < 8; ++j) {
            const float v = p2[(size_t)(kc + kq * 8 + j) * 256 + b0 + scol];
            split2(v, h8[j], l8[j]);
        }
        __syncthreads();
        *(v8s*)&sb_hi[scol * 40 + kq * 8] = *(v8s*)h8;
        *(v8s*)&sb_lo[scol * 40 + kq * 8] = *(v8s*)l8;
        __syncthreads();

        const int arow = (o0 + w * 16 + l15) * 10144 + kc + q8;
        const v8s ah = *(const v8s*)&w1s_hi[arow];
        const v8s al = *(const v8s*)&w1s_lo[arow];
#pragma unroll
        for (int nt = 0; nt < 4; ++nt) {
            const v8s bh = *(const v8s*)&sb_hi[(nt * 16 + l15) * 40 + q8];
            const v8s bl = *(const v8s*)&sb_lo[(nt * 16 + l15) * 40 + q8];
            acc[nt] = __builtin_amdgcn_mfma_f32_16x16x32_bf16(ah, bh, acc[nt], 0, 0, 0);
            acc[nt] = __builtin_amdgcn_mfma_f32_16x16x32_bf16(ah, bl, acc[nt], 0, 0, 0);
            acc[nt] = __builtin_amdgcn_mfma_f32_16x16x32_bf16(al, bh, acc[nt], 0, 0, 0);
        }
    }

#pragma unroll
    for (int nt = 0; nt < 4; ++nt)
#pragma unroll
        for (int r = 0; r < 4; ++r)
            atomicAdd(&out[(size_t)(o0 + w * 16 + quad * 4 + r) * 256 + b0 + nt * 16 + l15],
                      acc[nt][r]);
}

// Tiled f32 GEMM (FC2 only).
__global__ __launch_bounds__(256) void k_gemm64(const float* __restrict__ A,
                                                const float* __restrict__ B,
                                                float* __restrict__ C,
                                                const int Ktot, const int KC) {
    __shared__ float sA[32 * 65];
    __shared__ float sB[32 * 68];

    const int tid = threadIdx.x;
    const int o0 = blockIdx.x * 64;
    const int b0 = blockIdx.y * 64;
    const int k0 = blockIdx.z * KC;

    float acc[4][4];
#pragma unroll
    for (int i = 0; i < 4; ++i)
#pragma unroll
        for (int jq = 0; jq < 4; ++jq) acc[i][jq] = 0.f;

    const int ao  = tid >> 2;
    const int ak8 = (tid & 3) * 8;
    const int bk  = tid >> 3;
    const int bb8 = (tid & 7) * 8;
    const int to4 = (tid & 15) * 4;
    const int tb4 = (tid >> 4) * 4;

    for (int kc = 0; kc < KC; kc += 32) {
        const int kcLen = (KC - kc < 32) ? (KC - kc) : 32;
        const float* ap = A + (size_t)(o0 + ao) * Ktot + k0 + kc + ak8;
#pragma unroll
        for (int i = 0; i < 8; ++i) {
            float v = (ak8 + i < kcLen) ? ap[i] : 0.f;
            sA[(ak8 + i) * 65 + ao] = v;
        }
        if (bk < kcLen) {
            const float* bp = B + (size_t)(k0 + kc + bk) * 256 + b0 + bb8;
            const float4 v0 = *(const float4*)bp;
            const float4 v1 = *(const float4*)(bp + 4);
            *(float4*)&sB[bk * 68 + bb8] = v0;
            *(float4*)&sB[bk * 68 + bb8 + 4] = v1;
        } else {
            float4 z; z.x = z.y = z.z = z.w = 0.f;
            *(float4*)&sB[bk * 68 + bb8] = z;
            *(float4*)&sB[bk * 68 + bb8 + 4] = z;
        }
        __syncthreads();

#pragma unroll 8
        for (int kk = 0; kk < 32; ++kk) {
            const float4 av = *(const float4*)&sA[kk * 65 + to4];
            const float4 bv = *(const float4*)&sB[kk * 68 + tb4];
            const float aa[4] = {av.x, av.y, av.z, av.w};
#pragma unroll
            for (int i = 0; i < 4; ++i) {
                acc[i][0] = fmaf(aa[i], bv.x, acc[i][0]);
                acc[i][1] = fmaf(aa[i], bv.y, acc[i][1]);
                acc[i][2] = fmaf(aa[i], bv.z, acc[i][2]);
                acc[i][3] = fmaf(aa[i], bv.w, acc[i][3]);
            }
        }
        __syncthreads();
    }

#pragma unroll
    for (int i = 0; i < 4; ++i)
#pragma unroll
        for (int jq = 0; jq < 4; ++jq)
            atomicAdd(&C[(size_t)(o0 + to4 + i) * 256 + b0 + tb4 + jq], acc[i][jq]);
}

__global__ __launch_bounds__(256) void k_actbias(const float* __restrict__ raw,
                                                 const float* __restrict__ bias,
                                                 float* __restrict__ out) {
    const int k = blockIdx.x, b = threadIdx.x;
    out[k * 256 + b] = fmaxf(raw[k * 256 + b] + bias[k], 0.f);
}

__global__ __launch_bounds__(256) void k_fc3(const float* __restrict__ fc2raw,
                                             const float* __restrict__ fb2,
                                             const float* __restrict__ w3,
                                             const float* __restrict__ b3,
                                             float* __restrict__ out) {
    const int b = threadIdx.x;
    float l0 = b3[0], l1 = b3[1];
    for (int k = 0; k < 256; ++k) {
        const float a = fmaxf(fc2raw[k * 256 + b] + fb2[k], 0.f);
        l0 = fmaf(w3[k], a, l0);
        l1 = fmaf(w3[256 + k], a, l1);
    }
    out[2 * b] = l0;
    out[2 * b + 1] = l1;
    const float mx = fmaxf(l0, l1);
    const float e0 = expf(l0 - mx), e1 = expf(l1 - mx);
    const float inv = 1.f / (e0 + e1);
    out[512 + 2 * b] = e0 * inv;
    out[513 + 2 * b] = e1 * inv;
    out[1024 + b] = (l1 > l0) ? 1.f : 0.f;
}

extern "C" void kernel_launch(void* const* d_in, const int* in_sizes, int n_in,
                              void* d_out, int out_size, void* d_ws, size_t ws_size,
                              hipStream_t stream) {
    const float* x        = (const float*)d_in[0];
    const float* start_w  = (const float*)d_in[1];
    const float* filter_w = (const float*)d_in[2];
    const float* gate_w   = (const float*)d_in[3];
    const float* res_w    = (const float*)d_in[4];
    const float* skip_w   = (const float*)d_in[5];
    const float* e1w      = (const float*)d_in[6];
    const float* e1b      = (const float*)d_in[7];
    const float* e2w      = (const float*)d_in[8];
    const float* e2b      = (const float*)d_in[9];
    const float* w1       = (const float*)d_in[10];
    const float* fb1      = (const float*)d_in[11];
    const float* w2       = (const float*)d_in[12];
    const float* fb2      = (const float*)d_in[13];
    const float* w3       = (const float*)d_in[14];
    const float* b3       = (const float*)d_in[15];

    float* ws = (float*)d_ws;

    const long o_h0   = 0;            // 10,485,760
    const long o_p2   = 10485760;     // 2,596,864
    const long o_fc1  = 13082624;     // 262,144
    const long o_fc2  = 13344768;     // 65,536
    const long o_wbf  = 13410304;     // 81,920
    const long o_wfg  = 13492224;     // 24,576
    const long o_wr   = 13516800;     // 12,288
    const long o_e2s  = 13529088;     // 4,096
    const long o_act1 = 13533184;     // 262,144
    const long o_w1s  = 13795328;     // 10,387,456 (w1 hi+lo u16)
    const long o_G    = 24182784;

    long budget = (long)((double)ws_size * 0.94 / 4.0);
    int dB = 1;
    for (int d = 317; d >= 1; --d) {
        long mch = 256L * (4L * d + 3), hs = mch + 4096;
        long tot = o_G + 192L * mch + lmax_(128L * mch, 64L * hs);
        if (tot <= budget) { dB = d; break; }
    }
    int K = (317 + dB - 1) / dB;
    dB = (317 + K - 1) / K;
    const long MchA  = 256L * (4L * dB + 3);
    const long HSPAN = MchA + 4096;
    const long o_X   = o_G + 192L * MchA;
    const long P1S   = 256L * (2L * dB + 1);

    unsigned* h0 = (unsigned*)(ws + o_h0);
    float* p2   = ws + o_p2;
    float* fc1r = ws + o_fc1;
    float* fc2r = ws + o_fc2;
    unsigned short* swt_hi = (unsigned short*)(ws + o_wbf);
    unsigned short* swt_lo = swt_hi + 49152;
    unsigned short* e1t_hi = swt_lo + 49152;
    unsigned short* e1t_lo = e1t_hi + 32768;
    unsigned short* wfg_hi = (unsigned short*)(ws + o_wfg);
    unsigned short* wfg_lo = wfg_hi + 24576;
    unsigned short* wr_hi  = (unsigned short*)(ws + o_wr);
    unsigned short* wr_lo  = wr_hi + 12288;
    unsigned short* e2s_hi = (unsigned short*)(ws + o_e2s);
    unsigned short* e2s_lo = e2s_hi + 4096;
    unsigned short* w1s_hi = (unsigned short*)(ws + o_w1s);
    unsigned short* w1s_lo = w1s_hi + 10387456;
    float* act1 = ws + o_act1;
    unsigned* G  = (unsigned*)(ws + o_G);
    unsigned* hA = (unsigned*)(ws + o_X);
    unsigned* hB = (unsigned*)(ws + o_X) + 32L * HSPAN;
    float* y1c  = ws + o_X;                 // aliases hA/hB (dead by then)
    float* e2c  = ws + o_G;                 // aliases G (dead after skip_end1)

    k_zero<<<1280, 256, 0, stream>>>(fc1r, 327680);
    k_start<<<1280, 256, 0, stream>>>(x, start_w, h0);
    k_prep<<<192, 256, 0, stream>>>(skip_w, e1w, filter_w, gate_w, res_w, e2w,
                                    swt_hi, swt_lo, e1t_hi, e1t_lo,
                                    wfg_hi, wfg_lo, wr_hi, wr_lo,
                                    e2s_hi, e2s_lo);
    k_prep_w1<<<40576, 256, 0, stream>>>(w1, w1s_hi, w1s_lo);

    const int Mc[6]   = {327424, 327168, 326656, 326400, 326144, 325632};
    const int NpmP[6] = {256, 256, 512, 256, 256, 512};
    const int pN[6]   = {0, 256, 512, 0, 256, 512};
    const int so_[6]  = {1792, 1536, 1024, 768, 512, 0};
    const int JloO[6] = {-1536, -1280, -768, -768, -512, 0};

    for (int c = 0; c < K; ++c) {
        const int A = c * dB;
        int B = A + dB; if (B > 317) B = 317;
        const int dBc = B - A;
        const int M0 = 1024 * A;
        int tmax = 4 * B + 3; if (tmax > 1272) tmax = 1272;
        const int Tt = tmax - 4 * A;
        const int M1 = M0 + 256 * Tt;

        int Jlo[6], Jhi[6];
        for (int q = 0; q < 6; ++q) {
            int lo = M0 + JloO[q]; if (lo < 0) lo = 0;
            int hi = M1 + so_[q];  if (hi > Mc[q]) hi = Mc[q];
            Jlo[q] = lo; Jhi[q] = hi;
        }

        for (int q = 0; q < 6; ++q) {
            const unsigned* hin = (q == 0) ? h0 : ((q & 1) ? hA : hB);
            const int hinBase   = (q == 0) ? 0 : Jlo[q - 1];
            const int hinStride = (q == 0) ? MCAP : (int)HSPAN;
            unsigned* hout = (q & 1) ? hB : hA;
            const int Jcnt = Jhi[q] - Jlo[q];     // % 128 == 0
            k_layer_m<<<Jcnt / 128, 256, 0, stream>>>(
                hin, hinBase, hinStride, hout, Jlo[q], (int)HSPAN,
                G + (long)q * 32 * MchA, (int)MchA,
                wfg_hi + q * 4096, wfg_lo + q * 4096,
                wr_hi + q * 2048, wr_lo + q * 2048,
                Jlo[q], NpmP[q], pN[q], so_[q], M0, M1, (q < 5) ? 1 : 0);
        }

        const int Mchc = 256 * Tt;
        k_skip_end1_m<<<Mchc / 64, 256, 0, stream>>>(
            G, swt_hi, swt_lo, e1t_hi, e1t_lo, e1b, y1c, (int)MchA);
        const int T1c = 2 * dBc + 1;
        k_pe2_m<<<T1c * 4, 256, 0, stream>>>(
            y1c, e2s_hi, e2s_lo, e2b, e2c, (int)MchA, (int)P1S);
        k_pool2_c<<<dim3(dBc, 32), 256, 0, stream>>>(e2c, p2, (int)P1S, A);
    }

    k_fc1_m<<<dim3(16, 4, 8), 256, 0, stream>>>(w1s_hi, w1s_lo, p2, fc1r);
    k_actbias<<<1024, 256, 0, stream>>>(fc1r, fb1, act1);
    k_gemm64<<<dim3(4, 4, 4), 256, 0, stream>>>(w2, act1, fc2r, 1024, 256);
    k_fc3<<<1, 256, 0, stream>>>(fc2r, fb2, w3, b3, (float*)d_out);
}

// Round 9
// 842.592 us; speedup vs baseline: 4.8751x; 1.0425x over previous
//
#include <hip/hip_runtime.h>
#include <math.h>

// ---------------------------------------------------------------------------
// WaveNet forward. Layers, skip/end1, end2(+fused pool1), FC1 all via
// split-bf16 MFMA (3-term hi*hi+hi*lo+lo*hi, rel err ~2^-16). Flat layout
// (channel, time, batch) => buf[c][t*256+n]; dilate() is a reinterpretation.
// R9: layer LDS-op surgery. R8 layers issued ~1000 cyc/thread of LDS traffic
// (64 scalar ds_read_u16 tap1 + 32 scalar ds_write_u16 GT) vs 310 cyc MFMA.
// (1) tap1 re-loaded from global (16 coalesced u32 loads, same packed value
// -> bit-identical); (2) GT aliases AT (barrier-separated): LDS 53->35 KB,
// 3->4 blocks/CU; (3) p2 stored packed, fc1_m unpacks (2 ops vs 8-op split).
// ---------------------------------------------------------------------------

#define MCAP 327680

typedef short v8s __attribute__((ext_vector_type(8)));
typedef float v4f __attribute__((ext_vector_type(4)));

static inline long lmax_(long a, long b) { return a > b ? a : b; }

__device__ inline unsigned short rnbf(float x) {
    unsigned u = __float_as_uint(x);
    return (unsigned short)((u + 0x7FFFu + ((u >> 16) & 1u)) >> 16);
}
__device__ inline void split2(float v, unsigned short& h, unsigned short& l) {
    h = rnbf(v);
    const float hf = __uint_as_float(((unsigned)h) << 16);
    l = rnbf(v - hf);
}
__device__ inline unsigned packsplit(float v) {
    unsigned short h, l;
    split2(v, h, l);
    return ((unsigned)l << 16) | (unsigned)h;
}
__device__ inline float unpack2f(unsigned v) {
    return __uint_as_float(v << 16) + __uint_as_float(v & 0xffff0000u);
}

__global__ __launch_bounds__(256) void k_zero(float* __restrict__ p, int n) {
    int i = blockIdx.x * 256 + threadIdx.x;
    if (i < n) p[i] = 0.f;
}

// h0[o][t*256+n] = packsplit(sum_i start_w[o,i] * x[n,i,t])
__global__ __launch_bounds__(256) void k_start(const float* __restrict__ x,
                                               const float* __restrict__ sw,
                                               unsigned* __restrict__ h0) {
    int j = blockIdx.x * 256 + threadIdx.x;
    int t = j >> 8, n = j & 255;
    float xv[5];
#pragma unroll
    for (int i = 0; i < 5; ++i) xv[i] = x[n * 6400 + i * 1280 + t];
#pragma unroll
    for (int o = 0; o < 32; ++o) {
        float acc = 0.f;
#pragma unroll
        for (int i = 0; i < 5; ++i) acc = fmaf(sw[o * 5 + i], xv[i], acc);
        h0[o * MCAP + j] = packsplit(acc);
    }
}

// Prepack small weights (split bf16).
__global__ __launch_bounds__(256) void k_prep(const float* __restrict__ skw,
                                              const float* __restrict__ e1w,
                                              const float* __restrict__ fw,
                                              const float* __restrict__ gw,
                                              const float* __restrict__ rw,
                                              const float* __restrict__ e2w,
                                              unsigned short* __restrict__ swt_hi,
                                              unsigned short* __restrict__ swt_lo,
                                              unsigned short* __restrict__ e1t_hi,
                                              unsigned short* __restrict__ e1t_lo,
                                              unsigned short* __restrict__ wfg_hi,
                                              unsigned short* __restrict__ wfg_lo,
                                              unsigned short* __restrict__ wr_hi,
                                              unsigned short* __restrict__ wr_lo,
                                              unsigned short* __restrict__ e2s_hi,
                                              unsigned short* __restrict__ e2s_lo) {
    int idx = blockIdx.x * 256 + threadIdx.x;
    if (idx < 49152) {
        int ch = idx / 192, k = idx - ch * 192;
        int l = k >> 5, i = k & 31;
        unsigned short h, lo;
        split2(skw[l * 8192 + ch * 32 + i], h, lo);
        swt_hi[idx] = h; swt_lo[idx] = lo;
    }
    if (idx < 32768) {
        unsigned short h, lo;
        split2(e1w[idx], h, lo);
        e1t_hi[idx] = h; e1t_lo[idx] = lo;
    }
    if (idx < 24576) {
        int l = idx >> 12, r = idx & 4095;
        int row = r >> 6, k = r & 63;
        int o = row & 31, i = k & 31, tap = k >> 5;
        const float* src = (row < 32) ? fw : gw;
        unsigned short h, lo;
        split2(src[l * 2048 + o * 64 + i * 2 + tap], h, lo);
        wfg_hi[idx] = h; wfg_lo[idx] = lo;
    }
    if (idx < 12288) {
        int l = idx >> 11, r = idx & 2047;
        int o = r >> 6, k = r & 63, i = k & 31;
        unsigned short h, lo;
        split2(rw[l * 1024 + o * 32 + i], h, lo);
        wr_hi[idx] = h; wr_lo[idx] = lo;
    }
    if (idx < 4096) {
        unsigned short h, lo;
        split2(e2w[idx], h, lo);
        e2s_hi[idx] = h; e2s_lo[idx] = lo;
    }
}

// Split fc1 weights (1024 x 10144, row-major, k-contiguous).
__global__ __launch_bounds__(256) void k_prep_w1(const float* __restrict__ w1,
                                                 unsigned short* __restrict__ hi,
                                                 unsigned short* __restrict__ lo) {
    int idx = blockIdx.x * 256 + threadIdx.x;
    if (idx < 10387456) {
        unsigned short h, l;
        split2(w1[idx], h, l);
        hi[idx] = h; lo[idx] = l;
    }
}

// One dilated gated layer via split-bf16 MFMA. 128-col tile, Jcnt % 128 == 0.
// hin/hout/gsl hold packed-split u32 activations. LDS: single 128x136 u16
// buffer; acts (AT) during stage A, gated k-ext (GT) after a barrier.
__global__ __launch_bounds__(256) void k_layer_m(
    const unsigned* __restrict__ hin, const int hinBase, const int hinStride,
    unsigned* __restrict__ hout, const int houtBase, const int houtStride,
    unsigned* __restrict__ gsl, const int gStride,
    const unsigned short* __restrict__ wfg_hi, const unsigned short* __restrict__ wfg_lo,
    const unsigned short* __restrict__ wr_hi, const unsigned short* __restrict__ wr_lo,
    const int Jlo, const int NpmP, const int padN,
    const int so_, const int M0, const int M1, const int doRes)
{
    __shared__ unsigned short U[128 * 136];
    unsigned short* AT = U;          // [col][k]: 0..63 hi, 64..127 lo (stage A)
    unsigned short* GT = U;          // [col][72]: 0..31 ghi, 32..63 glo (stage B)

    const int tid = threadIdx.x;
    const int j0 = Jlo + blockIdx.x * 128;

    {
        const int col = tid & 127;
        const int kg = tid >> 7;
        unsigned short* bh = &AT[col * 136 + kg * 32];
        unsigned short* bl = &AT[col * 136 + 64 + kg * 32];
        if (kg == 0 && j0 < padN) {
            uint4 z; z.x = z.y = z.z = z.w = 0u;
#pragma unroll
            for (int ch = 0; ch < 32; ch += 8) {
                *(uint4*)&bh[ch] = z;
                *(uint4*)&bl[ch] = z;
            }
        } else {
            const int off = (kg == 0) ? (j0 - padN) : (j0 + NpmP);
            const unsigned* p = hin + (off - hinBase) + col;
#pragma unroll
            for (int ch = 0; ch < 32; ch += 8) {
                alignas(16) unsigned short h8[8], l8[8];
#pragma unroll
                for (int u = 0; u < 8; ++u) {
                    const unsigned v = p[(size_t)(ch + u) * hinStride];
                    h8[u] = (unsigned short)(v & 0xffffu);
                    l8[u] = (unsigned short)(v >> 16);
                }
                *(uint4*)&bh[ch] = *(uint4*)h8;
                *(uint4*)&bl[ch] = *(uint4*)l8;
            }
        }
    }
    __syncthreads();

    const int lane = tid & 63;
    const int w    = tid >> 6;
    const int ch2  = w >> 1;
    const int mh   = w & 1;
    const int l15  = lane & 15;
    const int quad = lane >> 4;
    const int q8   = quad * 8;
    const int colb = ch2 * 64;

    v4f accf[4], accg[4];
#pragma unroll
    for (int nt = 0; nt < 4; ++nt) { accf[nt] = (v4f)(0.f); accg[nt] = (v4f)(0.f); }

#pragma unroll
    for (int kt = 0; kt < 2; ++kt) {
        const int frow = (mh * 16 + l15) * 64 + kt * 32 + q8;
        const int grow = (32 + mh * 16 + l15) * 64 + kt * 32 + q8;
        const v8s afh = *(const v8s*)&wfg_hi[frow];
        const v8s afl = *(const v8s*)&wfg_lo[frow];
        const v8s agh = *(const v8s*)&wfg_hi[grow];
        const v8s agl = *(const v8s*)&wfg_lo[grow];
#pragma unroll
        for (int nt = 0; nt < 4; ++nt) {
            const int col = colb + nt * 16 + l15;
            const v8s bh = *(const v8s*)&AT[col * 136 + kt * 32 + q8];
            const v8s bl = *(const v8s*)&AT[col * 136 + 64 + kt * 32 + q8];
            accf[nt] = __builtin_amdgcn_mfma_f32_16x16x32_bf16(afh, bh, accf[nt], 0, 0, 0);
            accf[nt] = __builtin_amdgcn_mfma_f32_16x16x32_bf16(afh, bl, accf[nt], 0, 0, 0);
            accf[nt] = __builtin_amdgcn_mfma_f32_16x16x32_bf16(afl, bh, accf[nt], 0, 0, 0);
            accg[nt] = __builtin_amdgcn_mfma_f32_16x16x32_bf16(agh, bh, accg[nt], 0, 0, 0);
            accg[nt] = __builtin_amdgcn_mfma_f32_16x16x32_bf16(agh, bl, accg[nt], 0, 0, 0);
            accg[nt] = __builtin_amdgcn_mfma_f32_16x16x32_bf16(agl, bh, accg[nt], 0, 0, 0);
        }
    }

    // gate + split (split reused for G store and GT staging)
    unsigned short gh[4][4], gl[4][4];
#pragma unroll
    for (int nt = 0; nt < 4; ++nt)
#pragma unroll
        for (int r = 0; r < 4; ++r) {
            const float f = accf[nt][r];
            const float g = accg[nt][r];
            const float th = 1.f - 2.f / (__expf(2.f * f) + 1.f);
            const float sg = 1.f / (1.f + __expf(-g));
            split2(th * sg, gh[nt][r], gl[nt][r]);
        }

    const int m0c = j0 - so_;
    if (m0c >= M0 && m0c < M1) {
#pragma unroll
        for (int nt = 0; nt < 4; ++nt)
#pragma unroll
            for (int r = 0; r < 4; ++r) {
                const int ch = mh * 16 + quad * 4 + r;
                const int m = (m0c - M0) + colb + nt * 16 + l15;
                gsl[(size_t)ch * gStride + m] =
                    ((unsigned)gl[nt][r] << 16) | (unsigned)gh[nt][r];
            }
    }

    if (doRes) {
        __syncthreads();   // all stage-A AT reads complete before GT overlays U
#pragma unroll
        for (int nt = 0; nt < 4; ++nt)
#pragma unroll
            for (int r = 0; r < 4; ++r) {
                const int ch = mh * 16 + quad * 4 + r;
                const int col = colb + nt * 16 + l15;
                GT[col * 72 + ch] = gh[nt][r];
                GT[col * 72 + 32 + ch] = gl[nt][r];
            }
        __syncthreads();

        v4f accr[4];
#pragma unroll
        for (int nt = 0; nt < 4; ++nt) accr[nt] = (v4f)(0.f);
#pragma unroll
        for (int kt = 0; kt < 2; ++kt) {
            const int row = (mh * 16 + l15) * 64 + kt * 32 + q8;
            const v8s arh = *(const v8s*)&wr_hi[row];
            const v8s arl = *(const v8s*)&wr_lo[row];
#pragma unroll
            for (int nt = 0; nt < 4; ++nt) {
                const int col = colb + nt * 16 + l15;
                const v8s b = *(const v8s*)&GT[col * 72 + kt * 32 + q8];
                accr[nt] = __builtin_amdgcn_mfma_f32_16x16x32_bf16(arh, b, accr[nt], 0, 0, 0);
                accr[nt] = __builtin_amdgcn_mfma_f32_16x16x32_bf16(arl, b, accr[nt], 0, 0, 0);
            }
        }

        // tap1 re-loaded from global (same packed value as the AT copy)
        const unsigned* tp = hin + (j0 + NpmP - hinBase);
#pragma unroll
        for (int nt = 0; nt < 4; ++nt)
#pragma unroll
            for (int r = 0; r < 4; ++r) {
                const int o = mh * 16 + quad * 4 + r;
                const int col = colb + nt * 16 + l15;
                const float tap1 = unpack2f(tp[(size_t)o * hinStride + col]);
                hout[(size_t)o * houtStride + (j0 - houtBase) + col] =
                    packsplit(accr[nt][r] + tap1);
            }
    }
}

// Fused skip -> relu -> end1 + bias -> relu -> y1 (split-bf16 MFMA).
__global__ __launch_bounds__(256, 2) void k_skip_end1_m(
    const unsigned* __restrict__ g,
    const unsigned short* __restrict__ swt_hi, const unsigned short* __restrict__ swt_lo,
    const unsigned short* __restrict__ e1t_hi, const unsigned short* __restrict__ e1t_lo,
    const float* __restrict__ b1, float* __restrict__ y1, const int gs)
{
    __shared__ unsigned short U[33792];
    unsigned short* gt_hi = U;
    unsigned short* gt_lo = U + 12800;
    unsigned short* st_hi = U;
    unsigned short* st_lo = U + 16896;

    const int tid  = threadIdx.x;
    const int m0   = blockIdx.x * 64;
    const int lane = tid & 63;
    const int w    = tid >> 6;
    const int l15  = lane & 15;
    const int q8   = (lane >> 4) * 8;
    const int rbase = (lane >> 4) * 4;

    {
        const int scol = tid & 63;
        const int ks0  = (tid >> 6) * 8;
        for (int kc = 0; kc < 192; kc += 32) {
            alignas(16) unsigned short h8[8], l8[8];
#pragma unroll
            for (int j = 0; j < 8; ++j) {
                const int k = kc + ks0 + j;
                const unsigned v = g[(size_t)(k >> 5) * 32 * gs + (size_t)(k & 31) * gs + m0 + scol];
                h8[j] = (unsigned short)(v & 0xffffu);
                l8[j] = (unsigned short)(v >> 16);
            }
            *(v8s*)&gt_hi[scol * 200 + kc + ks0] = *(v8s*)h8;
            *(v8s*)&gt_lo[scol * 200 + kc + ks0] = *(v8s*)l8;
        }
    }
    __syncthreads();

    v4f acc1[4][4];
#pragma unroll
    for (int a = 0; a < 4; ++a)
#pragma unroll
        for (int b = 0; b < 4; ++b) acc1[a][b] = (v4f)(0.f);

    for (int kc = 0; kc < 192; kc += 32) {
        v8s ah[4], al[4], bh[4], bl[4];
#pragma unroll
        for (int t = 0; t < 4; ++t) {
            const int row = (w * 64 + t * 16 + l15) * 192 + kc + q8;
            ah[t] = *(const v8s*)&swt_hi[row];
            al[t] = *(const v8s*)&swt_lo[row];
            const int bo = (t * 16 + l15) * 200 + kc + q8;
            bh[t] = *(const v8s*)&gt_hi[bo];
            bl[t] = *(const v8s*)&gt_lo[bo];
        }
#pragma unroll
        for (int ct = 0; ct < 4; ++ct)
#pragma unroll
            for (int nt = 0; nt < 4; ++nt) {
                acc1[ct][nt] = __builtin_amdgcn_mfma_f32_16x16x32_bf16(ah[ct], bh[nt], acc1[ct][nt], 0, 0, 0);
                acc1[ct][nt] = __builtin_amdgcn_mfma_f32_16x16x32_bf16(ah[ct], bl[nt], acc1[ct][nt], 0, 0, 0);
                acc1[ct][nt] = __builtin_amdgcn_mfma_f32_16x16x32_bf16(al[ct], bh[nt], acc1[ct][nt], 0, 0, 0);
            }
    }
    __syncthreads();

#pragma unroll
    for (int ct = 0; ct < 4; ++ct)
#pragma unroll
        for (int nt = 0; nt < 4; ++nt) {
            alignas(8) unsigned short sh[4], sl[4];
#pragma unroll
            for (int r = 0; r < 4; ++r) {
                const float v = fmaxf(acc1[ct][nt][r], 0.f);
                split2(v, sh[r], sl[r]);
            }
            const int ci  = w * 64 + ct * 16 + rbase;
            const int col = nt * 16 + l15;
            *(uint2*)&st_hi[col * 264 + ci] = *(uint2*)sh;
            *(uint2*)&st_lo[col * 264 + ci] = *(uint2*)sl;
        }
    __syncthreads();

    v4f acc2[2][4];
#pragma unroll
    for (int a = 0; a < 2; ++a)
#pragma unroll
        for (int b = 0; b < 4; ++b) acc2[a][b] = (v4f)(0.f);

    for (int kc = 0; kc < 256; kc += 32) {
        v8s ah[2], al[2], bh[4], bl[4];
#pragma unroll
        for (int t = 0; t < 2; ++t) {
            const int row = (w * 32 + t * 16 + l15) * 256 + kc + q8;
            ah[t] = *(const v8s*)&e1t_hi[row];
            al[t] = *(const v8s*)&e1t_lo[row];
        }
#pragma unroll
        for (int t = 0; t < 4; ++t) {
            const int bo = (t * 16 + l15) * 264 + kc + q8;
            bh[t] = *(const v8s*)&st_hi[bo];
            bl[t] = *(const v8s*)&st_lo[bo];
        }
#pragma unroll
        for (int ct = 0; ct < 2; ++ct)
#pragma unroll
            for (int nt = 0; nt < 4; ++nt) {
                acc2[ct][nt] = __builtin_amdgcn_mfma_f32_16x16x32_bf16(ah[ct], bh[nt], acc2[ct][nt], 0, 0, 0);
                acc2[ct][nt] = __builtin_amdgcn_mfma_f32_16x16x32_bf16(ah[ct], bl[nt], acc2[ct][nt], 0, 0, 0);
                acc2[ct][nt] = __builtin_amdgcn_mfma_f32_16x16x32_bf16(al[ct], bh[nt], acc2[ct][nt], 0, 0, 0);
            }
    }

#pragma unroll
    for (int ct = 0; ct < 2; ++ct) {
        const int cobase = w * 32 + ct * 16 + rbase;
        float bb[4];
#pragma unroll
        for (int r = 0; r < 4; ++r) bb[r] = b1[cobase + r];
#pragma unroll
        for (int nt = 0; nt < 4; ++nt) {
            const int col = m0 + nt * 16 + l15;
#pragma unroll
            for (int r = 0; r < 4; ++r)
                y1[(size_t)(cobase + r) * gs + col] = fmaxf(acc2[ct][nt][r] + bb[r], 0.f);
        }
    }
}

// Fused maxpool3s2 + end2 (128->32) via split-bf16 MFMA. 64 pooled cols/block.
__global__ __launch_bounds__(256) void k_pe2_m(
    const float* __restrict__ y1c,
    const unsigned short* __restrict__ e2s_hi, const unsigned short* __restrict__ e2s_lo,
    const float* __restrict__ b2, float* __restrict__ e2c,
    const int gs, const int p1s)
{
    __shared__ unsigned short SP[2 * 64 * 136];
    unsigned short* sp_hi = SP;
    unsigned short* sp_lo = SP + 64 * 136;

    const int tid = threadIdx.x;
    const int m0 = blockIdx.x * 64;
    const int tp = m0 >> 8;
    const int nb = m0 & 255;

    {
        const int col = tid & 63;
        const int cig = tid >> 6;
        const int base = 2 * tp * 256 + nb + col;
#pragma unroll
        for (int u8 = 0; u8 < 4; ++u8) {
            alignas(16) unsigned short h8[8], l8[8];
#pragma unroll
            for (int u = 0; u < 8; ++u) {
                const int ci = cig * 32 + u8 * 8 + u;
                const float* yp = y1c + (size_t)ci * gs + base;
                const float v = fmaxf(fmaxf(yp[0], yp[256]), yp[512]);
                split2(v, h8[u], l8[u]);
            }
            *(uint4*)&sp_hi[col * 136 + cig * 32 + u8 * 8] = *(uint4*)h8;
            *(uint4*)&sp_lo[col * 136 + cig * 32 + u8 * 8] = *(uint4*)l8;
        }
    }
    __syncthreads();

    const int lane = tid & 63;
    const int w    = tid >> 6;
    const int mh   = w & 1;
    const int colh = w >> 1;
    const int l15  = lane & 15;
    const int quad = lane >> 4;
    const int q8   = quad * 8;

    v4f acc[2];
    acc[0] = (v4f)(0.f); acc[1] = (v4f)(0.f);

#pragma unroll
    for (int kc = 0; kc < 128; kc += 32) {
        const int row = (mh * 16 + l15) * 128 + kc + q8;
        const v8s ah = *(const v8s*)&e2s_hi[row];
        const v8s al = *(const v8s*)&e2s_lo[row];
#pragma unroll
        for (int nt = 0; nt < 2; ++nt) {
            const int col = colh * 32 + nt * 16 + l15;
            const v8s bh = *(const v8s*)&sp_hi[col * 136 + kc + q8];
            const v8s bl = *(const v8s*)&sp_lo[col * 136 + kc + q8];
            acc[nt] = __builtin_amdgcn_mfma_f32_16x16x32_bf16(ah, bh, acc[nt], 0, 0, 0);
            acc[nt] = __builtin_amdgcn_mfma_f32_16x16x32_bf16(ah, bl, acc[nt], 0, 0, 0);
            acc[nt] = __builtin_amdgcn_mfma_f32_16x16x32_bf16(al, bh, acc[nt], 0, 0, 0);
        }
    }

#pragma unroll
    for (int nt = 0; nt < 2; ++nt)
#pragma unroll
        for (int r = 0; r < 4; ++r) {
            const int co = mh * 16 + quad * 4 + r;
            const int col = m0 + colh * 32 + nt * 16 + l15;
            e2c[(size_t)co * p1s + col] = fmaxf(acc[nt][r] + b2[co], 0.f);
        }
}

// pool2 -> p2 stored packed-split u32 (consumed by k_fc1_m)
__global__ __launch_bounds__(256) void k_pool2p(const float* __restrict__ e2c,
                                                unsigned* __restrict__ p2,
                                                const int p1s, const int A) {
    const int n = threadIdx.x, tl2 = blockIdx.x, co = blockIdx.y;
    const int base = co * p1s + tl2 * 512 + n;
    float v = fmaxf(fmaxf(e2c[base], e2c[base + 256]), e2c[base + 512]);
    p2[co * 81152 + (A + tl2) * 256 + n] = packsplit(v);
}

// FC1 via split-bf16 MFMA: C[1024 x 256] += W1[1024 x 10144] @ P2[10144 x 256].
__global__ __launch_bounds__(256) void k_fc1_m(
    const unsigned short* __restrict__ w1s_hi, const unsigned short* __restrict__ w1s_lo,
    const unsigned* __restrict__ p2u, float* __restrict__ out)
{
    __shared__ unsigned short SB[2 * 64 * 40];
    unsigned short* sb_hi = SB;
    unsigned short* sb_lo = SB + 64 * 40;

    const int tid = threadIdx.x;
    const int o0 = blockIdx.x * 64;
    const int b0 = blockIdx.y * 64;
    const int k0 = blockIdx.z * 1280;
    const int kend = (k0 + 1280 < 10144) ? (k0 + 1280) : 10144;
    const int nch = (kend - k0) >> 5;

    const int lane = tid & 63;
    const int w    = tid >> 6;
    const int l15  = lane & 15;
    const int quad = lane >> 4;
    const int q8   = quad * 8;
    const int scol = tid & 63;
    const int kq   = tid >> 6;

    v4f acc[4];
#pragma unroll
    for (int nt = 0; nt < 4; ++nt) acc[nt] = (v4f)(0.f);

    for (int c = 0; c < nch; ++c) {
        const int kc = k0 + c * 32;
        alignas(16) unsigned short h8[8], l8[8];
#pragma unroll
        for (int j = 0; j < 8; ++j) {
            const unsigned v = p2u[(size_t)(kc + kq * 8 + j) * 256 + b0 + scol];
            h8[j] = (unsigned short)(v & 0xffffu);
            l8[j] = (unsigned short)(v >> 16);
        }
        __syncthreads();
        *(v8s*)&sb_hi[scol * 40 + kq * 8] = *(v8s*)h8;
        *(v8s*)&sb_lo[scol * 40 + kq * 8] = *(v8s*)l8;
        __syncthreads();

        const int arow = (o0 + w * 16 + l15) * 10144 + kc + q8;
        const v8s ah = *(const v8s*)&w1s_hi[arow];
        const v8s al = *(const v8s*)&w1s_lo[arow];
#pragma unroll
        for (int nt = 0; nt < 4; ++nt) {
            const v8s bh = *(const v8s*)&sb_hi[(nt * 16 + l15) * 40 + q8];
            const v8s bl = *(const v8s*)&sb_lo[(nt * 16 + l15) * 40 + q8];
            acc[nt] = __builtin_amdgcn_mfma_f32_16x16x32_bf16(ah, bh, acc[nt], 0, 0, 0);
            acc[nt] = __builtin_amdgcn_mfma_f32_16x16x32_bf16(ah, bl, acc[nt], 0, 0, 0);
            acc[nt] = __builtin_amdgcn_mfma_f32_16x16x32_bf16(al, bh, acc[nt], 0, 0, 0);
        }
    }

#pragma unroll
    for (int nt = 0; nt < 4; ++nt)
#pragma unroll
        for (int r = 0; r < 4; ++r)
            atomicAdd(&out[(size_t)(o0 + w * 16 + quad * 4 + r) * 256 + b0 + nt * 16 + l15],
                      acc[nt][r]);
}

// Tiled f32 GEMM (FC2 only).
__global__ __launch_bounds__(256) void k_gemm64(const float* __restrict__ A,
                                                const float* __restrict__ B,
                                                float* __restrict__ C,
                                                const int Ktot, const int KC) {
    __shared__ float sA[32 * 65];
    __shared__ float sB[32 * 68];

    const int tid = threadIdx.x;
    const int o0 = blockIdx.x * 64;
    const int b0 = blockIdx.y * 64;
    const int k0 = blockIdx.z * KC;

    float acc[4][4];
#pragma unroll
    for (int i = 0; i < 4; ++i)
#pragma unroll
        for (int jq = 0; jq < 4; ++jq) acc[i][jq] = 0.f;

    const int ao  = tid >> 2;
    const int ak8 = (tid & 3) * 8;
    const int bk  = tid >> 3;
    const int bb8 = (tid & 7) * 8;
    const int to4 = (tid & 15) * 4;
    const int tb4 = (tid >> 4) * 4;

    for (int kc = 0; kc < KC; kc += 32) {
        const int kcLen = (KC - kc < 32) ? (KC - kc) : 32;
        const float* ap = A + (size_t)(o0 + ao) * Ktot + k0 + kc + ak8;
#pragma unroll
        for (int i = 0; i < 8; ++i) {
            float v = (ak8 + i < kcLen) ? ap[i] : 0.f;
            sA[(ak8 + i) * 65 + ao] = v;
        }
        if (bk < kcLen) {
            const float* bp = B + (size_t)(k0 + kc + bk) * 256 + b0 + bb8;
            const float4 v0 = *(const float4*)bp;
            const float4 v1 = *(const float4*)(bp + 4);
            *(float4*)&sB[bk * 68 + bb8] = v0;
            *(float4*)&sB[bk * 68 + bb8 + 4] = v1;
        } else {
            float4 z; z.x = z.y = z.z = z.w = 0.f;
            *(float4*)&sB[bk * 68 + bb8] = z;
            *(float4*)&sB[bk * 68 + bb8 + 4] = z;
        }
        __syncthreads();

#pragma unroll 8
        for (int kk = 0; kk < 32; ++kk) {
            const float4 av = *(const float4*)&sA[kk * 65 + to4];
            const float4 bv = *(const float4*)&sB[kk * 68 + tb4];
            const float aa[4] = {av.x, av.y, av.z, av.w};
#pragma unroll
            for (int i = 0; i < 4; ++i) {
                acc[i][0] = fmaf(aa[i], bv.x, acc[i][0]);
                acc[i][1] = fmaf(aa[i], bv.y, acc[i][1]);
                acc[i][2] = fmaf(aa[i], bv.z, acc[i][2]);
                acc[i][3] = fmaf(aa[i], bv.w, acc[i][3]);
            }
        }
        __syncthreads();
    }

#pragma unroll
    for (int i = 0; i < 4; ++i)
#pragma unroll
        for (int jq = 0; jq < 4; ++jq)
            atomicAdd(&C[(size_t)(o0 + to4 + i) * 256 + b0 + tb4 + jq], acc[i][jq]);
}

__global__ __launch_bounds__(256) void k_actbias(const float* __restrict__ raw,
                                                 const float* __restrict__ bias,
                                                 float* __restrict__ out) {
    const int k = blockIdx.x, b = threadIdx.x;
    out[k * 256 + b] = fmaxf(raw[k * 256 + b] + bias[k], 0.f);
}

__global__ __launch_bounds__(256) void k_fc3(const float* __restrict__ fc2raw,
                                             const float* __restrict__ fb2,
                                             const float* __restrict__ w3,
                                             const float* __restrict__ b3,
                                             float* __restrict__ out) {
    const int b = threadIdx.x;
    float l0 = b3[0], l1 = b3[1];
    for (int k = 0; k < 256; ++k) {
        const float a = fmaxf(fc2raw[k * 256 + b] + fb2[k], 0.f);
        l0 = fmaf(w3[k], a, l0);
        l1 = fmaf(w3[256 + k], a, l1);
    }
    out[2 * b] = l0;
    out[2 * b + 1] = l1;
    const float mx = fmaxf(l0, l1);
    const float e0 = expf(l0 - mx), e1 = expf(l1 - mx);
    const float inv = 1.f / (e0 + e1);
    out[512 + 2 * b] = e0 * inv;
    out[513 + 2 * b] = e1 * inv;
    out[1024 + b] = (l1 > l0) ? 1.f : 0.f;
}

extern "C" void kernel_launch(void* const* d_in, const int* in_sizes, int n_in,
                              void* d_out, int out_size, void* d_ws, size_t ws_size,
                              hipStream_t stream) {
    const float* x        = (const float*)d_in[0];
    const float* start_w  = (const float*)d_in[1];
    const float* filter_w = (const float*)d_in[2];
    const float* gate_w   = (const float*)d_in[3];
    const float* res_w    = (const float*)d_in[4];
    const float* skip_w   = (const float*)d_in[5];
    const float* e1w      = (const float*)d_in[6];
    const float* e1b      = (const float*)d_in[7];
    const float* e2w      = (const float*)d_in[8];
    const float* e2b      = (const float*)d_in[9];
    const float* w1       = (const float*)d_in[10];
    const float* fb1      = (const float*)d_in[11];
    const float* w2       = (const float*)d_in[12];
    const float* fb2      = (const float*)d_in[13];
    const float* w3       = (const float*)d_in[14];
    const float* b3       = (const float*)d_in[15];

    float* ws = (float*)d_ws;

    const long o_h0   = 0;            // 10,485,760
    const long o_p2   = 10485760;     // 2,596,864
    const long o_fc1  = 13082624;     // 262,144
    const long o_fc2  = 13344768;     // 65,536
    const long o_wbf  = 13410304;     // 81,920
    const long o_wfg  = 13492224;     // 24,576
    const long o_wr   = 13516800;     // 12,288
    const long o_e2s  = 13529088;     // 4,096
    const long o_act1 = 13533184;     // 262,144
    const long o_w1s  = 13795328;     // 10,387,456 (w1 hi+lo u16)
    const long o_G    = 24182784;

    long budget = (long)((double)ws_size * 0.94 / 4.0);
    int dB = 1;
    for (int d = 317; d >= 1; --d) {
        long mch = 256L * (4L * d + 3), hs = mch + 4096;
        long tot = o_G + 192L * mch + lmax_(128L * mch, 64L * hs);
        if (tot <= budget) { dB = d; break; }
    }
    int K = (317 + dB - 1) / dB;
    dB = (317 + K - 1) / K;
    const long MchA  = 256L * (4L * dB + 3);
    const long HSPAN = MchA + 4096;
    const long o_X   = o_G + 192L * MchA;
    const long P1S   = 256L * (2L * dB + 1);

    unsigned* h0 = (unsigned*)(ws + o_h0);
    unsigned* p2 = (unsigned*)(ws + o_p2);
    float* fc1r = ws + o_fc1;
    float* fc2r = ws + o_fc2;
    unsigned short* swt_hi = (unsigned short*)(ws + o_wbf);
    unsigned short* swt_lo = swt_hi + 49152;
    unsigned short* e1t_hi = swt_lo + 49152;
    unsigned short* e1t_lo = e1t_hi + 32768;
    unsigned short* wfg_hi = (unsigned short*)(ws + o_wfg);
    unsigned short* wfg_lo = wfg_hi + 24576;
    unsigned short* wr_hi  = (unsigned short*)(ws + o_wr);
    unsigned short* wr_lo  = wr_hi + 12288;
    unsigned short* e2s_hi = (unsigned short*)(ws + o_e2s);
    unsigned short* e2s_lo = e2s_hi + 4096;
    unsigned short* w1s_hi = (unsigned short*)(ws + o_w1s);
    unsigned short* w1s_lo = w1s_hi + 10387456;
    float* act1 = ws + o_act1;
    unsigned* G  = (unsigned*)(ws + o_G);
    unsigned* hA = (unsigned*)(ws + o_X);
    unsigned* hB = (unsigned*)(ws + o_X) + 32L * HSPAN;
    float* y1c  = ws + o_X;                 // aliases hA/hB (dead by then)
    float* e2c  = ws + o_G;                 // aliases G (dead after skip_end1)

    k_zero<<<1280, 256, 0, stream>>>(fc1r, 327680);
    k_start<<<1280, 256, 0, stream>>>(x, start_w, h0);
    k_prep<<<192, 256, 0, stream>>>(skip_w, e1w, filter_w, gate_w, res_w, e2w,
                                    swt_hi, swt_lo, e1t_hi, e1t_lo,
                                    wfg_hi, wfg_lo, wr_hi, wr_lo,
                                    e2s_hi, e2s_lo);
    k_prep_w1<<<40576, 256, 0, stream>>>(w1, w1s_hi, w1s_lo);

    const int Mc[6]   = {327424, 327168, 326656, 326400, 326144, 325632};
    const int NpmP[6] = {256, 256, 512, 256, 256, 512};
    const int pN[6]   = {0, 256, 512, 0, 256, 512};
    const int so_[6]  = {1792, 1536, 1024, 768, 512, 0};
    const int JloO[6] = {-1536, -1280, -768, -768, -512, 0};

    for (int c = 0; c < K; ++c) {
        const int A = c * dB;
        int B = A + dB; if (B > 317) B = 317;
        const int dBc = B - A;
        const int M0 = 1024 * A;
        int tmax = 4 * B + 3; if (tmax > 1272) tmax = 1272;
        const int Tt = tmax - 4 * A;
        const int M1 = M0 + 256 * Tt;

        int Jlo[6], Jhi[6];
        for (int q = 0; q < 6; ++q) {
            int lo = M0 + JloO[q]; if (lo < 0) lo = 0;
            int hi = M1 + so_[q];  if (hi > Mc[q]) hi = Mc[q];
            Jlo[q] = lo; Jhi[q] = hi;
        }

        for (int q = 0; q < 6; ++q) {
            const unsigned* hin = (q == 0) ? h0 : ((q & 1) ? hA : hB);
            const int hinBase   = (q == 0) ? 0 : Jlo[q - 1];
            const int hinStride = (q == 0) ? MCAP : (int)HSPAN;
            unsigned* hout = (q & 1) ? hB : hA;
            const int Jcnt = Jhi[q] - Jlo[q];     // % 128 == 0
            k_layer_m<<<Jcnt / 128, 256, 0, stream>>>(
                hin, hinBase, hinStride, hout, Jlo[q], (int)HSPAN,
                G + (long)q * 32 * MchA, (int)MchA,
                wfg_hi + q * 4096, wfg_lo + q * 4096,
                wr_hi + q * 2048, wr_lo + q * 2048,
                Jlo[q], NpmP[q], pN[q], so_[q], M0, M1, (q < 5) ? 1 : 0);
        }

        const int Mchc = 256 * Tt;
        k_skip_end1_m<<<Mchc / 64, 256, 0, stream>>>(
            G, swt_hi, swt_lo, e1t_hi, e1t_lo, e1b, y1c, (int)MchA);
        const int T1c = 2 * dBc + 1;
        k_pe2_m<<<T1c * 4, 256, 0, stream>>>(
            y1c, e2s_hi, e2s_lo, e2b, e2c, (int)MchA, (int)P1S);
        k_pool2p<<<dim3(dBc, 32), 256, 0, stream>>>(e2c, p2, (int)P1S, A);
    }

    k_fc1_m<<<dim3(16, 4, 8), 256, 0, stream>>>(w1s_hi, w1s_lo, p2, fc1r);
    k_actbias<<<1024, 256, 0, stream>>>(fc1r, fb1, act1);
    k_gemm64<<<dim3(4, 4, 4), 256, 0, stream>>>(w2, act1, fc2r, 1024, 256);
    k_fc3<<<1, 256, 0, stream>>>(fc2r, fb2, w3, b3, (float*)d_out);
}